// Round 10
// baseline (212.379 us; speedup 1.0000x reference)
//
#include <hip/hip_runtime.h>
#include <math.h>

#define NH 16
#define NKV 8
#define HDIM 128
#define SEQ 2048
#define DMODEL 2048

typedef int   v4i __attribute__((ext_vector_type(4)));
typedef float v4f __attribute__((ext_vector_type(4)));
typedef _Float16 v8h __attribute__((ext_vector_type(8)));

static constexpr float SM_SCALE = 0.08838834764831843f; // 128**-0.5

#define GLOBP(p) (__attribute__((address_space(1))) void*)(p)
#define LDSP(p)  (__attribute__((address_space(3))) void*)(p)
#define ASYNC16(g, l) __builtin_amdgcn_global_load_lds(GLOBP(g), LDSP(l), 16, 0, 0)

// Fragment-tiled i8 layout for X[R][K] (R%16==0, K%64==0):
// frag (r>>4, k>>6) is 1024B; within: byte = ((k>>4)&3)*256 + (r&15)*16 + (k&15).

__device__ __forceinline__ unsigned short f2h_bits(float x) {
    _Float16 h = (_Float16)x;               // RN, exact for small ints
    return __builtin_bit_cast(unsigned short, h);
}

// ---------------- merged per-row int8 quant for all 5 inputs ----------------
__global__ __launch_bounds__(256) void quant_all_k(const float* __restrict__ hidden,
        const float* __restrict__ Wq, const float* __restrict__ Wk,
        const float* __restrict__ Wv, const float* __restrict__ Wo,
        signed char* __restrict__ out, float* __restrict__ scale) {
    int p = blockIdx.x;               // 16-row panel index, 512 total
    int row0g = p * 16;
    const float* in; int lr0;
    if (row0g < 2048)      { in = hidden; lr0 = row0g; }
    else if (row0g < 4096) { in = Wq; lr0 = row0g - 2048; }
    else if (row0g < 5120) { in = Wk; lr0 = row0g - 4096; }
    else if (row0g < 6144) { in = Wv; lr0 = row0g - 5120; }
    else                   { in = Wo; lr0 = row0g - 6144; }
    const int cols = 2048;
    int tid = threadIdx.x;
    __shared__ float srow[16];
    int r = tid >> 4, l16 = tid & 15;
    const float4* x4 = (const float4*)(in + (size_t)(lr0 + r) * cols);
    float amax = 0.f;
    for (int c4 = l16; c4 < (cols >> 2); c4 += 16) {
        float4 v = x4[c4];
        amax = fmaxf(amax, fmaxf(fmaxf(fabsf(v.x), fabsf(v.y)),
                                 fmaxf(fabsf(v.z), fabsf(v.w))));
    }
#pragma unroll
    for (int m = 1; m <= 8; m <<= 1) amax = fmaxf(amax, __shfl_xor(amax, m));
    if (l16 == 0) {
        float s = fmaxf(amax / 127.0f, 1e-8f);
        srow[r] = s;
        scale[row0g + r] = s;
    }
    __syncthreads();
    int total = (cols >> 4) * 16;
    size_t obase = (size_t)p * 32768;
    for (int idx = tid; idx < total; idx += 256) {
        int f = idx >> 6, q = (idx >> 4) & 3, rr = idx & 15;
        const float* src = in + (size_t)(lr0 + rr) * cols + f * 64 + q * 16;
        float s = srow[rr];
        unsigned int wds[4];
#pragma unroll
        for (int g = 0; g < 4; ++g) {
            float4 v = *(const float4*)(src + g * 4);
            int b0 = (int)fminf(fmaxf(rintf(v.x / s), -127.f), 127.f);
            int b1 = (int)fminf(fmaxf(rintf(v.y / s), -127.f), 127.f);
            int b2 = (int)fminf(fmaxf(rintf(v.z / s), -127.f), 127.f);
            int b3 = (int)fminf(fmaxf(rintf(v.w / s), -127.f), 127.f);
            wds[g] = (b0 & 255) | ((b1 & 255) << 8) | ((b2 & 255) << 16) | ((b3 & 255) << 24);
        }
        *(uint4*)(out + obase + (size_t)idx * 16) =
            make_uint4(wds[0], wds[1], wds[2], wds[3]);
    }
}

// ---------------- single-tensor row quant (for attn2) ----------------
__global__ __launch_bounds__(256) void row_quant_k(const float* __restrict__ in,
        signed char* __restrict__ out, float* __restrict__ scale, int cols) {
    int row0 = blockIdx.x * 16;
    int tid = threadIdx.x;
    __shared__ float srow[16];
    int r = tid >> 4, l16 = tid & 15;
    const float4* x4 = (const float4*)(in + (size_t)(row0 + r) * cols);
    float amax = 0.f;
    for (int c4 = l16; c4 < (cols >> 2); c4 += 16) {
        float4 v = x4[c4];
        amax = fmaxf(amax, fmaxf(fmaxf(fabsf(v.x), fabsf(v.y)),
                                 fmaxf(fabsf(v.z), fabsf(v.w))));
    }
#pragma unroll
    for (int m = 1; m <= 8; m <<= 1) amax = fmaxf(amax, __shfl_xor(amax, m));
    if (l16 == 0) {
        float s = fmaxf(amax / 127.0f, 1e-8f);
        srow[r] = s;
        scale[row0 + r] = s;
    }
    __syncthreads();
    int total = (cols >> 4) * 16;
    size_t obase = ((size_t)(row0 >> 4) * (cols >> 6)) << 10;
    for (int idx = tid; idx < total; idx += 256) {
        int f = idx >> 6, q = (idx >> 4) & 3, rr = idx & 15;
        const float* src = in + (size_t)(row0 + rr) * cols + f * 64 + q * 16;
        float s = srow[rr];
        unsigned int wds[4];
#pragma unroll
        for (int g = 0; g < 4; ++g) {
            float4 v = *(const float4*)(src + g * 4);
            int b0 = (int)fminf(fmaxf(rintf(v.x / s), -127.f), 127.f);
            int b1 = (int)fminf(fmaxf(rintf(v.y / s), -127.f), 127.f);
            int b2 = (int)fminf(fmaxf(rintf(v.z / s), -127.f), 127.f);
            int b3 = (int)fminf(fmaxf(rintf(v.w / s), -127.f), 127.f);
            wds[g] = (b0 & 255) | ((b1 & 255) << 8) | ((b2 & 255) << 16) | ((b3 & 255) << 24);
        }
        *(uint4*)(out + obase + (size_t)idx * 16) =
            make_uint4(wds[0], wds[1], wds[2], wds[3]);
    }
}

// ---------------- int8 GEMM on tiled A/B, double-buffered LDS ----------------
__global__ __launch_bounds__(256, 2) void gemm_i8_k(const signed char* __restrict__ A,
        const float* __restrict__ sa, const signed char* __restrict__ B,
        const float* __restrict__ sb, float* __restrict__ C, int M, int N, int K) {
    __shared__ __align__(16) signed char lsA[2][8192];
    __shared__ __align__(16) signed char lsB[2][8192];
    int tid = threadIdx.x;
    int w = tid >> 6, l = tid & 63;
    int wr = w >> 1, wc = w & 1;
    int lrow = l & 15;
    int m0 = blockIdx.y * 128, n0 = blockIdx.x * 128;
    int kb6 = K >> 6;
    v4i acc[4][4];
#pragma unroll
    for (int i = 0; i < 4; ++i)
#pragma unroll
        for (int j = 0; j < 4; ++j) acc[i][j] = (v4i){0, 0, 0, 0};

    auto stage = [&](int buf, int k6) {
#pragma unroll
        for (int a = 0; a < 2; ++a) {
            int f = a * 4 + w;
            ASYNC16(A + (((size_t)(((m0 >> 4) + f) * kb6 + k6)) << 10) + l * 16,
                    lsA[buf] + f * 1024);
            ASYNC16(B + (((size_t)(((n0 >> 4) + f) * kb6 + k6)) << 10) + l * 16,
                    lsB[buf] + f * 1024);
        }
    };

    stage(0, 0);
    asm volatile("s_waitcnt vmcnt(0)" ::: "memory");
    __syncthreads();
    int cur = 0;
    for (int t = 0; t < kb6; ++t) {
        if (t + 1 < kb6) stage(cur ^ 1, t + 1);
        v4i af[4], bf[4];
#pragma unroll
        for (int i = 0; i < 4; ++i) af[i] = *(const v4i*)(lsA[cur] + (wr * 4 + i) * 1024 + l * 16);
#pragma unroll
        for (int j = 0; j < 4; ++j) bf[j] = *(const v4i*)(lsB[cur] + (wc * 4 + j) * 1024 + l * 16);
#pragma unroll
        for (int i = 0; i < 4; ++i)
#pragma unroll
            for (int j = 0; j < 4; ++j)
                acc[i][j] = __builtin_amdgcn_mfma_i32_16x16x64_i8(af[i], bf[j], acc[i][j], 0, 0, 0);
        asm volatile("s_waitcnt vmcnt(0)" ::: "memory");
        __syncthreads();
        cur ^= 1;
    }
    int r0 = m0 + wr * 64, c0 = n0 + wc * 64;
    int lg = l >> 4;
    float sbv[4];
#pragma unroll
    for (int j = 0; j < 4; ++j) sbv[j] = sb[c0 + j * 16 + lrow];
#pragma unroll
    for (int i = 0; i < 4; ++i) {
        float4 s4 = *(const float4*)(sa + r0 + i * 16 + lg * 4);
        float sav[4] = {s4.x, s4.y, s4.z, s4.w};
#pragma unroll
        for (int j = 0; j < 4; ++j) {
#pragma unroll
            for (int reg = 0; reg < 4; ++reg) {
                int rr = r0 + i * 16 + lg * 4 + reg;
                C[(size_t)rr * N + c0 + j * 16 + lrow] = (float)acc[i][j][reg] * (sav[reg] * sbv[j]);
            }
        }
    }
}

// ---------------- rope tables ----------------
__global__ void rope_init_k(float* __restrict__ inv_tab) {
    int i = threadIdx.x; // 64
    inv_tab[i] = 1.0f / (float)pow(1.0e6, (double)i / 64.0);
}
__global__ void rope_tab_k(const int* __restrict__ pos_ids, const float* __restrict__ inv_tab,
                           float* __restrict__ ct, float* __restrict__ st) {
    int t = blockIdx.x;
    int fi = threadIdx.x; // 64
    float fr = (float)pos_ids[t] * inv_tab[fi];
    float sn, c;
    sincosf(fr, &sn, &c);
    ct[t * 64 + fi] = c;
    st[t * 64 + fi] = sn;
}

// ---------------- fused rmsnorm+rope+quant for q,k only (v handled by vt_split) ----------
__global__ __launch_bounds__(256) void qkv_post_k(const float* __restrict__ qkv_lin,
        const float* __restrict__ qw, const float* __restrict__ kw,
        const float* __restrict__ ct, const float* __restrict__ st,
        signed char* __restrict__ q_i8, float* __restrict__ sq,
        signed char* __restrict__ k_i8, float* __restrict__ sk) {
    int t = blockIdx.x;
    int wv = threadIdx.x >> 6, l = threadIdx.x & 63;
    const float* row = qkv_lin + (size_t)t * 4096;
    float cth = ct[t * 64 + l];
    float sth = st[t * 64 + l];
    size_t ta0 = (size_t)(((t >> 4) * 2) << 10)
               + (size_t)((((l >> 4) & 3) << 8) + ((t & 15) << 4) + (l & 15));
    for (int slot = wv; slot < 24; slot += 4) {
        float x0 = row[slot * 128 + l];
        float x1 = row[slot * 128 + l + 64];
        float ss = x0 * x0 + x1 * x1;
#pragma unroll
        for (int m = 1; m <= 32; m <<= 1) ss += __shfl_xor(ss, m);
        float rs = 1.0f / sqrtf(ss / 128.0f + 1e-6f);
        const float* wn = (slot < 16) ? qw : kw;
        x0 = (x0 * rs) * wn[l];
        x1 = (x1 * rs) * wn[l + 64];
        float nx0 = x0 * cth - x1 * sth;
        float nx1 = x1 * cth + x0 * sth;
        x0 = nx0; x1 = nx1;
        float amax = fmaxf(fabsf(x0), fabsf(x1));
#pragma unroll
        for (int m = 1; m <= 32; m <<= 1) amax = fmaxf(amax, __shfl_xor(amax, m));
        float s = fmaxf(amax / 127.0f, 1e-8f);
        float q0 = fminf(fmaxf(rintf(x0 / s), -127.f), 127.f);
        float q1 = fminf(fmaxf(rintf(x1 / s), -127.f), 127.f);
        if (slot < 16) {
            signed char* dst = q_i8 + (size_t)slot * (SEQ * 128);
            dst[ta0] = (signed char)(int)q0;
            dst[ta0 + 1024] = (signed char)(int)q1;
            if (l == 0) sq[slot * SEQ + t] = s;
        } else {
            signed char* dst = k_i8 + (size_t)(slot - 16) * (SEQ * 128);
            dst[ta0] = (signed char)(int)q0;
            dst[ta0 + 1024] = (signed char)(int)q1;
            if (l == 0) sk[(slot - 16) * SEQ + t] = s;
        }
    }
}

// ---------------- V: quantize (per-token) + dequant + fp16 + transpose to tiled vtT ----
// Reads qkv_lin directly (v slots 24..31). vtT halfword layout per kv:
// [kb][ (d>>4)*2 + ((t>>5)&1) ][ (d&15)+16*((t>>3)&3) ][ t&7 ]
__global__ __launch_bounds__(256) void vt_split_k(const float* __restrict__ qkv_lin,
        unsigned short* __restrict__ vtT) {
    int kv = blockIdx.y, kb = blockIdx.x;
    int t0 = kb * 64;
    __shared__ float tile[64][132];
    __shared__ float srow[64];
    int tid = threadIdx.x;
    const float* src = qkv_lin + (size_t)t0 * 4096 + 3072 + kv * 128;
#pragma unroll
    for (int i = 0; i < 8; ++i) {
        int f4 = i * 256 + tid;
        int r = f4 >> 5, c = (f4 & 31) << 2;
        float4 v = *(const float4*)(src + (size_t)r * 4096 + c);
        tile[r][c] = v.x; tile[r][c + 1] = v.y; tile[r][c + 2] = v.z; tile[r][c + 3] = v.w;
    }
    __syncthreads();
    // per-token amax over the 128 dims: 4 lanes per row
    {
        int r = tid >> 2, qq = tid & 3;
        float amax = 0.f;
#pragma unroll
        for (int e = 0; e < 32; ++e) amax = fmaxf(amax, fabsf(tile[r][qq * 32 + e]));
        amax = fmaxf(amax, __shfl_xor(amax, 1));
        amax = fmaxf(amax, __shfl_xor(amax, 2));
        if (qq == 0) srow[r] = fmaxf(amax / 127.0f, 1e-8f);
    }
    __syncthreads();
    int d = tid >> 1, th = (tid & 1) * 32;
    size_t base = (size_t)kv * (SEQ * 128);
#pragma unroll
    for (int j = 0; j < 32; j += 2) {
        int tl = th + j;
        float s0 = srow[tl], s1 = srow[tl + 1];
        float a = fminf(fmaxf(rintf(tile[tl][d] / s0), -127.f), 127.f) * s0;
        float b = fminf(fmaxf(rintf(tile[tl + 1][d] / s1), -127.f), 127.f) * s1;
        unsigned int ua = f2h_bits(a), ub = f2h_bits(b);
        int off = kb * 8192 + ((d >> 4) * 2 + ((tl >> 5) & 1)) * 512
                + (((d & 15) + (((tl >> 3) & 3) << 4)) << 3) + (tl & 7);
        *(unsigned int*)(vtT + base + off) = ua | (ub << 16);
    }
}

// ---------------- attention pass 1: GQA-paired, row MAX only ----------------
__global__ __launch_bounds__(256, 4) void attn_p1_k(const signed char* __restrict__ q_i8,
        const float* __restrict__ sq, const signed char* __restrict__ k_i8,
        const float* __restrict__ sk, float* __restrict__ mm) {
    int bx = blockIdx.x, hp = blockIdx.y;
    int qb = 31 - (bx >> 2), c = bx & 3;
    int nch = (qb + 8) >> 3;
    if (c >= nch) return;
    int q0 = qb * 64;
    int kb0 = c * 8, kb1 = min((c + 1) * 8, qb + 1);
    int tid = threadIdx.x, w = tid >> 6, l = tid & 63;
    int lrow = l & 15, lg = l >> 4;
    int h0 = hp * 2, h1 = h0 + 1;

    const signed char* qtA = q_i8 + (size_t)h0 * (SEQ * 128)
                           + ((size_t)((((q0 >> 4) + w) * 2)) << 10) + l * 16;
    const signed char* qtB = qtA + (size_t)(SEQ * 128);
    v4i qfA0 = *(const v4i*)(qtA), qfA1 = *(const v4i*)(qtA + 1024);
    v4i qfB0 = *(const v4i*)(qtB), qfB1 = *(const v4i*)(qtB + 1024);
    float4 sA = *(const float4*)(sq + (size_t)h0 * SEQ + q0 + w * 16 + lg * 4);
    float4 sB = *(const float4*)(sq + (size_t)h1 * SEQ + q0 + w * 16 + lg * 4);
    float sqrA[4] = {sA.x, sA.y, sA.z, sA.w};
    float sqrB[4] = {sB.x, sB.y, sB.z, sB.w};
    const signed char* kbase = k_i8 + (size_t)hp * (SEQ * 128);
    const float* skb = sk + (size_t)hp * SEQ;

    float mA[4], mB[4];
#pragma unroll
    for (int r = 0; r < 4; ++r) { mA[r] = -1e30f; mB[r] = -1e30f; }

    v4i ka[8], kn[8];
    float skc[4], skn[4];
    auto loadK = [&](v4i* dst, float* sdst, int k0) {
#pragma unroll
        for (int f = 0; f < 8; ++f)
            dst[f] = *(const v4i*)(kbase + ((size_t)((k0 >> 4) * 2 + f) << 10) + l * 16);
#pragma unroll
        for (int j = 0; j < 4; ++j) sdst[j] = skb[k0 + j * 16 + lrow];
    };

    loadK(ka, skc, kb0 * 64);
    for (int kb = kb0; kb < kb1; ++kb) {
        if (kb + 1 < kb1) loadK(kn, skn, (kb + 1) * 64);
        int k0 = kb * 64;
        v4i sciA[4], sciB[4];
#pragma unroll
        for (int j = 0; j < 4; ++j) {
            v4i z = {0, 0, 0, 0};
            v4i tA = __builtin_amdgcn_mfma_i32_16x16x64_i8(qfA0, ka[j * 2], z, 0, 0, 0);
            sciA[j] = __builtin_amdgcn_mfma_i32_16x16x64_i8(qfA1, ka[j * 2 + 1], tA, 0, 0, 0);
            v4i tB = __builtin_amdgcn_mfma_i32_16x16x64_i8(qfB0, ka[j * 2], z, 0, 0, 0);
            sciB[j] = __builtin_amdgcn_mfma_i32_16x16x64_i8(qfB1, ka[j * 2 + 1], tB, 0, 0, 0);
        }
#pragma unroll
        for (int reg = 0; reg < 4; ++reg) {
            int r = q0 + w * 16 + lg * 4 + reg;
#pragma unroll
            for (int j = 0; j < 4; ++j) {
                bool ok = (k0 + j * 16 + lrow <= r);
                float ss = skc[j] * SM_SCALE;
                float svA = ((float)sciA[j][reg] * sqrA[reg]) * ss;
                float svB = ((float)sciB[j][reg] * sqrB[reg]) * ss;
                mA[reg] = fmaxf(mA[reg], ok ? svA : -1e30f);
                mB[reg] = fmaxf(mB[reg], ok ? svB : -1e30f);
            }
        }
        if (kb + 1 < kb1) {
#pragma unroll
            for (int f = 0; f < 8; ++f) ka[f] = kn[f];
#pragma unroll
            for (int j = 0; j < 4; ++j) skc[j] = skn[j];
        }
    }
#pragma unroll
    for (int reg = 0; reg < 4; ++reg) {
#pragma unroll
        for (int mask = 1; mask <= 8; mask <<= 1) {
            mA[reg] = fmaxf(mA[reg], __shfl_xor(mA[reg], mask));
            mB[reg] = fmaxf(mB[reg], __shfl_xor(mB[reg], mask));
        }
    }
    if (lrow == 0) {
        size_t bA = ((size_t)(h0 * 32 + qb) * 4 + c) * 64;
        size_t bB = ((size_t)(h1 * 32 + qb) * 4 + c) * 64;
#pragma unroll
        for (int reg = 0; reg < 4; ++reg) {
            mm[bA + w * 16 + lg * 4 + reg] = mA[reg];
            mm[bB + w * 16 + lg * 4 + reg] = mB[reg];
        }
    }
}

// ---------------- attention pass 2: GQA-paired split-K PV, fp16 V ----------------
// LDS: V dbuf 32K + K 8K + plds 8K = 48KB -> 3 blocks/CU.
__global__ __launch_bounds__(256, 3) void attn_p2_k(const signed char* __restrict__ q_i8,
        const float* __restrict__ sq, const signed char* __restrict__ k_i8,
        const float* __restrict__ sk, const unsigned short* __restrict__ vtT,
        const float* __restrict__ mm, float* __restrict__ attn2, float* __restrict__ pp,
        float* __restrict__ zb) {
    __shared__ __align__(16) unsigned short vlds[2][8192];  // 32 KB
    __shared__ __align__(16) signed char klds[8192];        // 8 KB
    __shared__ __align__(16) unsigned short plds[4096];     // 8 KB wave-private (A then B)
    int bx = blockIdx.x, hp = blockIdx.y;
    int qb = 31 - (bx >> 1), c = bx & 1;
    int nch2 = (qb >= 16) ? 2 : 1;
    if (c >= nch2) return;
    int q0 = qb * 64;
    int kb0 = c * 16, kb1 = min((c + 1) * 16, qb + 1);
    int tid = threadIdx.x, w = tid >> 6, l = tid & 63;
    int lrow = l & 15, lg = l >> 4;
    int h0 = hp * 2, h1 = h0 + 1;

    const signed char* qtA = q_i8 + (size_t)h0 * (SEQ * 128)
                           + ((size_t)((((q0 >> 4) + w) * 2)) << 10) + l * 16;
    const signed char* qtB = qtA + (size_t)(SEQ * 128);
    v4i qfA0 = *(const v4i*)(qtA), qfA1 = *(const v4i*)(qtA + 1024);
    v4i qfB0 = *(const v4i*)(qtB), qfB1 = *(const v4i*)(qtB + 1024);
    float4 sA = *(const float4*)(sq + (size_t)h0 * SEQ + q0 + w * 16 + lg * 4);
    float4 sB = *(const float4*)(sq + (size_t)h1 * SEQ + q0 + w * 16 + lg * 4);
    float sqrA[4] = {sA.x, sA.y, sA.z, sA.w};
    float sqrB[4] = {sB.x, sB.y, sB.z, sB.w};

    int nch1 = (qb + 8) >> 3;
    float mfA[4], mfB[4];
#pragma unroll
    for (int reg = 0; reg < 4; ++reg) {
        int r = w * 16 + lg * 4 + reg;
        float MA = -1e30f, MB = -1e30f;
        for (int c1 = 0; c1 < nch1; ++c1) {
            MA = fmaxf(MA, mm[((size_t)(h0 * 32 + qb) * 4 + c1) * 64 + r]);
            MB = fmaxf(MB, mm[((size_t)(h1 * 32 + qb) * 4 + c1) * 64 + r]);
        }
        mfA[reg] = MA; mfB[reg] = MB;
    }

    const signed char* kbase = k_i8 + (size_t)hp * (SEQ * 128);
    const float* skb = sk + (size_t)hp * SEQ;
    const unsigned short* vt = vtT + (size_t)hp * (SEQ * 128);

    auto issueV = [&](int kb) {
        unsigned short* vb = &vlds[kb & 1][0];
#pragma unroll
        for (int a = 0; a < 4; ++a) {
            int fv = a * 4 + w;                   // 16 fragments of 1KB
            ASYNC16(vt + (size_t)kb * 8192 + fv * 512 + l * 8, vb + fv * 512);
        }
    };
    auto issueK = [&](int kb) {
#pragma unroll
        for (int a = 0; a < 2; ++a) {
            int f = a * 4 + w;
            ASYNC16(kbase + ((size_t)(kb * 8 + f) << 10) + l * 16, klds + f * 1024);
        }
    };

    v4f accA[8], accB[8];
#pragma unroll
    for (int jd = 0; jd < 8; ++jd) {
        accA[jd] = (v4f){0.f, 0.f, 0.f, 0.f};
        accB[jd] = (v4f){0.f, 0.f, 0.f, 0.f};
    }
    float ztA[4] = {0.f, 0.f, 0.f, 0.f};
    float ztB[4] = {0.f, 0.f, 0.f, 0.f};

    issueV(kb0);
    issueK(kb0);
    asm volatile("s_waitcnt vmcnt(0)" ::: "memory");
    __syncthreads();
    for (int kb = kb0; kb < kb1; ++kb) {
        int k0 = kb * 64;
        v4i ka[8];
#pragma unroll
        for (int f = 0; f < 8; ++f)
            ka[f] = *(const v4i*)(klds + f * 1024 + l * 16);
        float skc[4];
#pragma unroll
        for (int j = 0; j < 4; ++j) skc[j] = skb[k0 + j * 16 + lrow];
        __syncthreads();        // all waves' klds reads drained -> safe to refill
        if (kb + 1 < kb1) {
            issueV(kb + 1);
            issueK(kb + 1);
        }
        v4i sciA[4], sciB[4];
#pragma unroll
        for (int j = 0; j < 4; ++j) {
            v4i z = {0, 0, 0, 0};
            v4i tA = __builtin_amdgcn_mfma_i32_16x16x64_i8(qfA0, ka[j * 2], z, 0, 0, 0);
            sciA[j] = __builtin_amdgcn_mfma_i32_16x16x64_i8(qfA1, ka[j * 2 + 1], tA, 0, 0, 0);
            v4i tB = __builtin_amdgcn_mfma_i32_16x16x64_i8(qfB0, ka[j * 2], z, 0, 0, 0);
            sciB[j] = __builtin_amdgcn_mfma_i32_16x16x64_i8(qfB1, ka[j * 2 + 1], tB, 0, 0, 0);
        }
        // softmax A -> plds -> regs; then B reuses the same wave-private region
#pragma unroll
        for (int reg = 0; reg < 4; ++reg) {
            int rq = lg * 4 + reg;
            int r = q0 + w * 16 + rq;
#pragma unroll
            for (int j = 0; j < 4; ++j) {
                int cc = j * 16 + lrow;
                float pd = 0.f;
                if (k0 + cc <= r) {
                    float sv = ((float)sciA[j][reg] * (sqrA[reg] * skc[j])) * SM_SCALE;
                    float e = __expf(sv - mfA[reg]);
                    ztA[reg] += e;
                    pd = fminf(rintf(127.0f * e), 127.f);
                }
                plds[(w * 2 + (cc >> 5)) * 512 + (rq + 16 * ((cc >> 3) & 3)) * 8 + (cc & 7)] =
                    f2h_bits(pd);
            }
        }
        v8h pfA0 = *(const v8h*)(plds + (w * 2 + 0) * 512 + l * 8);
        v8h pfA1 = *(const v8h*)(plds + (w * 2 + 1) * 512 + l * 8);
#pragma unroll
        for (int reg = 0; reg < 4; ++reg) {
            int rq = lg * 4 + reg;
            int r = q0 + w * 16 + rq;
#pragma unroll
            for (int j = 0; j < 4; ++j) {
                int cc = j * 16 + lrow;
                float pd = 0.f;
                if (k0 + cc <= r) {
                    float sv = ((float)sciB[j][reg] * (sqrB[reg] * skc[j])) * SM_SCALE;
                    float e = __expf(sv - mfB[reg]);
                    ztB[reg] += e;
                    pd = fminf(rintf(127.0f * e), 127.f);
                }
                plds[(w * 2 + (cc >> 5)) * 512 + (rq + 16 * ((cc >> 3) & 3)) * 8 + (cc & 7)] =
                    f2h_bits(pd);
            }
        }
        v8h pfB0 = *(const v8h*)(plds + (w * 2 + 0) * 512 + l * 8);
        v8h pfB1 = *(const v8h*)(plds + (w * 2 + 1) * 512 + l * 8);
        const unsigned short* vb = &vlds[kb & 1][0];
#pragma unroll
        for (int jd = 0; jd < 8; ++jd) {
            v8h vh0 = *(const v8h*)(vb + (jd * 2 + 0) * 512 + l * 8);
            v8h vh1 = *(const v8h*)(vb + (jd * 2 + 1) * 512 + l * 8);
            v4f tA = accA[jd];
            tA = __builtin_amdgcn_mfma_f32_16x16x32_f16(pfA0, vh0, tA, 0, 0, 0);
            tA = __builtin_amdgcn_mfma_f32_16x16x32_f16(pfA1, vh1, tA, 0, 0, 0);
            accA[jd] = tA;
            v4f tB = accB[jd];
            tB = __builtin_amdgcn_mfma_f32_16x16x32_f16(pfB0, vh0, tB, 0, 0, 0);
            tB = __builtin_amdgcn_mfma_f32_16x16x32_f16(pfB1, vh1, tB, 0, 0, 0);
            accB[jd] = tB;
        }
        asm volatile("s_waitcnt vmcnt(0)" ::: "memory");
        __syncthreads();
    }
#pragma unroll
    for (int reg = 0; reg < 4; ++reg) {
#pragma unroll
        for (int mask = 1; mask <= 8; mask <<= 1) {
            ztA[reg] += __shfl_xor(ztA[reg], mask);
            ztB[reg] += __shfl_xor(ztB[reg], mask);
        }
    }
    if (qb < 16) {
        float spA[4], spB[4];
#pragma unroll
        for (int reg = 0; reg < 4; ++reg) {
            spA[reg] = fmaxf((1.0f / ztA[reg]) / 127.0f, 1e-8f);
            spB[reg] = fmaxf((1.0f / ztB[reg]) / 127.0f, 1e-8f);
        }
#pragma unroll
        for (int jd = 0; jd < 8; ++jd)
#pragma unroll
            for (int reg = 0; reg < 4; ++reg) {
                int r = q0 + w * 16 + lg * 4 + reg;
                attn2[(size_t)r * DMODEL + h0 * HDIM + jd * 16 + lrow] = accA[jd][reg] * spA[reg];
                attn2[(size_t)r * DMODEL + h1 * HDIM + jd * 16 + lrow] = accB[jd][reg] * spB[reg];
            }
    } else {
        if (c == 0) {
#pragma unroll
            for (int jd = 0; jd < 8; ++jd)
#pragma unroll
                for (int reg = 0; reg < 4; ++reg) {
                    int r = q0 + w * 16 + lg * 4 + reg;
                    attn2[(size_t)r * DMODEL + h0 * HDIM + jd * 16 + lrow] = accA[jd][reg];
                    attn2[(size_t)r * DMODEL + h1 * HDIM + jd * 16 + lrow] = accB[jd][reg];
                }
        } else {
#pragma unroll
            for (int jd = 0; jd < 8; ++jd)
#pragma unroll
                for (int reg = 0; reg < 4; ++reg) {
                    int rr = w * 16 + lg * 4 + reg;
                    pp[(((size_t)h0 * 16 + (qb - 16)) * 64 + rr) * 128 + jd * 16 + lrow] = accA[jd][reg];
                    pp[(((size_t)h1 * 16 + (qb - 16)) * 64 + rr) * 128 + jd * 16 + lrow] = accB[jd][reg];
                }
        }
        if (lrow == 0) {
            size_t zA = (((size_t)h0 * 16 + (qb - 16)) * 2 + c) * 64;
            size_t zB = (((size_t)h1 * 16 + (qb - 16)) * 2 + c) * 64;
#pragma unroll
            for (int reg = 0; reg < 4; ++reg) {
                zb[zA + w * 16 + lg * 4 + reg] = ztA[reg];
                zb[zB + w * 16 + lg * 4 + reg] = ztB[reg];
            }
        }
    }
}

// ---------------- reduce: out = (chunk0 + chunk1) * spv(Z0+Z1), tiles qb>=16 ----------------
__global__ __launch_bounds__(256) void attn_red_k(float* __restrict__ attn2,
        const float* __restrict__ pp, const float* __restrict__ zb) {
    int t16 = blockIdx.x, h = blockIdx.y;
    int qb = t16 + 16;
    int tid = threadIdx.x;
    for (int e = tid; e < 2048; e += 256) {
        int i = (e * 4) >> 7, j = (e * 4) & 127;
        float z0 = zb[(((size_t)h * 16 + t16) * 2 + 0) * 64 + i];
        float z1 = zb[(((size_t)h * 16 + t16) * 2 + 1) * 64 + i];
        float zinv = 1.0f / (z0 + z1);
        float spv = fmaxf(zinv / 127.0f, 1e-8f);
        float4 p = *(const float4*)&pp[(((size_t)h * 16 + t16) * 64 + i) * 128 + j];
        float* d = &attn2[(size_t)(qb * 64 + i) * DMODEL + h * HDIM + j];
        float4 dv = *(float4*)d;
        dv.x = (dv.x + p.x) * spv; dv.y = (dv.y + p.y) * spv;
        dv.z = (dv.z + p.z) * spv; dv.w = (dv.w + p.w) * spv;
        *(float4*)d = dv;
    }
}

extern "C" void kernel_launch(void* const* d_in, const int* in_sizes, int n_in,
                              void* d_out, int out_size, void* d_ws, size_t ws_size,
                              hipStream_t stream) {
    (void)in_sizes; (void)n_in; (void)out_size; (void)ws_size;
    const float* hidden = (const float*)d_in[0];
    const float* Wq = (const float*)d_in[1];
    const float* Wk = (const float*)d_in[2];
    const float* Wv = (const float*)d_in[3];
    const float* Wo = (const float*)d_in[4];
    const float* qw = (const float*)d_in[5];
    const float* kw = (const float*)d_in[6];
    const int* pos = (const int*)d_in[7];
    float* out = (float*)d_out;
    char* ws = (char*)d_ws;

    const size_t MB = 1024 * 1024;
    signed char* x_i8  = (signed char*)(ws);            // contiguous 16MB tiled i8 block
    signed char* wq_i8 = (signed char*)(ws + 4 * MB);
    signed char* wo_i8 = (signed char*)(ws + 12 * MB);
    signed char* q_i8  = (signed char*)(ws + 16 * MB);  // 4 MB (attn-tiled)
    signed char* k_i8  = (signed char*)(ws + 20 * MB);  // 2 MB (attn-tiled)
    float* sx  = (float*)(ws + 22 * MB);                // contiguous scales
    float* swq = sx + 2048;
    float* swo = sx + 6144;
    float* sq  = sx + 8192;                             // 16*2048
    float* sk  = sq + NH * SEQ;                         // 8*2048
    float* sa  = sk + NKV * SEQ;                        // 2048
    float* inv_tab = sa + 2048;                         // 64
    float* ct  = (float*)(ws + 22 * MB + 512 * 1024);   // 512 KB
    float* st  = (float*)(ws + 22 * MB + 1024 * 1024);  // 512 KB
    float* qkv_lin = (float*)(ws + 24 * MB);            // 32 MB [S,4096]
    float* attn2 = (float*)(ws + 32 * MB);              // 16 MB (inside dead qkv_lin)
    float* pp    = (float*)(ws + 48 * MB);              // 8 MB (inside dead qkv_lin)
    unsigned short* vtT = (unsigned short*)(ws + 56 * MB); // 4 MB (disjoint from qkv_lin!)
    float* mm    = (float*)(ws + 60 * MB);              // 512 KB
    float* zb    = (float*)(ws + 60 * MB + 512 * 1024); // 128 KB
    signed char* a_i8 = x_i8;

    rope_init_k<<<1, 64, 0, stream>>>(inv_tab);
    rope_tab_k<<<2048, 64, 0, stream>>>(pos, inv_tab, ct, st);
    quant_all_k<<<512, 256, 0, stream>>>(hidden, Wq, Wk, Wv, Wo, x_i8, sx);

    gemm_i8_k<<<dim3(32, 16), 256, 0, stream>>>(x_i8, sx, wq_i8, swq, qkv_lin, 2048, 4096, 2048);

    qkv_post_k<<<2048, 256, 0, stream>>>(qkv_lin, qw, kw, ct, st, q_i8, sq, k_i8, sk);
    vt_split_k<<<dim3(32, 8), 256, 0, stream>>>(qkv_lin, vtT);

    attn_p1_k<<<dim3(128, 8), 256, 0, stream>>>(q_i8, sq, k_i8, sk, mm);
    attn_p2_k<<<dim3(64, 8), 256, 0, stream>>>(q_i8, sq, k_i8, sk, vtT, mm, attn2, pp, zb);
    attn_red_k<<<dim3(16, 16), 256, 0, stream>>>(attn2, pp, zb);

    row_quant_k<<<128, 256, 0, stream>>>(attn2, a_i8, sa, 2048);
    gemm_i8_k<<<dim3(16, 16), 256, 0, stream>>>(a_i8, sa, wo_i8, swo, out, 2048, 2048, 2048);
}

// Round 11
// 197.444 us; speedup vs baseline: 1.0756x; 1.0756x over previous
//
#include <hip/hip_runtime.h>
#include <math.h>

#define NH 16
#define NKV 8
#define HDIM 128
#define SEQ 2048
#define DMODEL 2048

typedef int   v4i __attribute__((ext_vector_type(4)));
typedef float v4f __attribute__((ext_vector_type(4)));
typedef _Float16 v8h __attribute__((ext_vector_type(8)));

static constexpr float SM_SCALE = 0.08838834764831843f; // 128**-0.5

#define GLOBP(p) (__attribute__((address_space(1))) void*)(p)
#define LDSP(p)  (__attribute__((address_space(3))) void*)(p)
#define ASYNC16(g, l) __builtin_amdgcn_global_load_lds(GLOBP(g), LDSP(l), 16, 0, 0)

// Fragment-tiled i8 layout for X[R][K] (R%16==0, K%64==0):
// frag (r>>4, k>>6) is 1024B; within: byte = ((k>>4)&3)*256 + (r&15)*16 + (k&15).

__device__ __forceinline__ unsigned short f2h_bits(float x) {
    _Float16 h = (_Float16)x;               // RN, exact for small ints
    return __builtin_bit_cast(unsigned short, h);
}

// ---------------- merged per-row int8 quant for all 5 inputs ----------------
__global__ __launch_bounds__(256) void quant_all_k(const float* __restrict__ hidden,
        const float* __restrict__ Wq, const float* __restrict__ Wk,
        const float* __restrict__ Wv, const float* __restrict__ Wo,
        signed char* __restrict__ out, float* __restrict__ scale) {
    int p = blockIdx.x;               // 16-row panel index, 512 total
    int row0g = p * 16;
    const float* in; int lr0;
    if (row0g < 2048)      { in = hidden; lr0 = row0g; }
    else if (row0g < 4096) { in = Wq; lr0 = row0g - 2048; }
    else if (row0g < 5120) { in = Wk; lr0 = row0g - 4096; }
    else if (row0g < 6144) { in = Wv; lr0 = row0g - 5120; }
    else                   { in = Wo; lr0 = row0g - 6144; }
    const int cols = 2048;
    int tid = threadIdx.x;
    __shared__ float srow[16];
    int r = tid >> 4, l16 = tid & 15;
    const float4* x4 = (const float4*)(in + (size_t)(lr0 + r) * cols);
    float amax = 0.f;
    for (int c4 = l16; c4 < (cols >> 2); c4 += 16) {
        float4 v = x4[c4];
        amax = fmaxf(amax, fmaxf(fmaxf(fabsf(v.x), fabsf(v.y)),
                                 fmaxf(fabsf(v.z), fabsf(v.w))));
    }
#pragma unroll
    for (int m = 1; m <= 8; m <<= 1) amax = fmaxf(amax, __shfl_xor(amax, m));
    if (l16 == 0) {
        float s = fmaxf(amax / 127.0f, 1e-8f);
        srow[r] = s;
        scale[row0g + r] = s;
    }
    __syncthreads();
    int total = (cols >> 4) * 16;
    size_t obase = (size_t)p * 32768;
    for (int idx = tid; idx < total; idx += 256) {
        int f = idx >> 6, q = (idx >> 4) & 3, rr = idx & 15;
        const float* src = in + (size_t)(lr0 + rr) * cols + f * 64 + q * 16;
        float s = srow[rr];
        unsigned int wds[4];
#pragma unroll
        for (int g = 0; g < 4; ++g) {
            float4 v = *(const float4*)(src + g * 4);
            int b0 = (int)fminf(fmaxf(rintf(v.x / s), -127.f), 127.f);
            int b1 = (int)fminf(fmaxf(rintf(v.y / s), -127.f), 127.f);
            int b2 = (int)fminf(fmaxf(rintf(v.z / s), -127.f), 127.f);
            int b3 = (int)fminf(fmaxf(rintf(v.w / s), -127.f), 127.f);
            wds[g] = (b0 & 255) | ((b1 & 255) << 8) | ((b2 & 255) << 16) | ((b3 & 255) << 24);
        }
        *(uint4*)(out + obase + (size_t)idx * 16) =
            make_uint4(wds[0], wds[1], wds[2], wds[3]);
    }
}

// ---------------- single-tensor row quant (for attn2) ----------------
__global__ __launch_bounds__(256) void row_quant_k(const float* __restrict__ in,
        signed char* __restrict__ out, float* __restrict__ scale, int cols) {
    int row0 = blockIdx.x * 16;
    int tid = threadIdx.x;
    __shared__ float srow[16];
    int r = tid >> 4, l16 = tid & 15;
    const float4* x4 = (const float4*)(in + (size_t)(row0 + r) * cols);
    float amax = 0.f;
    for (int c4 = l16; c4 < (cols >> 2); c4 += 16) {
        float4 v = x4[c4];
        amax = fmaxf(amax, fmaxf(fmaxf(fabsf(v.x), fabsf(v.y)),
                                 fmaxf(fabsf(v.z), fabsf(v.w))));
    }
#pragma unroll
    for (int m = 1; m <= 8; m <<= 1) amax = fmaxf(amax, __shfl_xor(amax, m));
    if (l16 == 0) {
        float s = fmaxf(amax / 127.0f, 1e-8f);
        srow[r] = s;
        scale[row0 + r] = s;
    }
    __syncthreads();
    int total = (cols >> 4) * 16;
    size_t obase = ((size_t)(row0 >> 4) * (cols >> 6)) << 10;
    for (int idx = tid; idx < total; idx += 256) {
        int f = idx >> 6, q = (idx >> 4) & 3, rr = idx & 15;
        const float* src = in + (size_t)(row0 + rr) * cols + f * 64 + q * 16;
        float s = srow[rr];
        unsigned int wds[4];
#pragma unroll
        for (int g = 0; g < 4; ++g) {
            float4 v = *(const float4*)(src + g * 4);
            int b0 = (int)fminf(fmaxf(rintf(v.x / s), -127.f), 127.f);
            int b1 = (int)fminf(fmaxf(rintf(v.y / s), -127.f), 127.f);
            int b2 = (int)fminf(fmaxf(rintf(v.z / s), -127.f), 127.f);
            int b3 = (int)fminf(fmaxf(rintf(v.w / s), -127.f), 127.f);
            wds[g] = (b0 & 255) | ((b1 & 255) << 8) | ((b2 & 255) << 16) | ((b3 & 255) << 24);
        }
        *(uint4*)(out + obase + (size_t)idx * 16) =
            make_uint4(wds[0], wds[1], wds[2], wds[3]);
    }
}

// ---------------- int8 GEMM, triple-buffered LDS + counted vmcnt pipeline ----------------
__global__ __launch_bounds__(256, 3) void gemm_i8_k(const signed char* __restrict__ A,
        const float* __restrict__ sa, const signed char* __restrict__ B,
        const float* __restrict__ sb, float* __restrict__ C, int M, int N, int K) {
    __shared__ __align__(16) signed char lsA[3][8192];
    __shared__ __align__(16) signed char lsB[3][8192];
    int tid = threadIdx.x;
    int w = tid >> 6, l = tid & 63;
    int wr = w >> 1, wc = w & 1;
    int lrow = l & 15;
    int m0 = blockIdx.y * 128, n0 = blockIdx.x * 128;
    int kb6 = K >> 6;
    v4i acc[4][4];
#pragma unroll
    for (int i = 0; i < 4; ++i)
#pragma unroll
        for (int j = 0; j < 4; ++j) acc[i][j] = (v4i){0, 0, 0, 0};

    auto stage = [&](int buf, int k6) {   // 4 ASYNC16 per wave
#pragma unroll
        for (int a = 0; a < 2; ++a) {
            int f = a * 4 + w;
            ASYNC16(A + (((size_t)(((m0 >> 4) + f) * kb6 + k6)) << 10) + l * 16,
                    lsA[buf] + f * 1024);
            ASYNC16(B + (((size_t)(((n0 >> 4) + f) * kb6 + k6)) << 10) + l * 16,
                    lsB[buf] + f * 1024);
        }
    };

    stage(0, 0);
    if (kb6 > 1) {
        stage(1, 1);
        asm volatile("s_waitcnt vmcnt(4)" ::: "memory");
    } else {
        asm volatile("s_waitcnt vmcnt(0)" ::: "memory");
    }
    __builtin_amdgcn_s_barrier();
    for (int t = 0; t < kb6; ++t) {
        if (t + 2 < kb6) stage((t + 2) % 3, t + 2);
        int cur = t % 3;
        v4i af[4], bf[4];
#pragma unroll
        for (int i = 0; i < 4; ++i) af[i] = *(const v4i*)(lsA[cur] + (wr * 4 + i) * 1024 + l * 16);
#pragma unroll
        for (int j = 0; j < 4; ++j) bf[j] = *(const v4i*)(lsB[cur] + (wc * 4 + j) * 1024 + l * 16);
#pragma unroll
        for (int i = 0; i < 4; ++i)
#pragma unroll
            for (int j = 0; j < 4; ++j)
                acc[i][j] = __builtin_amdgcn_mfma_i32_16x16x64_i8(af[i], bf[j], acc[i][j], 0, 0, 0);
        if (t + 2 < kb6) asm volatile("s_waitcnt vmcnt(4)" ::: "memory");
        else             asm volatile("s_waitcnt vmcnt(0)" ::: "memory");
        __builtin_amdgcn_s_barrier();
    }
    int r0 = m0 + wr * 64, c0 = n0 + wc * 64;
    int lg = l >> 4;
    float sbv[4];
#pragma unroll
    for (int j = 0; j < 4; ++j) sbv[j] = sb[c0 + j * 16 + lrow];
#pragma unroll
    for (int i = 0; i < 4; ++i) {
        float4 s4 = *(const float4*)(sa + r0 + i * 16 + lg * 4);
        float sav[4] = {s4.x, s4.y, s4.z, s4.w};
#pragma unroll
        for (int j = 0; j < 4; ++j) {
#pragma unroll
            for (int reg = 0; reg < 4; ++reg) {
                int rr = r0 + i * 16 + lg * 4 + reg;
                C[(size_t)rr * N + c0 + j * 16 + lrow] = (float)acc[i][j][reg] * (sav[reg] * sbv[j]);
            }
        }
    }
}

// ---------------- rope tables ----------------
__global__ void rope_init_k(float* __restrict__ inv_tab) {
    int i = threadIdx.x; // 64
    inv_tab[i] = 1.0f / (float)pow(1.0e6, (double)i / 64.0);
}
__global__ void rope_tab_k(const int* __restrict__ pos_ids, const float* __restrict__ inv_tab,
                           float* __restrict__ ct, float* __restrict__ st) {
    int t = blockIdx.x;
    int fi = threadIdx.x; // 64
    float fr = (float)pos_ids[t] * inv_tab[fi];
    float sn, c;
    sincosf(fr, &sn, &c);
    ct[t * 64 + fi] = c;
    st[t * 64 + fi] = sn;
}

// ---------------- fused rmsnorm+rope+quant for q,k only ----------
__global__ __launch_bounds__(256) void qkv_post_k(const float* __restrict__ qkv_lin,
        const float* __restrict__ qw, const float* __restrict__ kw,
        const float* __restrict__ ct, const float* __restrict__ st,
        signed char* __restrict__ q_i8, float* __restrict__ sq,
        signed char* __restrict__ k_i8, float* __restrict__ sk) {
    int t = blockIdx.x;
    int wv = threadIdx.x >> 6, l = threadIdx.x & 63;
    const float* row = qkv_lin + (size_t)t * 4096;
    float cth = ct[t * 64 + l];
    float sth = st[t * 64 + l];
    size_t ta0 = (size_t)(((t >> 4) * 2) << 10)
               + (size_t)((((l >> 4) & 3) << 8) + ((t & 15) << 4) + (l & 15));
    for (int slot = wv; slot < 24; slot += 4) {
        float x0 = row[slot * 128 + l];
        float x1 = row[slot * 128 + l + 64];
        float ss = x0 * x0 + x1 * x1;
#pragma unroll
        for (int m = 1; m <= 32; m <<= 1) ss += __shfl_xor(ss, m);
        float rs = 1.0f / sqrtf(ss / 128.0f + 1e-6f);
        const float* wn = (slot < 16) ? qw : kw;
        x0 = (x0 * rs) * wn[l];
        x1 = (x1 * rs) * wn[l + 64];
        float nx0 = x0 * cth - x1 * sth;
        float nx1 = x1 * cth + x0 * sth;
        x0 = nx0; x1 = nx1;
        float amax = fmaxf(fabsf(x0), fabsf(x1));
#pragma unroll
        for (int m = 1; m <= 32; m <<= 1) amax = fmaxf(amax, __shfl_xor(amax, m));
        float s = fmaxf(amax / 127.0f, 1e-8f);
        float q0 = fminf(fmaxf(rintf(x0 / s), -127.f), 127.f);
        float q1 = fminf(fmaxf(rintf(x1 / s), -127.f), 127.f);
        if (slot < 16) {
            signed char* dst = q_i8 + (size_t)slot * (SEQ * 128);
            dst[ta0] = (signed char)(int)q0;
            dst[ta0 + 1024] = (signed char)(int)q1;
            if (l == 0) sq[slot * SEQ + t] = s;
        } else {
            signed char* dst = k_i8 + (size_t)(slot - 16) * (SEQ * 128);
            dst[ta0] = (signed char)(int)q0;
            dst[ta0 + 1024] = (signed char)(int)q1;
            if (l == 0) sk[(slot - 16) * SEQ + t] = s;
        }
    }
}

// ---------------- V: per-token quant + dequant + fp16 + transpose to tiled vtT ----
__global__ __launch_bounds__(256) void vt_split_k(const float* __restrict__ qkv_lin,
        unsigned short* __restrict__ vtT) {
    int kv = blockIdx.y, kb = blockIdx.x;
    int t0 = kb * 64;
    __shared__ float tile[64][132];
    __shared__ float srow[64];
    int tid = threadIdx.x;
    const float* src = qkv_lin + (size_t)t0 * 4096 + 3072 + kv * 128;
#pragma unroll
    for (int i = 0; i < 8; ++i) {
        int f4 = i * 256 + tid;
        int r = f4 >> 5, c = (f4 & 31) << 2;
        float4 v = *(const float4*)(src + (size_t)r * 4096 + c);
        tile[r][c] = v.x; tile[r][c + 1] = v.y; tile[r][c + 2] = v.z; tile[r][c + 3] = v.w;
    }
    __syncthreads();
    {
        int r = tid >> 2, qq = tid & 3;
        float amax = 0.f;
#pragma unroll
        for (int e = 0; e < 32; ++e) amax = fmaxf(amax, fabsf(tile[r][qq * 32 + e]));
        amax = fmaxf(amax, __shfl_xor(amax, 1));
        amax = fmaxf(amax, __shfl_xor(amax, 2));
        if (qq == 0) srow[r] = fmaxf(amax / 127.0f, 1e-8f);
    }
    __syncthreads();
    int d = tid >> 1, th = (tid & 1) * 32;
    size_t base = (size_t)kv * (SEQ * 128);
#pragma unroll
    for (int j = 0; j < 32; j += 2) {
        int tl = th + j;
        float s0 = srow[tl], s1 = srow[tl + 1];
        float a = fminf(fmaxf(rintf(tile[tl][d] / s0), -127.f), 127.f) * s0;
        float b = fminf(fmaxf(rintf(tile[tl + 1][d] / s1), -127.f), 127.f) * s1;
        unsigned int ua = f2h_bits(a), ub = f2h_bits(b);
        int off = kb * 8192 + ((d >> 4) * 2 + ((tl >> 5) & 1)) * 512
                + (((d & 15) + (((tl >> 3) & 3) << 4)) << 3) + (tl & 7);
        *(unsigned int*)(vtT + base + off) = ua | (ub << 16);
    }
}

// ---------------- attention pass 1: GQA-paired, row MAX only ----------------
__global__ __launch_bounds__(256, 4) void attn_p1_k(const signed char* __restrict__ q_i8,
        const float* __restrict__ sq, const signed char* __restrict__ k_i8,
        const float* __restrict__ sk, float* __restrict__ mm) {
    int bx = blockIdx.x, hp = blockIdx.y;
    int qb = 31 - (bx >> 2), c = bx & 3;
    int nch = (qb + 8) >> 3;
    if (c >= nch) return;
    int q0 = qb * 64;
    int kb0 = c * 8, kb1 = min((c + 1) * 8, qb + 1);
    int tid = threadIdx.x, w = tid >> 6, l = tid & 63;
    int lrow = l & 15, lg = l >> 4;
    int h0 = hp * 2, h1 = h0 + 1;

    const signed char* qtA = q_i8 + (size_t)h0 * (SEQ * 128)
                           + ((size_t)((((q0 >> 4) + w) * 2)) << 10) + l * 16;
    const signed char* qtB = qtA + (size_t)(SEQ * 128);
    v4i qfA0 = *(const v4i*)(qtA), qfA1 = *(const v4i*)(qtA + 1024);
    v4i qfB0 = *(const v4i*)(qtB), qfB1 = *(const v4i*)(qtB + 1024);
    float4 sA = *(const float4*)(sq + (size_t)h0 * SEQ + q0 + w * 16 + lg * 4);
    float4 sB = *(const float4*)(sq + (size_t)h1 * SEQ + q0 + w * 16 + lg * 4);
    float sqrA[4] = {sA.x, sA.y, sA.z, sA.w};
    float sqrB[4] = {sB.x, sB.y, sB.z, sB.w};
    const signed char* kbase = k_i8 + (size_t)hp * (SEQ * 128);
    const float* skb = sk + (size_t)hp * SEQ;

    float mA[4], mB[4];
#pragma unroll
    for (int r = 0; r < 4; ++r) { mA[r] = -1e30f; mB[r] = -1e30f; }

    v4i ka[8], kn[8];
    float skc[4], skn[4];
    auto loadK = [&](v4i* dst, float* sdst, int k0) {
#pragma unroll
        for (int f = 0; f < 8; ++f)
            dst[f] = *(const v4i*)(kbase + ((size_t)((k0 >> 4) * 2 + f) << 10) + l * 16);
#pragma unroll
        for (int j = 0; j < 4; ++j) sdst[j] = skb[k0 + j * 16 + lrow];
    };

    loadK(ka, skc, kb0 * 64);
    for (int kb = kb0; kb < kb1; ++kb) {
        if (kb + 1 < kb1) loadK(kn, skn, (kb + 1) * 64);
        int k0 = kb * 64;
        v4i sciA[4], sciB[4];
#pragma unroll
        for (int j = 0; j < 4; ++j) {
            v4i z = {0, 0, 0, 0};
            v4i tA = __builtin_amdgcn_mfma_i32_16x16x64_i8(qfA0, ka[j * 2], z, 0, 0, 0);
            sciA[j] = __builtin_amdgcn_mfma_i32_16x16x64_i8(qfA1, ka[j * 2 + 1], tA, 0, 0, 0);
            v4i tB = __builtin_amdgcn_mfma_i32_16x16x64_i8(qfB0, ka[j * 2], z, 0, 0, 0);
            sciB[j] = __builtin_amdgcn_mfma_i32_16x16x64_i8(qfB1, ka[j * 2 + 1], tB, 0, 0, 0);
        }
#pragma unroll
        for (int reg = 0; reg < 4; ++reg) {
            int r = q0 + w * 16 + lg * 4 + reg;
#pragma unroll
            for (int j = 0; j < 4; ++j) {
                bool ok = (k0 + j * 16 + lrow <= r);
                float ss = skc[j] * SM_SCALE;
                float svA = ((float)sciA[j][reg] * sqrA[reg]) * ss;
                float svB = ((float)sciB[j][reg] * sqrB[reg]) * ss;
                mA[reg] = fmaxf(mA[reg], ok ? svA : -1e30f);
                mB[reg] = fmaxf(mB[reg], ok ? svB : -1e30f);
            }
        }
        if (kb + 1 < kb1) {
#pragma unroll
            for (int f = 0; f < 8; ++f) ka[f] = kn[f];
#pragma unroll
            for (int j = 0; j < 4; ++j) skc[j] = skn[j];
        }
    }
#pragma unroll
    for (int reg = 0; reg < 4; ++reg) {
#pragma unroll
        for (int mask = 1; mask <= 8; mask <<= 1) {
            mA[reg] = fmaxf(mA[reg], __shfl_xor(mA[reg], mask));
            mB[reg] = fmaxf(mB[reg], __shfl_xor(mB[reg], mask));
        }
    }
    if (lrow == 0) {
        size_t bA = ((size_t)(h0 * 32 + qb) * 4 + c) * 64;
        size_t bB = ((size_t)(h1 * 32 + qb) * 4 + c) * 64;
#pragma unroll
        for (int reg = 0; reg < 4; ++reg) {
            mm[bA + w * 16 + lg * 4 + reg] = mA[reg];
            mm[bB + w * 16 + lg * 4 + reg] = mB[reg];
        }
    }
}

// ---------------- attention pass 2: GQA-paired, counted-vmcnt deep pipeline ----------------
// LDS: V 3x16K + K 2x8K + plds 8K + slds 4K = 76KB -> 2 blocks/CU.
// Per tile vmem: 4 V + 2 K ASYNC16. Loop never drains vmcnt to 0.
__global__ __launch_bounds__(256, 2) void attn_p2_k(const signed char* __restrict__ q_i8,
        const float* __restrict__ sq, const signed char* __restrict__ k_i8,
        const float* __restrict__ sk, const unsigned short* __restrict__ vtT,
        const float* __restrict__ mm, float* __restrict__ attn2, float* __restrict__ pp,
        float* __restrict__ zb) {
    __shared__ __align__(16) unsigned short vlds[3][8192];  // 48 KB
    __shared__ __align__(16) signed char klds[2][8192];     // 16 KB
    __shared__ __align__(16) unsigned short plds[4096];     // 8 KB wave-private (A then B)
    __shared__ __align__(16) float slds[1024];              // 4 KB chunk K-scales
    int bx = blockIdx.x, hp = blockIdx.y;
    int qb = 31 - (bx >> 1), c = bx & 1;
    int nch2 = (qb >= 16) ? 2 : 1;
    if (c >= nch2) return;
    int q0 = qb * 64;
    int kb0 = c * 16, kb1 = min((c + 1) * 16, qb + 1);
    int tid = threadIdx.x, w = tid >> 6, l = tid & 63;
    int lrow = l & 15, lg = l >> 4;
    int h0 = hp * 2, h1 = h0 + 1;

    const signed char* qtA = q_i8 + (size_t)h0 * (SEQ * 128)
                           + ((size_t)((((q0 >> 4) + w) * 2)) << 10) + l * 16;
    const signed char* qtB = qtA + (size_t)(SEQ * 128);
    v4i qfA0 = *(const v4i*)(qtA), qfA1 = *(const v4i*)(qtA + 1024);
    v4i qfB0 = *(const v4i*)(qtB), qfB1 = *(const v4i*)(qtB + 1024);
    float4 sA = *(const float4*)(sq + (size_t)h0 * SEQ + q0 + w * 16 + lg * 4);
    float4 sB = *(const float4*)(sq + (size_t)h1 * SEQ + q0 + w * 16 + lg * 4);
    float sqrA[4] = {sA.x, sA.y, sA.z, sA.w};
    float sqrB[4] = {sB.x, sB.y, sB.z, sB.w};

    int nch1 = (qb + 8) >> 3;
    float mfA[4], mfB[4];
#pragma unroll
    for (int reg = 0; reg < 4; ++reg) {
        int r = w * 16 + lg * 4 + reg;
        float MA = -1e30f, MB = -1e30f;
        for (int c1 = 0; c1 < nch1; ++c1) {
            MA = fmaxf(MA, mm[((size_t)(h0 * 32 + qb) * 4 + c1) * 64 + r]);
            MB = fmaxf(MB, mm[((size_t)(h1 * 32 + qb) * 4 + c1) * 64 + r]);
        }
        mfA[reg] = MA; mfB[reg] = MB;
    }

    const signed char* kbase = k_i8 + (size_t)hp * (SEQ * 128);
    const float* skb = sk + (size_t)hp * SEQ;
    const unsigned short* vt = vtT + (size_t)hp * (SEQ * 128);

    auto issueV = [&](int kb) {     // 4 ASYNC16 / wave
        unsigned short* vb = &vlds[kb % 3][0];
#pragma unroll
        for (int a = 0; a < 4; ++a) {
            int fv = a * 4 + w;
            ASYNC16(vt + (size_t)kb * 8192 + fv * 512 + l * 8, vb + fv * 512);
        }
    };
    auto issueK = [&](int kb) {     // 2 ASYNC16 / wave
        signed char* kbuf = &klds[kb & 1][0];
#pragma unroll
        for (int a = 0; a < 2; ++a) {
            int f = a * 4 + w;
            ASYNC16(kbase + ((size_t)(kb * 8 + f) << 10) + l * 16, kbuf + f * 1024);
        }
    };

    v4f accA[8], accB[8];
#pragma unroll
    for (int jd = 0; jd < 8; ++jd) {
        accA[jd] = (v4f){0.f, 0.f, 0.f, 0.f};
        accB[jd] = (v4f){0.f, 0.f, 0.f, 0.f};
    }
    float ztA[4] = {0.f, 0.f, 0.f, 0.f};
    float ztB[4] = {0.f, 0.f, 0.f, 0.f};

    // prologue: K-scales for whole chunk (1 op), K(kb0) (2), V(kb0) (4), V(kb0+1) (4)
    ASYNC16(skb + kb0 * 64 + w * 256 + l * 4, (char*)slds + w * 1024);
    issueK(kb0);
    issueV(kb0);
    if (kb0 + 1 < kb1) {
        issueV(kb0 + 1);
        asm volatile("s_waitcnt vmcnt(4)" ::: "memory");    // slds, K0, V0 done
    } else {
        asm volatile("s_waitcnt vmcnt(0)" ::: "memory");
    }
    __builtin_amdgcn_s_barrier();

    for (int kb = kb0; kb < kb1; ++kb) {
        int k0 = kb * 64;
        if (kb + 1 < kb1) issueK(kb + 1);
        if (kb + 2 < kb1) issueV(kb + 2);
        v4i ka[8];
#pragma unroll
        for (int f = 0; f < 8; ++f)
            ka[f] = *(const v4i*)(&klds[kb & 1][0] + f * 1024 + l * 16);
        float skc[4];
#pragma unroll
        for (int j = 0; j < 4; ++j) skc[j] = slds[(kb - kb0) * 64 + j * 16 + lrow];
        v4i sciA[4], sciB[4];
#pragma unroll
        for (int j = 0; j < 4; ++j) {
            v4i z = {0, 0, 0, 0};
            v4i tA = __builtin_amdgcn_mfma_i32_16x16x64_i8(qfA0, ka[j * 2], z, 0, 0, 0);
            sciA[j] = __builtin_amdgcn_mfma_i32_16x16x64_i8(qfA1, ka[j * 2 + 1], tA, 0, 0, 0);
            v4i tB = __builtin_amdgcn_mfma_i32_16x16x64_i8(qfB0, ka[j * 2], z, 0, 0, 0);
            sciB[j] = __builtin_amdgcn_mfma_i32_16x16x64_i8(qfB1, ka[j * 2 + 1], tB, 0, 0, 0);
        }
        // softmax A -> plds -> regs; then B reuses the same wave-private region
#pragma unroll
        for (int reg = 0; reg < 4; ++reg) {
            int rq = lg * 4 + reg;
            int r = q0 + w * 16 + rq;
#pragma unroll
            for (int j = 0; j < 4; ++j) {
                int cc = j * 16 + lrow;
                float pd = 0.f;
                if (k0 + cc <= r) {
                    float sv = ((float)sciA[j][reg] * (sqrA[reg] * skc[j])) * SM_SCALE;
                    float e = __expf(sv - mfA[reg]);
                    ztA[reg] += e;
                    pd = fminf(rintf(127.0f * e), 127.f);
                }
                plds[(w * 2 + (cc >> 5)) * 512 + (rq + 16 * ((cc >> 3) & 3)) * 8 + (cc & 7)] =
                    f2h_bits(pd);
            }
        }
        v8h pfA0 = *(const v8h*)(plds + (w * 2 + 0) * 512 + l * 8);
        v8h pfA1 = *(const v8h*)(plds + (w * 2 + 1) * 512 + l * 8);
#pragma unroll
        for (int reg = 0; reg < 4; ++reg) {
            int rq = lg * 4 + reg;
            int r = q0 + w * 16 + rq;
#pragma unroll
            for (int j = 0; j < 4; ++j) {
                int cc = j * 16 + lrow;
                float pd = 0.f;
                if (k0 + cc <= r) {
                    float sv = ((float)sciB[j][reg] * (sqrB[reg] * skc[j])) * SM_SCALE;
                    float e = __expf(sv - mfB[reg]);
                    ztB[reg] += e;
                    pd = fminf(rintf(127.0f * e), 127.f);
                }
                plds[(w * 2 + (cc >> 5)) * 512 + (rq + 16 * ((cc >> 3) & 3)) * 8 + (cc & 7)] =
                    f2h_bits(pd);
            }
        }
        v8h pfB0 = *(const v8h*)(plds + (w * 2 + 0) * 512 + l * 8);
        v8h pfB1 = *(const v8h*)(plds + (w * 2 + 1) * 512 + l * 8);
        const unsigned short* vb = &vlds[kb % 3][0];
#pragma unroll
        for (int jd = 0; jd < 8; ++jd) {
            v8h vh0 = *(const v8h*)(vb + (jd * 2 + 0) * 512 + l * 8);
            v8h vh1 = *(const v8h*)(vb + (jd * 2 + 1) * 512 + l * 8);
            v4f tA = accA[jd];
            tA = __builtin_amdgcn_mfma_f32_16x16x32_f16(pfA0, vh0, tA, 0, 0, 0);
            tA = __builtin_amdgcn_mfma_f32_16x16x32_f16(pfA1, vh1, tA, 0, 0, 0);
            accA[jd] = tA;
            v4f tB = accB[jd];
            tB = __builtin_amdgcn_mfma_f32_16x16x32_f16(pfB0, vh0, tB, 0, 0, 0);
            tB = __builtin_amdgcn_mfma_f32_16x16x32_f16(pfB1, vh1, tB, 0, 0, 0);
            accB[jd] = tB;
        }
        // counted wait: newest 4 = V(kb+2); K(kb+1) and V(kb+1) forced complete
        if (kb + 2 < kb1) asm volatile("s_waitcnt vmcnt(4)" ::: "memory");
        else              asm volatile("s_waitcnt vmcnt(0)" ::: "memory");
        __builtin_amdgcn_s_barrier();
    }
#pragma unroll
    for (int reg = 0; reg < 4; ++reg) {
#pragma unroll
        for (int mask = 1; mask <= 8; mask <<= 1) {
            ztA[reg] += __shfl_xor(ztA[reg], mask);
            ztB[reg] += __shfl_xor(ztB[reg], mask);
        }
    }
    if (qb < 16) {
        float spA[4], spB[4];
#pragma unroll
        for (int reg = 0; reg < 4; ++reg) {
            spA[reg] = fmaxf((1.0f / ztA[reg]) / 127.0f, 1e-8f);
            spB[reg] = fmaxf((1.0f / ztB[reg]) / 127.0f, 1e-8f);
        }
#pragma unroll
        for (int jd = 0; jd < 8; ++jd)
#pragma unroll
            for (int reg = 0; reg < 4; ++reg) {
                int r = q0 + w * 16 + lg * 4 + reg;
                attn2[(size_t)r * DMODEL + h0 * HDIM + jd * 16 + lrow] = accA[jd][reg] * spA[reg];
                attn2[(size_t)r * DMODEL + h1 * HDIM + jd * 16 + lrow] = accB[jd][reg] * spB[reg];
            }
    } else {
        if (c == 0) {
#pragma unroll
            for (int jd = 0; jd < 8; ++jd)
#pragma unroll
                for (int reg = 0; reg < 4; ++reg) {
                    int r = q0 + w * 16 + lg * 4 + reg;
                    attn2[(size_t)r * DMODEL + h0 * HDIM + jd * 16 + lrow] = accA[jd][reg];
                    attn2[(size_t)r * DMODEL + h1 * HDIM + jd * 16 + lrow] = accB[jd][reg];
                }
        } else {
#pragma unroll
            for (int jd = 0; jd < 8; ++jd)
#pragma unroll
                for (int reg = 0; reg < 4; ++reg) {
                    int rr = w * 16 + lg * 4 + reg;
                    pp[(((size_t)h0 * 16 + (qb - 16)) * 64 + rr) * 128 + jd * 16 + lrow] = accA[jd][reg];
                    pp[(((size_t)h1 * 16 + (qb - 16)) * 64 + rr) * 128 + jd * 16 + lrow] = accB[jd][reg];
                }
        }
        if (lrow == 0) {
            size_t zA = (((size_t)h0 * 16 + (qb - 16)) * 2 + c) * 64;
            size_t zB = (((size_t)h1 * 16 + (qb - 16)) * 2 + c) * 64;
#pragma unroll
            for (int reg = 0; reg < 4; ++reg) {
                zb[zA + w * 16 + lg * 4 + reg] = ztA[reg];
                zb[zB + w * 16 + lg * 4 + reg] = ztB[reg];
            }
        }
    }
}

// ---------------- reduce: out = (chunk0 + chunk1) * spv(Z0+Z1), tiles qb>=16 ----------------
__global__ __launch_bounds__(256) void attn_red_k(float* __restrict__ attn2,
        const float* __restrict__ pp, const float* __restrict__ zb) {
    int t16 = blockIdx.x, h = blockIdx.y;
    int qb = t16 + 16;
    int tid = threadIdx.x;
    for (int e = tid; e < 2048; e += 256) {
        int i = (e * 4) >> 7, j = (e * 4) & 127;
        float z0 = zb[(((size_t)h * 16 + t16) * 2 + 0) * 64 + i];
        float z1 = zb[(((size_t)h * 16 + t16) * 2 + 1) * 64 + i];
        float zinv = 1.0f / (z0 + z1);
        float spv = fmaxf(zinv / 127.0f, 1e-8f);
        float4 p = *(const float4*)&pp[(((size_t)h * 16 + t16) * 64 + i) * 128 + j];
        float* d = &attn2[(size_t)(qb * 64 + i) * DMODEL + h * HDIM + j];
        float4 dv = *(float4*)d;
        dv.x = (dv.x + p.x) * spv; dv.y = (dv.y + p.y) * spv;
        dv.z = (dv.z + p.z) * spv; dv.w = (dv.w + p.w) * spv;
        *(float4*)d = dv;
    }
}

extern "C" void kernel_launch(void* const* d_in, const int* in_sizes, int n_in,
                              void* d_out, int out_size, void* d_ws, size_t ws_size,
                              hipStream_t stream) {
    (void)in_sizes; (void)n_in; (void)out_size; (void)ws_size;
    const float* hidden = (const float*)d_in[0];
    const float* Wq = (const float*)d_in[1];
    const float* Wk = (const float*)d_in[2];
    const float* Wv = (const float*)d_in[3];
    const float* Wo = (const float*)d_in[4];
    const float* qw = (const float*)d_in[5];
    const float* kw = (const float*)d_in[6];
    const int* pos = (const int*)d_in[7];
    float* out = (float*)d_out;
    char* ws = (char*)d_ws;

    const size_t MB = 1024 * 1024;
    signed char* x_i8  = (signed char*)(ws);            // contiguous 16MB tiled i8 block
    signed char* wq_i8 = (signed char*)(ws + 4 * MB);
    signed char* wo_i8 = (signed char*)(ws + 12 * MB);
    signed char* q_i8  = (signed char*)(ws + 16 * MB);  // 4 MB (attn-tiled)
    signed char* k_i8  = (signed char*)(ws + 20 * MB);  // 2 MB (attn-tiled)
    float* sx  = (float*)(ws + 22 * MB);                // contiguous scales
    float* swq = sx + 2048;
    float* swo = sx + 6144;
    float* sq  = sx + 8192;                             // 16*2048
    float* sk  = sq + NH * SEQ;                         // 8*2048
    float* sa  = sk + NKV * SEQ;                        // 2048
    float* inv_tab = sa + 2048;                         // 64
    float* ct  = (float*)(ws + 22 * MB + 512 * 1024);   // 512 KB
    float* st  = (float*)(ws + 22 * MB + 1024 * 1024);  // 512 KB
    float* qkv_lin = (float*)(ws + 24 * MB);            // 32 MB [S,4096]
    float* attn2 = (float*)(ws + 32 * MB);              // 16 MB (inside dead qkv_lin)
    float* pp    = (float*)(ws + 48 * MB);              // 8 MB (inside dead qkv_lin)
    unsigned short* vtT = (unsigned short*)(ws + 56 * MB); // 4 MB (disjoint from qkv_lin)
    float* mm    = (float*)(ws + 60 * MB);              // 512 KB
    float* zb    = (float*)(ws + 60 * MB + 512 * 1024); // 128 KB
    signed char* a_i8 = x_i8;

    rope_init_k<<<1, 64, 0, stream>>>(inv_tab);
    rope_tab_k<<<2048, 64, 0, stream>>>(pos, inv_tab, ct, st);
    quant_all_k<<<512, 256, 0, stream>>>(hidden, Wq, Wk, Wv, Wo, x_i8, sx);

    gemm_i8_k<<<dim3(32, 16), 256, 0, stream>>>(x_i8, sx, wq_i8, swq, qkv_lin, 2048, 4096, 2048);

    qkv_post_k<<<2048, 256, 0, stream>>>(qkv_lin, qw, kw, ct, st, q_i8, sq, k_i8, sk);
    vt_split_k<<<dim3(32, 8), 256, 0, stream>>>(qkv_lin, vtT);

    attn_p1_k<<<dim3(128, 8), 256, 0, stream>>>(q_i8, sq, k_i8, sk, mm);
    attn_p2_k<<<dim3(64, 8), 256, 0, stream>>>(q_i8, sq, k_i8, sk, vtT, mm, attn2, pp, zb);
    attn_red_k<<<dim3(16, 16), 256, 0, stream>>>(attn2, pp, zb);

    row_quant_k<<<128, 256, 0, stream>>>(attn2, a_i8, sa, 2048);
    gemm_i8_k<<<dim3(16, 16), 256, 0, stream>>>(a_i8, sa, wo_i8, swo, out, 2048, 2048, 2048);
}

// Round 12
// 194.164 us; speedup vs baseline: 1.0938x; 1.0169x over previous
//
#include <hip/hip_runtime.h>
#include <math.h>

#define NH 16
#define NKV 8
#define HDIM 128
#define SEQ 2048
#define DMODEL 2048

typedef int   v4i __attribute__((ext_vector_type(4)));
typedef float v4f __attribute__((ext_vector_type(4)));
typedef _Float16 v8h __attribute__((ext_vector_type(8)));

static constexpr float SM_SCALE = 0.08838834764831843f; // 128**-0.5

#define GLOBP(p) (__attribute__((address_space(1))) void*)(p)
#define LDSP(p)  (__attribute__((address_space(3))) void*)(p)
#define ASYNC16(g, l) __builtin_amdgcn_global_load_lds(GLOBP(g), LDSP(l), 16, 0, 0)

// Fragment-tiled i8 layout for X[R][K] (R%16==0, K%64==0):
// frag (r>>4, k>>6) is 1024B; within: byte = ((k>>4)&3)*256 + (r&15)*16 + (k&15).

__device__ __forceinline__ unsigned short f2h_bits(float x) {
    _Float16 h = (_Float16)x;               // RN, exact for small ints
    return __builtin_bit_cast(unsigned short, h);
}

// ---------------- merged per-row int8 quant for all 5 inputs ----------------
__global__ __launch_bounds__(256) void quant_all_k(const float* __restrict__ hidden,
        const float* __restrict__ Wq, const float* __restrict__ Wk,
        const float* __restrict__ Wv, const float* __restrict__ Wo,
        signed char* __restrict__ out, float* __restrict__ scale) {
    int p = blockIdx.x;               // 16-row panel index, 512 total
    int row0g = p * 16;
    const float* in; int lr0;
    if (row0g < 2048)      { in = hidden; lr0 = row0g; }
    else if (row0g < 4096) { in = Wq; lr0 = row0g - 2048; }
    else if (row0g < 5120) { in = Wk; lr0 = row0g - 4096; }
    else if (row0g < 6144) { in = Wv; lr0 = row0g - 5120; }
    else                   { in = Wo; lr0 = row0g - 6144; }
    const int cols = 2048;
    int tid = threadIdx.x;
    __shared__ float srow[16];
    int r = tid >> 4, l16 = tid & 15;
    const float4* x4 = (const float4*)(in + (size_t)(lr0 + r) * cols);
    float amax = 0.f;
    for (int c4 = l16; c4 < (cols >> 2); c4 += 16) {
        float4 v = x4[c4];
        amax = fmaxf(amax, fmaxf(fmaxf(fabsf(v.x), fabsf(v.y)),
                                 fmaxf(fabsf(v.z), fabsf(v.w))));
    }
#pragma unroll
    for (int m = 1; m <= 8; m <<= 1) amax = fmaxf(amax, __shfl_xor(amax, m));
    if (l16 == 0) {
        float s = fmaxf(amax / 127.0f, 1e-8f);
        srow[r] = s;
        scale[row0g + r] = s;
    }
    __syncthreads();
    int total = (cols >> 4) * 16;
    size_t obase = (size_t)p * 32768;
    for (int idx = tid; idx < total; idx += 256) {
        int f = idx >> 6, q = (idx >> 4) & 3, rr = idx & 15;
        const float* src = in + (size_t)(lr0 + rr) * cols + f * 64 + q * 16;
        float s = srow[rr];
        unsigned int wds[4];
#pragma unroll
        for (int g = 0; g < 4; ++g) {
            float4 v = *(const float4*)(src + g * 4);
            int b0 = (int)fminf(fmaxf(rintf(v.x / s), -127.f), 127.f);
            int b1 = (int)fminf(fmaxf(rintf(v.y / s), -127.f), 127.f);
            int b2 = (int)fminf(fmaxf(rintf(v.z / s), -127.f), 127.f);
            int b3 = (int)fminf(fmaxf(rintf(v.w / s), -127.f), 127.f);
            wds[g] = (b0 & 255) | ((b1 & 255) << 8) | ((b2 & 255) << 16) | ((b3 & 255) << 24);
        }
        *(uint4*)(out + obase + (size_t)idx * 16) =
            make_uint4(wds[0], wds[1], wds[2], wds[3]);
    }
}

// ---------------- single-tensor row quant (for attn2) ----------------
__global__ __launch_bounds__(256) void row_quant_k(const float* __restrict__ in,
        signed char* __restrict__ out, float* __restrict__ scale, int cols) {
    int row0 = blockIdx.x * 16;
    int tid = threadIdx.x;
    __shared__ float srow[16];
    int r = tid >> 4, l16 = tid & 15;
    const float4* x4 = (const float4*)(in + (size_t)(row0 + r) * cols);
    float amax = 0.f;
    for (int c4 = l16; c4 < (cols >> 2); c4 += 16) {
        float4 v = x4[c4];
        amax = fmaxf(amax, fmaxf(fmaxf(fabsf(v.x), fabsf(v.y)),
                                 fmaxf(fabsf(v.z), fabsf(v.w))));
    }
#pragma unroll
    for (int m = 1; m <= 8; m <<= 1) amax = fmaxf(amax, __shfl_xor(amax, m));
    if (l16 == 0) {
        float s = fmaxf(amax / 127.0f, 1e-8f);
        srow[r] = s;
        scale[row0 + r] = s;
    }
    __syncthreads();
    int total = (cols >> 4) * 16;
    size_t obase = ((size_t)(row0 >> 4) * (cols >> 6)) << 10;
    for (int idx = tid; idx < total; idx += 256) {
        int f = idx >> 6, q = (idx >> 4) & 3, rr = idx & 15;
        const float* src = in + (size_t)(row0 + rr) * cols + f * 64 + q * 16;
        float s = srow[rr];
        unsigned int wds[4];
#pragma unroll
        for (int g = 0; g < 4; ++g) {
            float4 v = *(const float4*)(src + g * 4);
            int b0 = (int)fminf(fmaxf(rintf(v.x / s), -127.f), 127.f);
            int b1 = (int)fminf(fmaxf(rintf(v.y / s), -127.f), 127.f);
            int b2 = (int)fminf(fmaxf(rintf(v.z / s), -127.f), 127.f);
            int b3 = (int)fminf(fmaxf(rintf(v.w / s), -127.f), 127.f);
            wds[g] = (b0 & 255) | ((b1 & 255) << 8) | ((b2 & 255) << 16) | ((b3 & 255) << 24);
        }
        *(uint4*)(out + obase + (size_t)idx * 16) =
            make_uint4(wds[0], wds[1], wds[2], wds[3]);
    }
}

// ---------------- int8 GEMM (plain epilogue, used for O-projection) ----------------
__global__ __launch_bounds__(256, 3) void gemm_i8_k(const signed char* __restrict__ A,
        const float* __restrict__ sa, const signed char* __restrict__ B,
        const float* __restrict__ sb, float* __restrict__ C, int M, int N, int K) {
    __shared__ __align__(16) signed char lsA[3][8192];
    __shared__ __align__(16) signed char lsB[3][8192];
    int tid = threadIdx.x;
    int w = tid >> 6, l = tid & 63;
    int wr = w >> 1, wc = w & 1;
    int lrow = l & 15;
    int m0 = blockIdx.y * 128, n0 = blockIdx.x * 128;
    int kb6 = K >> 6;
    v4i acc[4][4];
#pragma unroll
    for (int i = 0; i < 4; ++i)
#pragma unroll
        for (int j = 0; j < 4; ++j) acc[i][j] = (v4i){0, 0, 0, 0};

    auto stage = [&](int buf, int k6) {
#pragma unroll
        for (int a = 0; a < 2; ++a) {
            int f = a * 4 + w;
            ASYNC16(A + (((size_t)(((m0 >> 4) + f) * kb6 + k6)) << 10) + l * 16,
                    lsA[buf] + f * 1024);
            ASYNC16(B + (((size_t)(((n0 >> 4) + f) * kb6 + k6)) << 10) + l * 16,
                    lsB[buf] + f * 1024);
        }
    };

    stage(0, 0);
    if (kb6 > 1) {
        stage(1, 1);
        asm volatile("s_waitcnt vmcnt(4)" ::: "memory");
    } else {
        asm volatile("s_waitcnt vmcnt(0)" ::: "memory");
    }
    __builtin_amdgcn_s_barrier();
    for (int t = 0; t < kb6; ++t) {
        if (t + 2 < kb6) stage((t + 2) % 3, t + 2);
        int cur = t % 3;
        v4i af[4], bf[4];
#pragma unroll
        for (int i = 0; i < 4; ++i) af[i] = *(const v4i*)(lsA[cur] + (wr * 4 + i) * 1024 + l * 16);
#pragma unroll
        for (int j = 0; j < 4; ++j) bf[j] = *(const v4i*)(lsB[cur] + (wc * 4 + j) * 1024 + l * 16);
#pragma unroll
        for (int i = 0; i < 4; ++i)
#pragma unroll
            for (int j = 0; j < 4; ++j)
                acc[i][j] = __builtin_amdgcn_mfma_i32_16x16x64_i8(af[i], bf[j], acc[i][j], 0, 0, 0);
        if (t + 2 < kb6) asm volatile("s_waitcnt vmcnt(4)" ::: "memory");
        else             asm volatile("s_waitcnt vmcnt(0)" ::: "memory");
        __builtin_amdgcn_s_barrier();
    }
    int r0 = m0 + wr * 64, c0 = n0 + wc * 64;
    int lg = l >> 4;
    float sbv[4];
#pragma unroll
    for (int j = 0; j < 4; ++j) sbv[j] = sb[c0 + j * 16 + lrow];
#pragma unroll
    for (int i = 0; i < 4; ++i) {
        float4 s4 = *(const float4*)(sa + r0 + i * 16 + lg * 4);
        float sav[4] = {s4.x, s4.y, s4.z, s4.w};
#pragma unroll
        for (int j = 0; j < 4; ++j) {
#pragma unroll
            for (int reg = 0; reg < 4; ++reg) {
                int rr = r0 + i * 16 + lg * 4 + reg;
                C[(size_t)rr * N + c0 + j * 16 + lrow] = (float)acc[i][j][reg] * (sav[reg] * sbv[j]);
            }
        }
    }
}

// ---------------- QKV GEMM with fused rmsnorm+rope+quant / V-transpose epilogue ----------
// grid (32, 16): n-tile = one head-slot (q:0-15, k:16-23, v:24-31), m-tile = 128 tokens.
// LDS union: staging 48KB (main loop) / fp32 tile [128][132]+srow (epilogue) = 68KB.
__global__ __launch_bounds__(256, 2) void gemm_qkv_k(const signed char* __restrict__ A,
        const float* __restrict__ sa, const signed char* __restrict__ B,
        const float* __restrict__ sb,
        const float* __restrict__ qw, const float* __restrict__ kw,
        const float* __restrict__ ct, const float* __restrict__ st,
        signed char* __restrict__ q_i8, float* __restrict__ sq,
        signed char* __restrict__ k_i8, float* __restrict__ sk,
        unsigned short* __restrict__ vtT) {
    __shared__ __align__(16) char smem[68608];
    signed char (*lsA)[8192] = (signed char(*)[8192])smem;
    signed char (*lsB)[8192] = (signed char(*)[8192])(smem + 24576);
    float (*tile)[132] = (float(*)[132])smem;
    float* srow = (float*)(smem + 67584);            // 128 floats
    int tid = threadIdx.x;
    int w = tid >> 6, l = tid & 63;
    int wr = w >> 1, wc = w & 1;
    int lrow = l & 15, lg = l >> 4;
    int m0 = blockIdx.y * 128, n0 = blockIdx.x * 128;
    const int kb6 = 32;                               // K = 2048
    v4i acc[4][4];
#pragma unroll
    for (int i = 0; i < 4; ++i)
#pragma unroll
        for (int j = 0; j < 4; ++j) acc[i][j] = (v4i){0, 0, 0, 0};

    auto stage = [&](int buf, int k6) {
#pragma unroll
        for (int a = 0; a < 2; ++a) {
            int f = a * 4 + w;
            ASYNC16(A + (((size_t)(((m0 >> 4) + f) * kb6 + k6)) << 10) + l * 16,
                    lsA[buf] + f * 1024);
            ASYNC16(B + (((size_t)(((n0 >> 4) + f) * kb6 + k6)) << 10) + l * 16,
                    lsB[buf] + f * 1024);
        }
    };

    stage(0, 0);
    stage(1, 1);
    asm volatile("s_waitcnt vmcnt(4)" ::: "memory");
    __builtin_amdgcn_s_barrier();
    for (int t = 0; t < kb6; ++t) {
        if (t + 2 < kb6) stage((t + 2) % 3, t + 2);
        int cur = t % 3;
        v4i af[4], bf[4];
#pragma unroll
        for (int i = 0; i < 4; ++i) af[i] = *(const v4i*)(lsA[cur] + (wr * 4 + i) * 1024 + l * 16);
#pragma unroll
        for (int j = 0; j < 4; ++j) bf[j] = *(const v4i*)(lsB[cur] + (wc * 4 + j) * 1024 + l * 16);
#pragma unroll
        for (int i = 0; i < 4; ++i)
#pragma unroll
            for (int j = 0; j < 4; ++j)
                acc[i][j] = __builtin_amdgcn_mfma_i32_16x16x64_i8(af[i], bf[j], acc[i][j], 0, 0, 0);
        if (t + 2 < kb6) asm volatile("s_waitcnt vmcnt(4)" ::: "memory");
        else             asm volatile("s_waitcnt vmcnt(0)" ::: "memory");
        __builtin_amdgcn_s_barrier();
    }
    // ---- scaled fp32 tile -> LDS (staging buffers dead after final barrier) ----
    {
        int c0 = n0 + wc * 64;
        float sbv[4];
#pragma unroll
        for (int j = 0; j < 4; ++j) sbv[j] = sb[c0 + j * 16 + lrow];
#pragma unroll
        for (int i = 0; i < 4; ++i) {
            float4 s4 = *(const float4*)(sa + m0 + wr * 64 + i * 16 + lg * 4);
            float sav[4] = {s4.x, s4.y, s4.z, s4.w};
#pragma unroll
            for (int j = 0; j < 4; ++j)
#pragma unroll
                for (int reg = 0; reg < 4; ++reg)
                    tile[wr * 64 + i * 16 + lg * 4 + reg][wc * 64 + j * 16 + lrow] =
                        (float)acc[i][j][reg] * (sav[reg] * sbv[j]);
        }
    }
    __syncthreads();
    int slot = n0 >> 7;
    if (slot < 24) {
        // ---- q/k: per-token rmsnorm + rope + int8 quant (same math as before) ----
        const float* wn = (slot < 16) ? qw : kw;
        signed char* dst8 = (slot < 16) ? q_i8 + (size_t)slot * (SEQ * 128)
                                        : k_i8 + (size_t)(slot - 16) * (SEQ * 128);
        float* sdst = (slot < 16) ? sq + (size_t)slot * SEQ : sk + (size_t)(slot - 16) * SEQ;
        float wn0 = wn[l], wn1 = wn[l + 64];
        for (int it = 0; it < 32; ++it) {
            int tl = it * 4 + w;
            int t = m0 + tl;
            float x0 = tile[tl][l];
            float x1 = tile[tl][l + 64];
            float ss = x0 * x0 + x1 * x1;
#pragma unroll
            for (int m = 1; m <= 32; m <<= 1) ss += __shfl_xor(ss, m);
            float rs = 1.0f / sqrtf(ss / 128.0f + 1e-6f);
            x0 = (x0 * rs) * wn0;
            x1 = (x1 * rs) * wn1;
            float cth = ct[t * 64 + l];
            float sth = st[t * 64 + l];
            float nx0 = x0 * cth - x1 * sth;
            float nx1 = x1 * cth + x0 * sth;
            float amax = fmaxf(fabsf(nx0), fabsf(nx1));
#pragma unroll
            for (int m = 1; m <= 32; m <<= 1) amax = fmaxf(amax, __shfl_xor(amax, m));
            float s = fmaxf(amax / 127.0f, 1e-8f);
            float q0 = fminf(fmaxf(rintf(nx0 / s), -127.f), 127.f);
            float q1 = fminf(fmaxf(rintf(nx1 / s), -127.f), 127.f);
            size_t ta0 = (size_t)(((t >> 4) * 2) << 10)
                       + (size_t)((((l >> 4) & 3) << 8) + ((t & 15) << 4) + (l & 15));
            dst8[ta0] = (signed char)(int)q0;
            dst8[ta0 + 1024] = (signed char)(int)q1;
            if (l == 0) sdst[t] = s;
        }
    } else {
        // ---- v: per-token quant scale, then quant-dequant-fp16 transpose into vtT ----
        int kv = slot - 24;
        for (int it = 0; it < 32; ++it) {
            int tl = it * 4 + w;
            float x0 = tile[tl][l];
            float x1 = tile[tl][l + 64];
            float amax = fmaxf(fabsf(x0), fabsf(x1));
#pragma unroll
            for (int m = 1; m <= 32; m <<= 1) amax = fmaxf(amax, __shfl_xor(amax, m));
            if (l == 0) srow[tl] = fmaxf(amax / 127.0f, 1e-8f);
        }
        __syncthreads();
        int d = tid >> 1, th = (tid & 1) * 32;
        size_t base = (size_t)kv * (SEQ * 128);
#pragma unroll
        for (int kbl = 0; kbl < 2; ++kbl) {
            int kb = (m0 >> 6) + kbl;
#pragma unroll
            for (int j = 0; j < 32; j += 2) {
                int t64 = th + j;                    // token index within 64-tile
                int tg = kbl * 64 + t64;             // tile-local token
                float s0 = srow[tg], s1 = srow[tg + 1];
                float a = fminf(fmaxf(rintf(tile[tg][d] / s0), -127.f), 127.f) * s0;
                float b = fminf(fmaxf(rintf(tile[tg + 1][d] / s1), -127.f), 127.f) * s1;
                unsigned int ua = f2h_bits(a), ub = f2h_bits(b);
                int off = kb * 8192 + ((d >> 4) * 2 + ((t64 >> 5) & 1)) * 512
                        + (((d & 15) + (((t64 >> 3) & 3) << 4)) << 3) + (t64 & 7);
                *(unsigned int*)(vtT + base + off) = ua | (ub << 16);
            }
        }
    }
}

// ---------------- rope cos/sin table (inline double-pow, fully parallel) ----------------
__global__ void rope_tab_k(const int* __restrict__ pos_ids,
                           float* __restrict__ ct, float* __restrict__ st) {
    int t = blockIdx.x;
    int fi = threadIdx.x; // 64
    float inv = 1.0f / (float)pow(1.0e6, (double)fi / 64.0);
    float fr = (float)pos_ids[t] * inv;
    float sn, c;
    sincosf(fr, &sn, &c);
    ct[t * 64 + fi] = c;
    st[t * 64 + fi] = sn;
}

// ---------------- attention pass 1: GQA-paired, row MAX only ----------------
__global__ __launch_bounds__(256, 4) void attn_p1_k(const signed char* __restrict__ q_i8,
        const float* __restrict__ sq, const signed char* __restrict__ k_i8,
        const float* __restrict__ sk, float* __restrict__ mm) {
    int bx = blockIdx.x, hp = blockIdx.y;
    int qb = 31 - (bx >> 2), c = bx & 3;
    int nch = (qb + 8) >> 3;
    if (c >= nch) return;
    int q0 = qb * 64;
    int kb0 = c * 8, kb1 = min((c + 1) * 8, qb + 1);
    int tid = threadIdx.x, w = tid >> 6, l = tid & 63;
    int lrow = l & 15, lg = l >> 4;
    int h0 = hp * 2, h1 = h0 + 1;

    const signed char* qtA = q_i8 + (size_t)h0 * (SEQ * 128)
                           + ((size_t)((((q0 >> 4) + w) * 2)) << 10) + l * 16;
    const signed char* qtB = qtA + (size_t)(SEQ * 128);
    v4i qfA0 = *(const v4i*)(qtA), qfA1 = *(const v4i*)(qtA + 1024);
    v4i qfB0 = *(const v4i*)(qtB), qfB1 = *(const v4i*)(qtB + 1024);
    float4 sA = *(const float4*)(sq + (size_t)h0 * SEQ + q0 + w * 16 + lg * 4);
    float4 sB = *(const float4*)(sq + (size_t)h1 * SEQ + q0 + w * 16 + lg * 4);
    float sqrA[4] = {sA.x, sA.y, sA.z, sA.w};
    float sqrB[4] = {sB.x, sB.y, sB.z, sB.w};
    const signed char* kbase = k_i8 + (size_t)hp * (SEQ * 128);
    const float* skb = sk + (size_t)hp * SEQ;

    float mA[4], mB[4];
#pragma unroll
    for (int r = 0; r < 4; ++r) { mA[r] = -1e30f; mB[r] = -1e30f; }

    v4i ka[8], kn[8];
    float skc[4], skn[4];
    auto loadK = [&](v4i* dst, float* sdst, int k0) {
#pragma unroll
        for (int f = 0; f < 8; ++f)
            dst[f] = *(const v4i*)(kbase + ((size_t)((k0 >> 4) * 2 + f) << 10) + l * 16);
#pragma unroll
        for (int j = 0; j < 4; ++j) sdst[j] = skb[k0 + j * 16 + lrow];
    };

    loadK(ka, skc, kb0 * 64);
    for (int kb = kb0; kb < kb1; ++kb) {
        if (kb + 1 < kb1) loadK(kn, skn, (kb + 1) * 64);
        int k0 = kb * 64;
        v4i sciA[4], sciB[4];
#pragma unroll
        for (int j = 0; j < 4; ++j) {
            v4i z = {0, 0, 0, 0};
            v4i tA = __builtin_amdgcn_mfma_i32_16x16x64_i8(qfA0, ka[j * 2], z, 0, 0, 0);
            sciA[j] = __builtin_amdgcn_mfma_i32_16x16x64_i8(qfA1, ka[j * 2 + 1], tA, 0, 0, 0);
            v4i tB = __builtin_amdgcn_mfma_i32_16x16x64_i8(qfB0, ka[j * 2], z, 0, 0, 0);
            sciB[j] = __builtin_amdgcn_mfma_i32_16x16x64_i8(qfB1, ka[j * 2 + 1], tB, 0, 0, 0);
        }
#pragma unroll
        for (int reg = 0; reg < 4; ++reg) {
            int r = q0 + w * 16 + lg * 4 + reg;
#pragma unroll
            for (int j = 0; j < 4; ++j) {
                bool ok = (k0 + j * 16 + lrow <= r);
                float ss = skc[j] * SM_SCALE;
                float svA = ((float)sciA[j][reg] * sqrA[reg]) * ss;
                float svB = ((float)sciB[j][reg] * sqrB[reg]) * ss;
                mA[reg] = fmaxf(mA[reg], ok ? svA : -1e30f);
                mB[reg] = fmaxf(mB[reg], ok ? svB : -1e30f);
            }
        }
        if (kb + 1 < kb1) {
#pragma unroll
            for (int f = 0; f < 8; ++f) ka[f] = kn[f];
#pragma unroll
            for (int j = 0; j < 4; ++j) skc[j] = skn[j];
        }
    }
#pragma unroll
    for (int reg = 0; reg < 4; ++reg) {
#pragma unroll
        for (int mask = 1; mask <= 8; mask <<= 1) {
            mA[reg] = fmaxf(mA[reg], __shfl_xor(mA[reg], mask));
            mB[reg] = fmaxf(mB[reg], __shfl_xor(mB[reg], mask));
        }
    }
    if (lrow == 0) {
        size_t bA = ((size_t)(h0 * 32 + qb) * 4 + c) * 64;
        size_t bB = ((size_t)(h1 * 32 + qb) * 4 + c) * 64;
#pragma unroll
        for (int reg = 0; reg < 4; ++reg) {
            mm[bA + w * 16 + lg * 4 + reg] = mA[reg];
            mm[bB + w * 16 + lg * 4 + reg] = mB[reg];
        }
    }
}

// ---------------- attention pass 2: GQA-paired, counted-vmcnt deep pipeline ----------------
__global__ __launch_bounds__(256, 2) void attn_p2_k(const signed char* __restrict__ q_i8,
        const float* __restrict__ sq, const signed char* __restrict__ k_i8,
        const float* __restrict__ sk, const unsigned short* __restrict__ vtT,
        const float* __restrict__ mm, float* __restrict__ attn2, float* __restrict__ pp,
        float* __restrict__ zb) {
    __shared__ __align__(16) unsigned short vlds[3][8192];  // 48 KB
    __shared__ __align__(16) signed char klds[2][8192];     // 16 KB
    __shared__ __align__(16) unsigned short plds[4096];     // 8 KB wave-private (A then B)
    __shared__ __align__(16) float slds[1024];              // 4 KB chunk K-scales
    int bx = blockIdx.x, hp = blockIdx.y;
    int qb = 31 - (bx >> 1), c = bx & 1;
    int nch2 = (qb >= 16) ? 2 : 1;
    if (c >= nch2) return;
    int q0 = qb * 64;
    int kb0 = c * 16, kb1 = min((c + 1) * 16, qb + 1);
    int tid = threadIdx.x, w = tid >> 6, l = tid & 63;
    int lrow = l & 15, lg = l >> 4;
    int h0 = hp * 2, h1 = h0 + 1;

    const signed char* qtA = q_i8 + (size_t)h0 * (SEQ * 128)
                           + ((size_t)((((q0 >> 4) + w) * 2)) << 10) + l * 16;
    const signed char* qtB = qtA + (size_t)(SEQ * 128);
    v4i qfA0 = *(const v4i*)(qtA), qfA1 = *(const v4i*)(qtA + 1024);
    v4i qfB0 = *(const v4i*)(qtB), qfB1 = *(const v4i*)(qtB + 1024);
    float4 sA = *(const float4*)(sq + (size_t)h0 * SEQ + q0 + w * 16 + lg * 4);
    float4 sB = *(const float4*)(sq + (size_t)h1 * SEQ + q0 + w * 16 + lg * 4);
    float sqrA[4] = {sA.x, sA.y, sA.z, sA.w};
    float sqrB[4] = {sB.x, sB.y, sB.z, sB.w};

    int nch1 = (qb + 8) >> 3;
    float mfA[4], mfB[4];
#pragma unroll
    for (int reg = 0; reg < 4; ++reg) {
        int r = w * 16 + lg * 4 + reg;
        float MA = -1e30f, MB = -1e30f;
        for (int c1 = 0; c1 < nch1; ++c1) {
            MA = fmaxf(MA, mm[((size_t)(h0 * 32 + qb) * 4 + c1) * 64 + r]);
            MB = fmaxf(MB, mm[((size_t)(h1 * 32 + qb) * 4 + c1) * 64 + r]);
        }
        mfA[reg] = MA; mfB[reg] = MB;
    }

    const signed char* kbase = k_i8 + (size_t)hp * (SEQ * 128);
    const float* skb = sk + (size_t)hp * SEQ;
    const unsigned short* vt = vtT + (size_t)hp * (SEQ * 128);

    auto issueV = [&](int kb) {     // 4 ASYNC16 / wave
        unsigned short* vb = &vlds[kb % 3][0];
#pragma unroll
        for (int a = 0; a < 4; ++a) {
            int fv = a * 4 + w;
            ASYNC16(vt + (size_t)kb * 8192 + fv * 512 + l * 8, vb + fv * 512);
        }
    };
    auto issueK = [&](int kb) {     // 2 ASYNC16 / wave
        signed char* kbuf = &klds[kb & 1][0];
#pragma unroll
        for (int a = 0; a < 2; ++a) {
            int f = a * 4 + w;
            ASYNC16(kbase + ((size_t)(kb * 8 + f) << 10) + l * 16, kbuf + f * 1024);
        }
    };

    v4f accA[8], accB[8];
#pragma unroll
    for (int jd = 0; jd < 8; ++jd) {
        accA[jd] = (v4f){0.f, 0.f, 0.f, 0.f};
        accB[jd] = (v4f){0.f, 0.f, 0.f, 0.f};
    }
    float ztA[4] = {0.f, 0.f, 0.f, 0.f};
    float ztB[4] = {0.f, 0.f, 0.f, 0.f};

    ASYNC16(skb + kb0 * 64 + w * 256 + l * 4, (char*)slds + w * 1024);
    issueK(kb0);
    issueV(kb0);
    if (kb0 + 1 < kb1) {
        issueV(kb0 + 1);
        asm volatile("s_waitcnt vmcnt(4)" ::: "memory");
    } else {
        asm volatile("s_waitcnt vmcnt(0)" ::: "memory");
    }
    __builtin_amdgcn_s_barrier();

    for (int kb = kb0; kb < kb1; ++kb) {
        int k0 = kb * 64;
        if (kb + 1 < kb1) issueK(kb + 1);
        if (kb + 2 < kb1) issueV(kb + 2);
        v4i ka[8];
#pragma unroll
        for (int f = 0; f < 8; ++f)
            ka[f] = *(const v4i*)(&klds[kb & 1][0] + f * 1024 + l * 16);
        float skc[4];
#pragma unroll
        for (int j = 0; j < 4; ++j) skc[j] = slds[(kb - kb0) * 64 + j * 16 + lrow];
        v4i sciA[4], sciB[4];
#pragma unroll
        for (int j = 0; j < 4; ++j) {
            v4i z = {0, 0, 0, 0};
            v4i tA = __builtin_amdgcn_mfma_i32_16x16x64_i8(qfA0, ka[j * 2], z, 0, 0, 0);
            sciA[j] = __builtin_amdgcn_mfma_i32_16x16x64_i8(qfA1, ka[j * 2 + 1], tA, 0, 0, 0);
            v4i tB = __builtin_amdgcn_mfma_i32_16x16x64_i8(qfB0, ka[j * 2], z, 0, 0, 0);
            sciB[j] = __builtin_amdgcn_mfma_i32_16x16x64_i8(qfB1, ka[j * 2 + 1], tB, 0, 0, 0);
        }
#pragma unroll
        for (int reg = 0; reg < 4; ++reg) {
            int rq = lg * 4 + reg;
            int r = q0 + w * 16 + rq;
#pragma unroll
            for (int j = 0; j < 4; ++j) {
                int cc = j * 16 + lrow;
                float pd = 0.f;
                if (k0 + cc <= r) {
                    float sv = ((float)sciA[j][reg] * (sqrA[reg] * skc[j])) * SM_SCALE;
                    float e = __expf(sv - mfA[reg]);
                    ztA[reg] += e;
                    pd = fminf(rintf(127.0f * e), 127.f);
                }
                plds[(w * 2 + (cc >> 5)) * 512 + (rq + 16 * ((cc >> 3) & 3)) * 8 + (cc & 7)] =
                    f2h_bits(pd);
            }
        }
        v8h pfA0 = *(const v8h*)(plds + (w * 2 + 0) * 512 + l * 8);
        v8h pfA1 = *(const v8h*)(plds + (w * 2 + 1) * 512 + l * 8);
#pragma unroll
        for (int reg = 0; reg < 4; ++reg) {
            int rq = lg * 4 + reg;
            int r = q0 + w * 16 + rq;
#pragma unroll
            for (int j = 0; j < 4; ++j) {
                int cc = j * 16 + lrow;
                float pd = 0.f;
                if (k0 + cc <= r) {
                    float sv = ((float)sciB[j][reg] * (sqrB[reg] * skc[j])) * SM_SCALE;
                    float e = __expf(sv - mfB[reg]);
                    ztB[reg] += e;
                    pd = fminf(rintf(127.0f * e), 127.f);
                }
                plds[(w * 2 + (cc >> 5)) * 512 + (rq + 16 * ((cc >> 3) & 3)) * 8 + (cc & 7)] =
                    f2h_bits(pd);
            }
        }
        v8h pfB0 = *(const v8h*)(plds + (w * 2 + 0) * 512 + l * 8);
        v8h pfB1 = *(const v8h*)(plds + (w * 2 + 1) * 512 + l * 8);
        const unsigned short* vb = &vlds[kb % 3][0];
#pragma unroll
        for (int jd = 0; jd < 8; ++jd) {
            v8h vh0 = *(const v8h*)(vb + (jd * 2 + 0) * 512 + l * 8);
            v8h vh1 = *(const v8h*)(vb + (jd * 2 + 1) * 512 + l * 8);
            v4f tA = accA[jd];
            tA = __builtin_amdgcn_mfma_f32_16x16x32_f16(pfA0, vh0, tA, 0, 0, 0);
            tA = __builtin_amdgcn_mfma_f32_16x16x32_f16(pfA1, vh1, tA, 0, 0, 0);
            accA[jd] = tA;
            v4f tB = accB[jd];
            tB = __builtin_amdgcn_mfma_f32_16x16x32_f16(pfB0, vh0, tB, 0, 0, 0);
            tB = __builtin_amdgcn_mfma_f32_16x16x32_f16(pfB1, vh1, tB, 0, 0, 0);
            accB[jd] = tB;
        }
        if (kb + 2 < kb1) asm volatile("s_waitcnt vmcnt(4)" ::: "memory");
        else              asm volatile("s_waitcnt vmcnt(0)" ::: "memory");
        __builtin_amdgcn_s_barrier();
    }
#pragma unroll
    for (int reg = 0; reg < 4; ++reg) {
#pragma unroll
        for (int mask = 1; mask <= 8; mask <<= 1) {
            ztA[reg] += __shfl_xor(ztA[reg], mask);
            ztB[reg] += __shfl_xor(ztB[reg], mask);
        }
    }
    if (qb < 16) {
        float spA[4], spB[4];
#pragma unroll
        for (int reg = 0; reg < 4; ++reg) {
            spA[reg] = fmaxf((1.0f / ztA[reg]) / 127.0f, 1e-8f);
            spB[reg] = fmaxf((1.0f / ztB[reg]) / 127.0f, 1e-8f);
        }
#pragma unroll
        for (int jd = 0; jd < 8; ++jd)
#pragma unroll
            for (int reg = 0; reg < 4; ++reg) {
                int r = q0 + w * 16 + lg * 4 + reg;
                attn2[(size_t)r * DMODEL + h0 * HDIM + jd * 16 + lrow] = accA[jd][reg] * spA[reg];
                attn2[(size_t)r * DMODEL + h1 * HDIM + jd * 16 + lrow] = accB[jd][reg] * spB[reg];
            }
    } else {
        if (c == 0) {
#pragma unroll
            for (int jd = 0; jd < 8; ++jd)
#pragma unroll
                for (int reg = 0; reg < 4; ++reg) {
                    int r = q0 + w * 16 + lg * 4 + reg;
                    attn2[(size_t)r * DMODEL + h0 * HDIM + jd * 16 + lrow] = accA[jd][reg];
                    attn2[(size_t)r * DMODEL + h1 * HDIM + jd * 16 + lrow] = accB[jd][reg];
                }
        } else {
#pragma unroll
            for (int jd = 0; jd < 8; ++jd)
#pragma unroll
                for (int reg = 0; reg < 4; ++reg) {
                    int rr = w * 16 + lg * 4 + reg;
                    pp[(((size_t)h0 * 16 + (qb - 16)) * 64 + rr) * 128 + jd * 16 + lrow] = accA[jd][reg];
                    pp[(((size_t)h1 * 16 + (qb - 16)) * 64 + rr) * 128 + jd * 16 + lrow] = accB[jd][reg];
                }
        }
        if (lrow == 0) {
            size_t zA = (((size_t)h0 * 16 + (qb - 16)) * 2 + c) * 64;
            size_t zB = (((size_t)h1 * 16 + (qb - 16)) * 2 + c) * 64;
#pragma unroll
            for (int reg = 0; reg < 4; ++reg) {
                zb[zA + w * 16 + lg * 4 + reg] = ztA[reg];
                zb[zB + w * 16 + lg * 4 + reg] = ztB[reg];
            }
        }
    }
}

// ---------------- reduce: out = (chunk0 + chunk1) * spv(Z0+Z1), tiles qb>=16 ----------------
__global__ __launch_bounds__(256) void attn_red_k(float* __restrict__ attn2,
        const float* __restrict__ pp, const float* __restrict__ zb) {
    int t16 = blockIdx.x, h = blockIdx.y;
    int qb = t16 + 16;
    int tid = threadIdx.x;
    for (int e = tid; e < 2048; e += 256) {
        int i = (e * 4) >> 7, j = (e * 4) & 127;
        float z0 = zb[(((size_t)h * 16 + t16) * 2 + 0) * 64 + i];
        float z1 = zb[(((size_t)h * 16 + t16) * 2 + 1) * 64 + i];
        float zinv = 1.0f / (z0 + z1);
        float spv = fmaxf(zinv / 127.0f, 1e-8f);
        float4 p = *(const float4*)&pp[(((size_t)h * 16 + t16) * 64 + i) * 128 + j];
        float* d = &attn2[(size_t)(qb * 64 + i) * DMODEL + h * HDIM + j];
        float4 dv = *(float4*)d;
        dv.x = (dv.x + p.x) * spv; dv.y = (dv.y + p.y) * spv;
        dv.z = (dv.z + p.z) * spv; dv.w = (dv.w + p.w) * spv;
        *(float4*)d = dv;
    }
}

extern "C" void kernel_launch(void* const* d_in, const int* in_sizes, int n_in,
                              void* d_out, int out_size, void* d_ws, size_t ws_size,
                              hipStream_t stream) {
    (void)in_sizes; (void)n_in; (void)out_size; (void)ws_size;
    const float* hidden = (const float*)d_in[0];
    const float* Wq = (const float*)d_in[1];
    const float* Wk = (const float*)d_in[2];
    const float* Wv = (const float*)d_in[3];
    const float* Wo = (const float*)d_in[4];
    const float* qw = (const float*)d_in[5];
    const float* kw = (const float*)d_in[6];
    const int* pos = (const int*)d_in[7];
    float* out = (float*)d_out;
    char* ws = (char*)d_ws;

    const size_t MB = 1024 * 1024;
    signed char* x_i8  = (signed char*)(ws);            // contiguous 16MB tiled i8 block
    signed char* wq_i8 = (signed char*)(ws + 4 * MB);
    signed char* wo_i8 = (signed char*)(ws + 12 * MB);
    signed char* q_i8  = (signed char*)(ws + 16 * MB);  // 4 MB (attn-tiled)
    signed char* k_i8  = (signed char*)(ws + 20 * MB);  // 2 MB (attn-tiled)
    float* sx  = (float*)(ws + 22 * MB);                // contiguous scales
    float* swq = sx + 2048;
    float* swo = sx + 6144;
    float* sq  = sx + 8192;                             // 16*2048
    float* sk  = sq + NH * SEQ;                         // 8*2048
    float* sa  = sk + NKV * SEQ;                        // 2048
    float* ct  = (float*)(ws + 22 * MB + 512 * 1024);   // 512 KB
    float* st  = (float*)(ws + 22 * MB + 1024 * 1024);  // 512 KB
    float* attn2 = (float*)(ws + 32 * MB);              // 16 MB
    float* pp    = (float*)(ws + 48 * MB);              // 8 MB
    unsigned short* vtT = (unsigned short*)(ws + 56 * MB); // 4 MB
    float* mm    = (float*)(ws + 60 * MB);              // 512 KB
    float* zb    = (float*)(ws + 60 * MB + 512 * 1024); // 128 KB
    signed char* a_i8 = x_i8;

    rope_tab_k<<<2048, 64, 0, stream>>>(pos, ct, st);
    quant_all_k<<<512, 256, 0, stream>>>(hidden, Wq, Wk, Wv, Wo, x_i8, sx);

    // fused QKV projection + rmsnorm/rope/quant + V fp16-transpose epilogue
    gemm_qkv_k<<<dim3(32, 16), 256, 0, stream>>>(x_i8, sx, wq_i8, swq, qw, kw, ct, st,
                                                 q_i8, sq, k_i8, sk, vtT);

    attn_p1_k<<<dim3(128, 8), 256, 0, stream>>>(q_i8, sq, k_i8, sk, mm);
    attn_p2_k<<<dim3(64, 8), 256, 0, stream>>>(q_i8, sq, k_i8, sk, vtT, mm, attn2, pp, zb);
    attn_red_k<<<dim3(16, 16), 256, 0, stream>>>(attn2, pp, zb);

    row_quant_k<<<128, 256, 0, stream>>>(attn2, a_i8, sa, 2048);
    gemm_i8_k<<<dim3(16, 16), 256, 0, stream>>>(a_i8, sa, wo_i8, swo, out, 2048, 2048, 2048);
}

// Round 13
// 190.416 us; speedup vs baseline: 1.1153x; 1.0197x over previous
//
#include <hip/hip_runtime.h>
#include <math.h>

#define NH 16
#define NKV 8
#define HDIM 128
#define SEQ 2048
#define DMODEL 2048

typedef int   v4i __attribute__((ext_vector_type(4)));
typedef float v4f __attribute__((ext_vector_type(4)));
typedef _Float16 v8h __attribute__((ext_vector_type(8)));

static constexpr float SM_SCALE = 0.08838834764831843f; // 128**-0.5

#define GLOBP(p) (__attribute__((address_space(1))) void*)(p)
#define LDSP(p)  (__attribute__((address_space(3))) void*)(p)
#define ASYNC16(g, l) __builtin_amdgcn_global_load_lds(GLOBP(g), LDSP(l), 16, 0, 0)

// Fragment-tiled i8 layout for X[R][K] (R%16==0, K%64==0):
// frag (r>>4, k>>6) is 1024B; within: byte = ((k>>4)&3)*256 + (r&15)*16 + (k&15).

__device__ __forceinline__ unsigned short f2h_bits(float x) {
    _Float16 h = (_Float16)x;               // RN, exact for small ints
    return __builtin_bit_cast(unsigned short, h);
}

// ---------------- merged per-row int8 quant (5 inputs) + rope table ----------------
// blocks 0..511: quant 16-row panels; blocks 512..1023: cos/sin table (4 tokens each).
__global__ __launch_bounds__(256) void quant_rope_k(const float* __restrict__ hidden,
        const float* __restrict__ Wq, const float* __restrict__ Wk,
        const float* __restrict__ Wv, const float* __restrict__ Wo,
        const int* __restrict__ pos_ids,
        signed char* __restrict__ out, float* __restrict__ scale,
        float* __restrict__ ct, float* __restrict__ st) {
    int p = blockIdx.x;
    if (p >= 512) {
        int t = (p - 512) * 4 + (threadIdx.x >> 6);
        int fi = threadIdx.x & 63;
        float inv = 1.0f / (float)pow(1.0e6, (double)fi / 64.0);
        float fr = (float)pos_ids[t] * inv;
        float sn, c;
        sincosf(fr, &sn, &c);
        ct[t * 64 + fi] = c;
        st[t * 64 + fi] = sn;
        return;
    }
    int row0g = p * 16;
    const float* in; int lr0;
    if (row0g < 2048)      { in = hidden; lr0 = row0g; }
    else if (row0g < 4096) { in = Wq; lr0 = row0g - 2048; }
    else if (row0g < 5120) { in = Wk; lr0 = row0g - 4096; }
    else if (row0g < 6144) { in = Wv; lr0 = row0g - 5120; }
    else                   { in = Wo; lr0 = row0g - 6144; }
    const int cols = 2048;
    int tid = threadIdx.x;
    __shared__ float srow[16];
    int r = tid >> 4, l16 = tid & 15;
    const float4* x4 = (const float4*)(in + (size_t)(lr0 + r) * cols);
    float amax = 0.f;
    for (int c4 = l16; c4 < (cols >> 2); c4 += 16) {
        float4 v = x4[c4];
        amax = fmaxf(amax, fmaxf(fmaxf(fabsf(v.x), fabsf(v.y)),
                                 fmaxf(fabsf(v.z), fabsf(v.w))));
    }
#pragma unroll
    for (int m = 1; m <= 8; m <<= 1) amax = fmaxf(amax, __shfl_xor(amax, m));
    if (l16 == 0) {
        float s = fmaxf(amax / 127.0f, 1e-8f);
        srow[r] = s;
        scale[row0g + r] = s;
    }
    __syncthreads();
    int total = (cols >> 4) * 16;
    size_t obase = (size_t)p * 32768;
    for (int idx = tid; idx < total; idx += 256) {
        int f = idx >> 6, q = (idx >> 4) & 3, rr = idx & 15;
        const float* src = in + (size_t)(lr0 + rr) * cols + f * 64 + q * 16;
        float s = srow[rr];
        unsigned int wds[4];
#pragma unroll
        for (int g = 0; g < 4; ++g) {
            float4 v = *(const float4*)(src + g * 4);
            int b0 = (int)fminf(fmaxf(rintf(v.x / s), -127.f), 127.f);
            int b1 = (int)fminf(fmaxf(rintf(v.y / s), -127.f), 127.f);
            int b2 = (int)fminf(fmaxf(rintf(v.z / s), -127.f), 127.f);
            int b3 = (int)fminf(fmaxf(rintf(v.w / s), -127.f), 127.f);
            wds[g] = (b0 & 255) | ((b1 & 255) << 8) | ((b2 & 255) << 16) | ((b3 & 255) << 24);
        }
        *(uint4*)(out + obase + (size_t)idx * 16) =
            make_uint4(wds[0], wds[1], wds[2], wds[3]);
    }
}

// ---------------- fused split-K reduce + row quant (attn2 -> a_i8) ----------------
// rows >= 1024 need (attn2 + pp) * spv(Z0+Z1); identical fp32 ops/order to the old
// attn_red_k followed by row_quant_k. attn2 itself is never written (dead after this).
__global__ __launch_bounds__(256) void row_quant_red_k(const float* __restrict__ attn2,
        const float* __restrict__ pp, const float* __restrict__ zb,
        signed char* __restrict__ out, float* __restrict__ scale) {
    int row0 = blockIdx.x * 16;
    bool corr = (row0 >= 1024);
    int tid = threadIdx.x;
    __shared__ float srow[16];
    __shared__ float spvt[16][17];
    if (corr) {
        int r = tid >> 4, h = tid & 15;
        int row = row0 + r;
        int t16 = (row >> 6) - 16, rr = row & 63;
        float z0 = zb[(((size_t)h * 16 + t16) * 2 + 0) * 64 + rr];
        float z1 = zb[(((size_t)h * 16 + t16) * 2 + 1) * 64 + rr];
        spvt[r][h] = fmaxf((1.0f / (z0 + z1)) / 127.0f, 1e-8f);
    }
    __syncthreads();
    int r = tid >> 4, l16 = tid & 15;
    int row = row0 + r;
    const float4* x4 = (const float4*)(attn2 + (size_t)row * 2048);
    size_t ppr = corr ? ((((size_t)(row >> 6) - 16) * 64 + (row & 63)) * 128) : 0;
    float amax = 0.f;
    for (int c4 = l16; c4 < 512; c4 += 16) {
        float4 v = x4[c4];
        if (corr) {
            int h = c4 >> 5;
            int j = (c4 & 31) * 4;
            float4 pv = *(const float4*)&pp[(size_t)h * 16 * 64 * 128 + ppr + j];
            float s = spvt[r][h];
            v.x = (v.x + pv.x) * s; v.y = (v.y + pv.y) * s;
            v.z = (v.z + pv.z) * s; v.w = (v.w + pv.w) * s;
        }
        amax = fmaxf(amax, fmaxf(fmaxf(fabsf(v.x), fabsf(v.y)),
                                 fmaxf(fabsf(v.z), fabsf(v.w))));
    }
#pragma unroll
    for (int m = 1; m <= 8; m <<= 1) amax = fmaxf(amax, __shfl_xor(amax, m));
    if (l16 == 0) {
        float s = fmaxf(amax / 127.0f, 1e-8f);
        srow[r] = s;
        scale[row0 + r] = s;
    }
    __syncthreads();
    size_t obase = ((size_t)(row0 >> 4) * 32) << 10;
    for (int idx = tid; idx < 2048; idx += 256) {
        int f = idx >> 6, q = (idx >> 4) & 3, rr16 = idx & 15;
        int rowb = row0 + rr16;
        int colb = f * 64 + q * 16;
        const float* src = attn2 + (size_t)rowb * 2048 + colb;
        float s = srow[rr16];
        int h = f >> 1;
        float sp = corr ? spvt[rr16][h] : 0.f;
        size_t ppb = corr ? ((size_t)h * 16 * 64 * 128
                     + (((size_t)(rowb >> 6) - 16) * 64 + (rowb & 63)) * 128 + (colb & 127)) : 0;
        unsigned int wds[4];
#pragma unroll
        for (int g = 0; g < 4; ++g) {
            float4 v = *(const float4*)(src + g * 4);
            if (corr) {
                float4 pv = *(const float4*)&pp[ppb + g * 4];
                v.x = (v.x + pv.x) * sp; v.y = (v.y + pv.y) * sp;
                v.z = (v.z + pv.z) * sp; v.w = (v.w + pv.w) * sp;
            }
            int b0 = (int)fminf(fmaxf(rintf(v.x / s), -127.f), 127.f);
            int b1 = (int)fminf(fmaxf(rintf(v.y / s), -127.f), 127.f);
            int b2 = (int)fminf(fmaxf(rintf(v.z / s), -127.f), 127.f);
            int b3 = (int)fminf(fmaxf(rintf(v.w / s), -127.f), 127.f);
            wds[g] = (b0 & 255) | ((b1 & 255) << 8) | ((b2 & 255) << 16) | ((b3 & 255) << 24);
        }
        *(uint4*)(out + obase + (size_t)idx * 16) =
            make_uint4(wds[0], wds[1], wds[2], wds[3]);
    }
}

// ---------------- O-projection GEMM: 128x64 tile -> 512 blocks (2/CU) ----------------
__global__ __launch_bounds__(256, 3) void gemm_o_k(const signed char* __restrict__ A,
        const float* __restrict__ sa, const signed char* __restrict__ B,
        const float* __restrict__ sb, float* __restrict__ C, int M, int N, int K) {
    __shared__ __align__(16) signed char lsA[3][8192];
    __shared__ __align__(16) signed char lsB[3][4096];
    int tid = threadIdx.x;
    int w = tid >> 6, l = tid & 63;
    int wr = w >> 1, wc = w & 1;
    int lrow = l & 15;
    int m0 = blockIdx.y * 128, n0 = blockIdx.x * 64;
    int kb6 = K >> 6;
    v4i acc[4][2];
#pragma unroll
    for (int i = 0; i < 4; ++i)
#pragma unroll
        for (int j = 0; j < 2; ++j) acc[i][j] = (v4i){0, 0, 0, 0};

    auto stage = [&](int buf, int k6) {   // 3 ASYNC16 per wave
#pragma unroll
        for (int a = 0; a < 2; ++a) {
            int f = a * 4 + w;
            ASYNC16(A + (((size_t)(((m0 >> 4) + f) * kb6 + k6)) << 10) + l * 16,
                    lsA[buf] + f * 1024);
        }
        ASYNC16(B + (((size_t)(((n0 >> 4) + w) * kb6 + k6)) << 10) + l * 16,
                lsB[buf] + w * 1024);
    };

    stage(0, 0);
    if (kb6 > 1) {
        stage(1, 1);
        asm volatile("s_waitcnt vmcnt(3)" ::: "memory");
    } else {
        asm volatile("s_waitcnt vmcnt(0)" ::: "memory");
    }
    __builtin_amdgcn_s_barrier();
    for (int t = 0; t < kb6; ++t) {
        if (t + 2 < kb6) stage((t + 2) % 3, t + 2);
        int cur = t % 3;
        v4i af[4], bf[2];
#pragma unroll
        for (int i = 0; i < 4; ++i) af[i] = *(const v4i*)(lsA[cur] + (wr * 4 + i) * 1024 + l * 16);
#pragma unroll
        for (int j = 0; j < 2; ++j) bf[j] = *(const v4i*)(lsB[cur] + (wc * 2 + j) * 1024 + l * 16);
#pragma unroll
        for (int i = 0; i < 4; ++i)
#pragma unroll
            for (int j = 0; j < 2; ++j)
                acc[i][j] = __builtin_amdgcn_mfma_i32_16x16x64_i8(af[i], bf[j], acc[i][j], 0, 0, 0);
        if (t + 2 < kb6) asm volatile("s_waitcnt vmcnt(3)" ::: "memory");
        else             asm volatile("s_waitcnt vmcnt(0)" ::: "memory");
        __builtin_amdgcn_s_barrier();
    }
    int r0 = m0 + wr * 64, c0 = n0 + wc * 32;
    int lg = l >> 4;
    float sbv[2];
#pragma unroll
    for (int j = 0; j < 2; ++j) sbv[j] = sb[c0 + j * 16 + lrow];
#pragma unroll
    for (int i = 0; i < 4; ++i) {
        float4 s4 = *(const float4*)(sa + r0 + i * 16 + lg * 4);
        float sav[4] = {s4.x, s4.y, s4.z, s4.w};
#pragma unroll
        for (int j = 0; j < 2; ++j) {
#pragma unroll
            for (int reg = 0; reg < 4; ++reg) {
                int rr = r0 + i * 16 + lg * 4 + reg;
                C[(size_t)rr * N + c0 + j * 16 + lrow] = (float)acc[i][j][reg] * (sav[reg] * sbv[j]);
            }
        }
    }
}

// ---------------- QKV GEMM with fused rmsnorm+rope+quant / V-transpose epilogue ----------
__global__ __launch_bounds__(256, 2) void gemm_qkv_k(const signed char* __restrict__ A,
        const float* __restrict__ sa, const signed char* __restrict__ B,
        const float* __restrict__ sb,
        const float* __restrict__ qw, const float* __restrict__ kw,
        const float* __restrict__ ct, const float* __restrict__ st,
        signed char* __restrict__ q_i8, float* __restrict__ sq,
        signed char* __restrict__ k_i8, float* __restrict__ sk,
        unsigned short* __restrict__ vtT) {
    __shared__ __align__(16) char smem[68608];
    signed char (*lsA)[8192] = (signed char(*)[8192])smem;
    signed char (*lsB)[8192] = (signed char(*)[8192])(smem + 24576);
    float (*tile)[132] = (float(*)[132])smem;
    float* srow = (float*)(smem + 67584);            // 128 floats
    int tid = threadIdx.x;
    int w = tid >> 6, l = tid & 63;
    int wr = w >> 1, wc = w & 1;
    int lrow = l & 15, lg = l >> 4;
    int m0 = blockIdx.y * 128, n0 = blockIdx.x * 128;
    const int kb6 = 32;                               // K = 2048
    v4i acc[4][4];
#pragma unroll
    for (int i = 0; i < 4; ++i)
#pragma unroll
        for (int j = 0; j < 4; ++j) acc[i][j] = (v4i){0, 0, 0, 0};

    auto stage = [&](int buf, int k6) {
#pragma unroll
        for (int a = 0; a < 2; ++a) {
            int f = a * 4 + w;
            ASYNC16(A + (((size_t)(((m0 >> 4) + f) * kb6 + k6)) << 10) + l * 16,
                    lsA[buf] + f * 1024);
            ASYNC16(B + (((size_t)(((n0 >> 4) + f) * kb6 + k6)) << 10) + l * 16,
                    lsB[buf] + f * 1024);
        }
    };

    stage(0, 0);
    stage(1, 1);
    asm volatile("s_waitcnt vmcnt(4)" ::: "memory");
    __builtin_amdgcn_s_barrier();
    for (int t = 0; t < kb6; ++t) {
        if (t + 2 < kb6) stage((t + 2) % 3, t + 2);
        int cur = t % 3;
        v4i af[4], bf[4];
#pragma unroll
        for (int i = 0; i < 4; ++i) af[i] = *(const v4i*)(lsA[cur] + (wr * 4 + i) * 1024 + l * 16);
#pragma unroll
        for (int j = 0; j < 4; ++j) bf[j] = *(const v4i*)(lsB[cur] + (wc * 4 + j) * 1024 + l * 16);
#pragma unroll
        for (int i = 0; i < 4; ++i)
#pragma unroll
            for (int j = 0; j < 4; ++j)
                acc[i][j] = __builtin_amdgcn_mfma_i32_16x16x64_i8(af[i], bf[j], acc[i][j], 0, 0, 0);
        if (t + 2 < kb6) asm volatile("s_waitcnt vmcnt(4)" ::: "memory");
        else             asm volatile("s_waitcnt vmcnt(0)" ::: "memory");
        __builtin_amdgcn_s_barrier();
    }
    {
        int c0 = n0 + wc * 64;
        float sbv[4];
#pragma unroll
        for (int j = 0; j < 4; ++j) sbv[j] = sb[c0 + j * 16 + lrow];
#pragma unroll
        for (int i = 0; i < 4; ++i) {
            float4 s4 = *(const float4*)(sa + m0 + wr * 64 + i * 16 + lg * 4);
            float sav[4] = {s4.x, s4.y, s4.z, s4.w};
#pragma unroll
            for (int j = 0; j < 4; ++j)
#pragma unroll
                for (int reg = 0; reg < 4; ++reg)
                    tile[wr * 64 + i * 16 + lg * 4 + reg][wc * 64 + j * 16 + lrow] =
                        (float)acc[i][j][reg] * (sav[reg] * sbv[j]);
        }
    }
    __syncthreads();
    int slot = n0 >> 7;
    if (slot < 24) {
        const float* wn = (slot < 16) ? qw : kw;
        signed char* dst8 = (slot < 16) ? q_i8 + (size_t)slot * (SEQ * 128)
                                        : k_i8 + (size_t)(slot - 16) * (SEQ * 128);
        float* sdst = (slot < 16) ? sq + (size_t)slot * SEQ : sk + (size_t)(slot - 16) * SEQ;
        float wn0 = wn[l], wn1 = wn[l + 64];
        for (int it = 0; it < 32; ++it) {
            int tl = it * 4 + w;
            int t = m0 + tl;
            float x0 = tile[tl][l];
            float x1 = tile[tl][l + 64];
            float ss = x0 * x0 + x1 * x1;
#pragma unroll
            for (int m = 1; m <= 32; m <<= 1) ss += __shfl_xor(ss, m);
            float rs = 1.0f / sqrtf(ss / 128.0f + 1e-6f);
            x0 = (x0 * rs) * wn0;
            x1 = (x1 * rs) * wn1;
            float cth = ct[t * 64 + l];
            float sth = st[t * 64 + l];
            float nx0 = x0 * cth - x1 * sth;
            float nx1 = x1 * cth + x0 * sth;
            float amax = fmaxf(fabsf(nx0), fabsf(nx1));
#pragma unroll
            for (int m = 1; m <= 32; m <<= 1) amax = fmaxf(amax, __shfl_xor(amax, m));
            float s = fmaxf(amax / 127.0f, 1e-8f);
            float q0 = fminf(fmaxf(rintf(nx0 / s), -127.f), 127.f);
            float q1 = fminf(fmaxf(rintf(nx1 / s), -127.f), 127.f);
            size_t ta0 = (size_t)(((t >> 4) * 2) << 10)
                       + (size_t)((((l >> 4) & 3) << 8) + ((t & 15) << 4) + (l & 15));
            dst8[ta0] = (signed char)(int)q0;
            dst8[ta0 + 1024] = (signed char)(int)q1;
            if (l == 0) sdst[t] = s;
        }
    } else {
        int kv = slot - 24;
        for (int it = 0; it < 32; ++it) {
            int tl = it * 4 + w;
            float x0 = tile[tl][l];
            float x1 = tile[tl][l + 64];
            float amax = fmaxf(fabsf(x0), fabsf(x1));
#pragma unroll
            for (int m = 1; m <= 32; m <<= 1) amax = fmaxf(amax, __shfl_xor(amax, m));
            if (l == 0) srow[tl] = fmaxf(amax / 127.0f, 1e-8f);
        }
        __syncthreads();
        int d = tid >> 1, th = (tid & 1) * 32;
        size_t base = (size_t)kv * (SEQ * 128);
#pragma unroll
        for (int kbl = 0; kbl < 2; ++kbl) {
            int kb = (m0 >> 6) + kbl;
#pragma unroll
            for (int j = 0; j < 32; j += 2) {
                int t64 = th + j;
                int tg = kbl * 64 + t64;
                float s0 = srow[tg], s1 = srow[tg + 1];
                float a = fminf(fmaxf(rintf(tile[tg][d] / s0), -127.f), 127.f) * s0;
                float b = fminf(fmaxf(rintf(tile[tg + 1][d] / s1), -127.f), 127.f) * s1;
                unsigned int ua = f2h_bits(a), ub = f2h_bits(b);
                int off = kb * 8192 + ((d >> 4) * 2 + ((t64 >> 5) & 1)) * 512
                        + (((d & 15) + (((t64 >> 3) & 3) << 4)) << 3) + (t64 & 7);
                *(unsigned int*)(vtT + base + off) = ua | (ub << 16);
            }
        }
    }
}

// ---------------- attention pass 1: GQA-paired, row MAX only ----------------
__global__ __launch_bounds__(256, 4) void attn_p1_k(const signed char* __restrict__ q_i8,
        const float* __restrict__ sq, const signed char* __restrict__ k_i8,
        const float* __restrict__ sk, float* __restrict__ mm) {
    int bx = blockIdx.x, hp = blockIdx.y;
    int qb = 31 - (bx >> 2), c = bx & 3;
    int nch = (qb + 8) >> 3;
    if (c >= nch) return;
    int q0 = qb * 64;
    int kb0 = c * 8, kb1 = min((c + 1) * 8, qb + 1);
    int tid = threadIdx.x, w = tid >> 6, l = tid & 63;
    int lrow = l & 15, lg = l >> 4;
    int h0 = hp * 2, h1 = h0 + 1;

    const signed char* qtA = q_i8 + (size_t)h0 * (SEQ * 128)
                           + ((size_t)((((q0 >> 4) + w) * 2)) << 10) + l * 16;
    const signed char* qtB = qtA + (size_t)(SEQ * 128);
    v4i qfA0 = *(const v4i*)(qtA), qfA1 = *(const v4i*)(qtA + 1024);
    v4i qfB0 = *(const v4i*)(qtB), qfB1 = *(const v4i*)(qtB + 1024);
    float4 sA = *(const float4*)(sq + (size_t)h0 * SEQ + q0 + w * 16 + lg * 4);
    float4 sB = *(const float4*)(sq + (size_t)h1 * SEQ + q0 + w * 16 + lg * 4);
    float sqrA[4] = {sA.x, sA.y, sA.z, sA.w};
    float sqrB[4] = {sB.x, sB.y, sB.z, sB.w};
    const signed char* kbase = k_i8 + (size_t)hp * (SEQ * 128);
    const float* skb = sk + (size_t)hp * SEQ;

    float mA[4], mB[4];
#pragma unroll
    for (int r = 0; r < 4; ++r) { mA[r] = -1e30f; mB[r] = -1e30f; }

    v4i ka[8], kn[8];
    float skc[4], skn[4];
    auto loadK = [&](v4i* dst, float* sdst, int k0) {
#pragma unroll
        for (int f = 0; f < 8; ++f)
            dst[f] = *(const v4i*)(kbase + ((size_t)((k0 >> 4) * 2 + f) << 10) + l * 16);
#pragma unroll
        for (int j = 0; j < 4; ++j) sdst[j] = skb[k0 + j * 16 + lrow];
    };

    loadK(ka, skc, kb0 * 64);
    for (int kb = kb0; kb < kb1; ++kb) {
        if (kb + 1 < kb1) loadK(kn, skn, (kb + 1) * 64);
        int k0 = kb * 64;
        v4i sciA[4], sciB[4];
#pragma unroll
        for (int j = 0; j < 4; ++j) {
            v4i z = {0, 0, 0, 0};
            v4i tA = __builtin_amdgcn_mfma_i32_16x16x64_i8(qfA0, ka[j * 2], z, 0, 0, 0);
            sciA[j] = __builtin_amdgcn_mfma_i32_16x16x64_i8(qfA1, ka[j * 2 + 1], tA, 0, 0, 0);
            v4i tB = __builtin_amdgcn_mfma_i32_16x16x64_i8(qfB0, ka[j * 2], z, 0, 0, 0);
            sciB[j] = __builtin_amdgcn_mfma_i32_16x16x64_i8(qfB1, ka[j * 2 + 1], tB, 0, 0, 0);
        }
#pragma unroll
        for (int reg = 0; reg < 4; ++reg) {
            int r = q0 + w * 16 + lg * 4 + reg;
#pragma unroll
            for (int j = 0; j < 4; ++j) {
                bool ok = (k0 + j * 16 + lrow <= r);
                float ss = skc[j] * SM_SCALE;
                float svA = ((float)sciA[j][reg] * sqrA[reg]) * ss;
                float svB = ((float)sciB[j][reg] * sqrB[reg]) * ss;
                mA[reg] = fmaxf(mA[reg], ok ? svA : -1e30f);
                mB[reg] = fmaxf(mB[reg], ok ? svB : -1e30f);
            }
        }
        if (kb + 1 < kb1) {
#pragma unroll
            for (int f = 0; f < 8; ++f) ka[f] = kn[f];
#pragma unroll
            for (int j = 0; j < 4; ++j) skc[j] = skn[j];
        }
    }
#pragma unroll
    for (int reg = 0; reg < 4; ++reg) {
#pragma unroll
        for (int mask = 1; mask <= 8; mask <<= 1) {
            mA[reg] = fmaxf(mA[reg], __shfl_xor(mA[reg], mask));
            mB[reg] = fmaxf(mB[reg], __shfl_xor(mB[reg], mask));
        }
    }
    if (lrow == 0) {
        size_t bA = ((size_t)(h0 * 32 + qb) * 4 + c) * 64;
        size_t bB = ((size_t)(h1 * 32 + qb) * 4 + c) * 64;
#pragma unroll
        for (int reg = 0; reg < 4; ++reg) {
            mm[bA + w * 16 + lg * 4 + reg] = mA[reg];
            mm[bB + w * 16 + lg * 4 + reg] = mB[reg];
        }
    }
}

// ---------------- attention pass 2: GQA-paired, counted-vmcnt deep pipeline ----------------
__global__ __launch_bounds__(256, 2) void attn_p2_k(const signed char* __restrict__ q_i8,
        const float* __restrict__ sq, const signed char* __restrict__ k_i8,
        const float* __restrict__ sk, const unsigned short* __restrict__ vtT,
        const float* __restrict__ mm, float* __restrict__ attn2, float* __restrict__ pp,
        float* __restrict__ zb) {
    __shared__ __align__(16) unsigned short vlds[3][8192];  // 48 KB
    __shared__ __align__(16) signed char klds[2][8192];     // 16 KB
    __shared__ __align__(16) unsigned short plds[4096];     // 8 KB wave-private (A then B)
    __shared__ __align__(16) float slds[1024];              // 4 KB chunk K-scales
    int bx = blockIdx.x, hp = blockIdx.y;
    int qb = 31 - (bx >> 1), c = bx & 1;
    int nch2 = (qb >= 16) ? 2 : 1;
    if (c >= nch2) return;
    int q0 = qb * 64;
    int kb0 = c * 16, kb1 = min((c + 1) * 16, qb + 1);
    int tid = threadIdx.x, w = tid >> 6, l = tid & 63;
    int lrow = l & 15, lg = l >> 4;
    int h0 = hp * 2, h1 = h0 + 1;

    const signed char* qtA = q_i8 + (size_t)h0 * (SEQ * 128)
                           + ((size_t)((((q0 >> 4) + w) * 2)) << 10) + l * 16;
    const signed char* qtB = qtA + (size_t)(SEQ * 128);
    v4i qfA0 = *(const v4i*)(qtA), qfA1 = *(const v4i*)(qtA + 1024);
    v4i qfB0 = *(const v4i*)(qtB), qfB1 = *(const v4i*)(qtB + 1024);
    float4 sA = *(const float4*)(sq + (size_t)h0 * SEQ + q0 + w * 16 + lg * 4);
    float4 sB = *(const float4*)(sq + (size_t)h1 * SEQ + q0 + w * 16 + lg * 4);
    float sqrA[4] = {sA.x, sA.y, sA.z, sA.w};
    float sqrB[4] = {sB.x, sB.y, sB.z, sB.w};

    int nch1 = (qb + 8) >> 3;
    float mfA[4], mfB[4];
#pragma unroll
    for (int reg = 0; reg < 4; ++reg) {
        int r = w * 16 + lg * 4 + reg;
        float MA = -1e30f, MB = -1e30f;
        for (int c1 = 0; c1 < nch1; ++c1) {
            MA = fmaxf(MA, mm[((size_t)(h0 * 32 + qb) * 4 + c1) * 64 + r]);
            MB = fmaxf(MB, mm[((size_t)(h1 * 32 + qb) * 4 + c1) * 64 + r]);
        }
        mfA[reg] = MA; mfB[reg] = MB;
    }

    const signed char* kbase = k_i8 + (size_t)hp * (SEQ * 128);
    const float* skb = sk + (size_t)hp * SEQ;
    const unsigned short* vt = vtT + (size_t)hp * (SEQ * 128);

    auto issueV = [&](int kb) {     // 4 ASYNC16 / wave
        unsigned short* vb = &vlds[kb % 3][0];
#pragma unroll
        for (int a = 0; a < 4; ++a) {
            int fv = a * 4 + w;
            ASYNC16(vt + (size_t)kb * 8192 + fv * 512 + l * 8, vb + fv * 512);
        }
    };
    auto issueK = [&](int kb) {     // 2 ASYNC16 / wave
        signed char* kbuf = &klds[kb & 1][0];
#pragma unroll
        for (int a = 0; a < 2; ++a) {
            int f = a * 4 + w;
            ASYNC16(kbase + ((size_t)(kb * 8 + f) << 10) + l * 16, kbuf + f * 1024);
        }
    };

    v4f accA[8], accB[8];
#pragma unroll
    for (int jd = 0; jd < 8; ++jd) {
        accA[jd] = (v4f){0.f, 0.f, 0.f, 0.f};
        accB[jd] = (v4f){0.f, 0.f, 0.f, 0.f};
    }
    float ztA[4] = {0.f, 0.f, 0.f, 0.f};
    float ztB[4] = {0.f, 0.f, 0.f, 0.f};

    ASYNC16(skb + kb0 * 64 + w * 256 + l * 4, (char*)slds + w * 1024);
    issueK(kb0);
    issueV(kb0);
    if (kb0 + 1 < kb1) {
        issueV(kb0 + 1);
        asm volatile("s_waitcnt vmcnt(4)" ::: "memory");
    } else {
        asm volatile("s_waitcnt vmcnt(0)" ::: "memory");
    }
    __builtin_amdgcn_s_barrier();

    for (int kb = kb0; kb < kb1; ++kb) {
        int k0 = kb * 64;
        if (kb + 1 < kb1) issueK(kb + 1);
        if (kb + 2 < kb1) issueV(kb + 2);
        v4i ka[8];
#pragma unroll
        for (int f = 0; f < 8; ++f)
            ka[f] = *(const v4i*)(&klds[kb & 1][0] + f * 1024 + l * 16);
        float skc[4];
#pragma unroll
        for (int j = 0; j < 4; ++j) skc[j] = slds[(kb - kb0) * 64 + j * 16 + lrow];
        v4i sciA[4], sciB[4];
#pragma unroll
        for (int j = 0; j < 4; ++j) {
            v4i z = {0, 0, 0, 0};
            v4i tA = __builtin_amdgcn_mfma_i32_16x16x64_i8(qfA0, ka[j * 2], z, 0, 0, 0);
            sciA[j] = __builtin_amdgcn_mfma_i32_16x16x64_i8(qfA1, ka[j * 2 + 1], tA, 0, 0, 0);
            v4i tB = __builtin_amdgcn_mfma_i32_16x16x64_i8(qfB0, ka[j * 2], z, 0, 0, 0);
            sciB[j] = __builtin_amdgcn_mfma_i32_16x16x64_i8(qfB1, ka[j * 2 + 1], tB, 0, 0, 0);
        }
#pragma unroll
        for (int reg = 0; reg < 4; ++reg) {
            int rq = lg * 4 + reg;
            int r = q0 + w * 16 + rq;
#pragma unroll
            for (int j = 0; j < 4; ++j) {
                int cc = j * 16 + lrow;
                float pd = 0.f;
                if (k0 + cc <= r) {
                    float sv = ((float)sciA[j][reg] * (sqrA[reg] * skc[j])) * SM_SCALE;
                    float e = __expf(sv - mfA[reg]);
                    ztA[reg] += e;
                    pd = fminf(rintf(127.0f * e), 127.f);
                }
                plds[(w * 2 + (cc >> 5)) * 512 + (rq + 16 * ((cc >> 3) & 3)) * 8 + (cc & 7)] =
                    f2h_bits(pd);
            }
        }
        v8h pfA0 = *(const v8h*)(plds + (w * 2 + 0) * 512 + l * 8);
        v8h pfA1 = *(const v8h*)(plds + (w * 2 + 1) * 512 + l * 8);
#pragma unroll
        for (int reg = 0; reg < 4; ++reg) {
            int rq = lg * 4 + reg;
            int r = q0 + w * 16 + rq;
#pragma unroll
            for (int j = 0; j < 4; ++j) {
                int cc = j * 16 + lrow;
                float pd = 0.f;
                if (k0 + cc <= r) {
                    float sv = ((float)sciB[j][reg] * (sqrB[reg] * skc[j])) * SM_SCALE;
                    float e = __expf(sv - mfB[reg]);
                    ztB[reg] += e;
                    pd = fminf(rintf(127.0f * e), 127.f);
                }
                plds[(w * 2 + (cc >> 5)) * 512 + (rq + 16 * ((cc >> 3) & 3)) * 8 + (cc & 7)] =
                    f2h_bits(pd);
            }
        }
        v8h pfB0 = *(const v8h*)(plds + (w * 2 + 0) * 512 + l * 8);
        v8h pfB1 = *(const v8h*)(plds + (w * 2 + 1) * 512 + l * 8);
        const unsigned short* vb = &vlds[kb % 3][0];
#pragma unroll
        for (int jd = 0; jd < 8; ++jd) {
            v8h vh0 = *(const v8h*)(vb + (jd * 2 + 0) * 512 + l * 8);
            v8h vh1 = *(const v8h*)(vb + (jd * 2 + 1) * 512 + l * 8);
            v4f tA = accA[jd];
            tA = __builtin_amdgcn_mfma_f32_16x16x32_f16(pfA0, vh0, tA, 0, 0, 0);
            tA = __builtin_amdgcn_mfma_f32_16x16x32_f16(pfA1, vh1, tA, 0, 0, 0);
            accA[jd] = tA;
            v4f tB = accB[jd];
            tB = __builtin_amdgcn_mfma_f32_16x16x32_f16(pfB0, vh0, tB, 0, 0, 0);
            tB = __builtin_amdgcn_mfma_f32_16x16x32_f16(pfB1, vh1, tB, 0, 0, 0);
            accB[jd] = tB;
        }
        if (kb + 2 < kb1) asm volatile("s_waitcnt vmcnt(4)" ::: "memory");
        else              asm volatile("s_waitcnt vmcnt(0)" ::: "memory");
        __builtin_amdgcn_s_barrier();
    }
#pragma unroll
    for (int reg = 0; reg < 4; ++reg) {
#pragma unroll
        for (int mask = 1; mask <= 8; mask <<= 1) {
            ztA[reg] += __shfl_xor(ztA[reg], mask);
            ztB[reg] += __shfl_xor(ztB[reg], mask);
        }
    }
    if (qb < 16) {
        float spA[4], spB[4];
#pragma unroll
        for (int reg = 0; reg < 4; ++reg) {
            spA[reg] = fmaxf((1.0f / ztA[reg]) / 127.0f, 1e-8f);
            spB[reg] = fmaxf((1.0f / ztB[reg]) / 127.0f, 1e-8f);
        }
#pragma unroll
        for (int jd = 0; jd < 8; ++jd)
#pragma unroll
            for (int reg = 0; reg < 4; ++reg) {
                int r = q0 + w * 16 + lg * 4 + reg;
                attn2[(size_t)r * DMODEL + h0 * HDIM + jd * 16 + lrow] = accA[jd][reg] * spA[reg];
                attn2[(size_t)r * DMODEL + h1 * HDIM + jd * 16 + lrow] = accB[jd][reg] * spB[reg];
            }
    } else {
        if (c == 0) {
#pragma unroll
            for (int jd = 0; jd < 8; ++jd)
#pragma unroll
                for (int reg = 0; reg < 4; ++reg) {
                    int r = q0 + w * 16 + lg * 4 + reg;
                    attn2[(size_t)r * DMODEL + h0 * HDIM + jd * 16 + lrow] = accA[jd][reg];
                    attn2[(size_t)r * DMODEL + h1 * HDIM + jd * 16 + lrow] = accB[jd][reg];
                }
        } else {
#pragma unroll
            for (int jd = 0; jd < 8; ++jd)
#pragma unroll
                for (int reg = 0; reg < 4; ++reg) {
                    int rr = w * 16 + lg * 4 + reg;
                    pp[(((size_t)h0 * 16 + (qb - 16)) * 64 + rr) * 128 + jd * 16 + lrow] = accA[jd][reg];
                    pp[(((size_t)h1 * 16 + (qb - 16)) * 64 + rr) * 128 + jd * 16 + lrow] = accB[jd][reg];
                }
        }
        if (lrow == 0) {
            size_t zA = (((size_t)h0 * 16 + (qb - 16)) * 2 + c) * 64;
            size_t zB = (((size_t)h1 * 16 + (qb - 16)) * 2 + c) * 64;
#pragma unroll
            for (int reg = 0; reg < 4; ++reg) {
                zb[zA + w * 16 + lg * 4 + reg] = ztA[reg];
                zb[zB + w * 16 + lg * 4 + reg] = ztB[reg];
            }
        }
    }
}

extern "C" void kernel_launch(void* const* d_in, const int* in_sizes, int n_in,
                              void* d_out, int out_size, void* d_ws, size_t ws_size,
                              hipStream_t stream) {
    (void)in_sizes; (void)n_in; (void)out_size; (void)ws_size;
    const float* hidden = (const float*)d_in[0];
    const float* Wq = (const float*)d_in[1];
    const float* Wk = (const float*)d_in[2];
    const float* Wv = (const float*)d_in[3];
    const float* Wo = (const float*)d_in[4];
    const float* qw = (const float*)d_in[5];
    const float* kw = (const float*)d_in[6];
    const int* pos = (const int*)d_in[7];
    float* out = (float*)d_out;
    char* ws = (char*)d_ws;

    const size_t MB = 1024 * 1024;
    signed char* x_i8  = (signed char*)(ws);            // contiguous 16MB tiled i8 block
    signed char* wq_i8 = (signed char*)(ws + 4 * MB);
    signed char* wo_i8 = (signed char*)(ws + 12 * MB);
    signed char* q_i8  = (signed char*)(ws + 16 * MB);  // 4 MB (attn-tiled)
    signed char* k_i8  = (signed char*)(ws + 20 * MB);  // 2 MB (attn-tiled)
    float* sx  = (float*)(ws + 22 * MB);                // contiguous scales
    float* swq = sx + 2048;
    float* swo = sx + 6144;
    float* sq  = sx + 8192;                             // 16*2048
    float* sk  = sq + NH * SEQ;                         // 8*2048
    float* sa  = sk + NKV * SEQ;                        // 2048
    float* ct  = (float*)(ws + 22 * MB + 512 * 1024);   // 512 KB
    float* st  = (float*)(ws + 22 * MB + 1024 * 1024);  // 512 KB
    float* attn2 = (float*)(ws + 32 * MB);              // 16 MB
    float* pp    = (float*)(ws + 48 * MB);              // 8 MB
    unsigned short* vtT = (unsigned short*)(ws + 56 * MB); // 4 MB
    float* mm    = (float*)(ws + 60 * MB);              // 512 KB
    float* zb    = (float*)(ws + 60 * MB + 512 * 1024); // 128 KB
    signed char* a_i8 = x_i8;

    quant_rope_k<<<1024, 256, 0, stream>>>(hidden, Wq, Wk, Wv, Wo, pos, x_i8, sx, ct, st);

    gemm_qkv_k<<<dim3(32, 16), 256, 0, stream>>>(x_i8, sx, wq_i8, swq, qw, kw, ct, st,
                                                 q_i8, sq, k_i8, sk, vtT);

    attn_p1_k<<<dim3(128, 8), 256, 0, stream>>>(q_i8, sq, k_i8, sk, mm);
    attn_p2_k<<<dim3(64, 8), 256, 0, stream>>>(q_i8, sq, k_i8, sk, vtT, mm, attn2, pp, zb);

    row_quant_red_k<<<128, 256, 0, stream>>>(attn2, pp, zb, a_i8, sa);
    gemm_o_k<<<dim3(32, 16), 256, 0, stream>>>(a_i8, sa, wo_i8, swo, out, 2048, 2048, 2048);
}

// Round 14
// 187.047 us; speedup vs baseline: 1.1354x; 1.0180x over previous
//
#include <hip/hip_runtime.h>
#include <math.h>

#define NH 16
#define NKV 8
#define HDIM 128
#define SEQ 2048
#define DMODEL 2048

typedef int   v4i __attribute__((ext_vector_type(4)));
typedef float v4f __attribute__((ext_vector_type(4)));
typedef _Float16 v8h __attribute__((ext_vector_type(8)));

static constexpr float SM_SCALE = 0.08838834764831843f; // 128**-0.5

#define GLOBP(p) (__attribute__((address_space(1))) void*)(p)
#define LDSP(p)  (__attribute__((address_space(3))) void*)(p)
#define ASYNC16(g, l) __builtin_amdgcn_global_load_lds(GLOBP(g), LDSP(l), 16, 0, 0)

// Fragment-tiled i8 layout for X[R][K] (R%16==0, K%64==0):
// frag (r>>4, k>>6) is 1024B; within: byte = ((k>>4)&3)*256 + (r&15)*16 + (k&15).

__device__ __forceinline__ unsigned short f2h_bits(float x) {
    _Float16 h = (_Float16)x;               // RN, exact for small ints
    return __builtin_bit_cast(unsigned short, h);
}

// ---------------- merged per-row int8 quant (5 inputs) + rope table ----------------
__global__ __launch_bounds__(256) void quant_rope_k(const float* __restrict__ hidden,
        const float* __restrict__ Wq, const float* __restrict__ Wk,
        const float* __restrict__ Wv, const float* __restrict__ Wo,
        const int* __restrict__ pos_ids,
        signed char* __restrict__ out, float* __restrict__ scale,
        float* __restrict__ ct, float* __restrict__ st) {
    int p = blockIdx.x;
    if (p >= 512) {
        int t = (p - 512) * 4 + (threadIdx.x >> 6);
        int fi = threadIdx.x & 63;
        float inv = 1.0f / (float)pow(1.0e6, (double)fi / 64.0);
        float fr = (float)pos_ids[t] * inv;
        float sn, c;
        sincosf(fr, &sn, &c);
        ct[t * 64 + fi] = c;
        st[t * 64 + fi] = sn;
        return;
    }
    int row0g = p * 16;
    const float* in; int lr0;
    if (row0g < 2048)      { in = hidden; lr0 = row0g; }
    else if (row0g < 4096) { in = Wq; lr0 = row0g - 2048; }
    else if (row0g < 5120) { in = Wk; lr0 = row0g - 4096; }
    else if (row0g < 6144) { in = Wv; lr0 = row0g - 5120; }
    else                   { in = Wo; lr0 = row0g - 6144; }
    const int cols = 2048;
    int tid = threadIdx.x;
    __shared__ float srow[16];
    int r = tid >> 4, l16 = tid & 15;
    const float4* x4 = (const float4*)(in + (size_t)(lr0 + r) * cols);
    float amax = 0.f;
    for (int c4 = l16; c4 < (cols >> 2); c4 += 16) {
        float4 v = x4[c4];
        amax = fmaxf(amax, fmaxf(fmaxf(fabsf(v.x), fabsf(v.y)),
                                 fmaxf(fabsf(v.z), fabsf(v.w))));
    }
#pragma unroll
    for (int m = 1; m <= 8; m <<= 1) amax = fmaxf(amax, __shfl_xor(amax, m));
    if (l16 == 0) {
        float s = fmaxf(amax / 127.0f, 1e-8f);
        srow[r] = s;
        scale[row0g + r] = s;
    }
    __syncthreads();
    int total = (cols >> 4) * 16;
    size_t obase = (size_t)p * 32768;
    for (int idx = tid; idx < total; idx += 256) {
        int f = idx >> 6, q = (idx >> 4) & 3, rr = idx & 15;
        const float* src = in + (size_t)(lr0 + rr) * cols + f * 64 + q * 16;
        float s = srow[rr];
        unsigned int wds[4];
#pragma unroll
        for (int g = 0; g < 4; ++g) {
            float4 v = *(const float4*)(src + g * 4);
            int b0 = (int)fminf(fmaxf(rintf(v.x / s), -127.f), 127.f);
            int b1 = (int)fminf(fmaxf(rintf(v.y / s), -127.f), 127.f);
            int b2 = (int)fminf(fmaxf(rintf(v.z / s), -127.f), 127.f);
            int b3 = (int)fminf(fmaxf(rintf(v.w / s), -127.f), 127.f);
            wds[g] = (b0 & 255) | ((b1 & 255) << 8) | ((b2 & 255) << 16) | ((b3 & 255) << 24);
        }
        *(uint4*)(out + obase + (size_t)idx * 16) =
            make_uint4(wds[0], wds[1], wds[2], wds[3]);
    }
}

// ---------------- fused max-aware split-K reduce + row quant (attn2 -> a_i8) ----------
// Per row/head: M=max(m0,m1), w_c=exp(m_c-M), Zt=Z0w0+Z1w1,
// value = (acc0*w0 + acc1*w1) * max((1/Zt)/127, 1e-8).
__global__ __launch_bounds__(256) void row_quant_red_k(const float* __restrict__ attn2,
        const float* __restrict__ pp, const float* __restrict__ zb,
        signed char* __restrict__ out, float* __restrict__ scale) {
    int row0 = blockIdx.x * 16;
    bool corr = (row0 >= 1024);
    int tid = threadIdx.x;
    __shared__ float srow[16];
    __shared__ float4 spvt[16][17];     // (w0, w1, spv, -)
    if (corr) {
        int r = tid >> 4, h = tid & 15;
        int row = row0 + r;
        int t16 = (row >> 6) - 16, rr = row & 63;
        const float2* zb2 = (const float2*)zb;
        float2 a0 = zb2[(((size_t)h * 16 + t16) * 2 + 0) * 64 + rr];
        float2 a1 = zb2[(((size_t)h * 16 + t16) * 2 + 1) * 64 + rr];
        float M = fmaxf(a0.x, a1.x);
        float w0 = __expf(a0.x - M), w1 = __expf(a1.x - M);
        float Zt = a0.y * w0 + a1.y * w1;
        float spv = fmaxf((1.0f / Zt) / 127.0f, 1e-8f);
        spvt[r][h] = make_float4(w0, w1, spv, 0.f);
    }
    __syncthreads();
    int r = tid >> 4, l16 = tid & 15;
    int row = row0 + r;
    const float4* x4 = (const float4*)(attn2 + (size_t)row * 2048);
    size_t ppr = corr ? ((((size_t)(row >> 6) - 16) * 64 + (row & 63)) * 128) : 0;
    float amax = 0.f;
    for (int c4 = l16; c4 < 512; c4 += 16) {
        float4 v = x4[c4];
        if (corr) {
            int h = c4 >> 5;
            int j = (c4 & 31) * 4;
            float4 pv = *(const float4*)&pp[(size_t)h * 16 * 64 * 128 + ppr + j];
            float4 wz = spvt[r][h];
            v.x = (v.x * wz.x + pv.x * wz.y) * wz.z;
            v.y = (v.y * wz.x + pv.y * wz.y) * wz.z;
            v.z = (v.z * wz.x + pv.z * wz.y) * wz.z;
            v.w = (v.w * wz.x + pv.w * wz.y) * wz.z;
        }
        amax = fmaxf(amax, fmaxf(fmaxf(fabsf(v.x), fabsf(v.y)),
                                 fmaxf(fabsf(v.z), fabsf(v.w))));
    }
#pragma unroll
    for (int m = 1; m <= 8; m <<= 1) amax = fmaxf(amax, __shfl_xor(amax, m));
    if (l16 == 0) {
        float s = fmaxf(amax / 127.0f, 1e-8f);
        srow[r] = s;
        scale[row0 + r] = s;
    }
    __syncthreads();
    size_t obase = ((size_t)(row0 >> 4) * 32) << 10;
    for (int idx = tid; idx < 2048; idx += 256) {
        int f = idx >> 6, q = (idx >> 4) & 3, rr16 = idx & 15;
        int rowb = row0 + rr16;
        int colb = f * 64 + q * 16;
        const float* src = attn2 + (size_t)rowb * 2048 + colb;
        float s = srow[rr16];
        int h = f >> 1;
        float4 wz = corr ? spvt[rr16][h] : make_float4(1.f, 0.f, 0.f, 0.f);
        size_t ppb = corr ? ((size_t)h * 16 * 64 * 128
                     + (((size_t)(rowb >> 6) - 16) * 64 + (rowb & 63)) * 128 + (colb & 127)) : 0;
        unsigned int wds[4];
#pragma unroll
        for (int g = 0; g < 4; ++g) {
            float4 v = *(const float4*)(src + g * 4);
            if (corr) {
                float4 pv = *(const float4*)&pp[ppb + g * 4];
                v.x = (v.x * wz.x + pv.x * wz.y) * wz.z;
                v.y = (v.y * wz.x + pv.y * wz.y) * wz.z;
                v.z = (v.z * wz.x + pv.z * wz.y) * wz.z;
                v.w = (v.w * wz.x + pv.w * wz.y) * wz.z;
            }
            int b0 = (int)fminf(fmaxf(rintf(v.x / s), -127.f), 127.f);
            int b1 = (int)fminf(fmaxf(rintf(v.y / s), -127.f), 127.f);
            int b2 = (int)fminf(fmaxf(rintf(v.z / s), -127.f), 127.f);
            int b3 = (int)fminf(fmaxf(rintf(v.w / s), -127.f), 127.f);
            wds[g] = (b0 & 255) | ((b1 & 255) << 8) | ((b2 & 255) << 16) | ((b3 & 255) << 24);
        }
        *(uint4*)(out + obase + (size_t)idx * 16) =
            make_uint4(wds[0], wds[1], wds[2], wds[3]);
    }
}

// ---------------- O-projection GEMM: 128x64 tile -> 512 blocks (2/CU) ----------------
__global__ __launch_bounds__(256, 3) void gemm_o_k(const signed char* __restrict__ A,
        const float* __restrict__ sa, const signed char* __restrict__ B,
        const float* __restrict__ sb, float* __restrict__ C, int M, int N, int K) {
    __shared__ __align__(16) signed char lsA[3][8192];
    __shared__ __align__(16) signed char lsB[3][4096];
    int tid = threadIdx.x;
    int w = tid >> 6, l = tid & 63;
    int wr = w >> 1, wc = w & 1;
    int lrow = l & 15;
    int m0 = blockIdx.y * 128, n0 = blockIdx.x * 64;
    int kb6 = K >> 6;
    v4i acc[4][2];
#pragma unroll
    for (int i = 0; i < 4; ++i)
#pragma unroll
        for (int j = 0; j < 2; ++j) acc[i][j] = (v4i){0, 0, 0, 0};

    auto stage = [&](int buf, int k6) {
#pragma unroll
        for (int a = 0; a < 2; ++a) {
            int f = a * 4 + w;
            ASYNC16(A + (((size_t)(((m0 >> 4) + f) * kb6 + k6)) << 10) + l * 16,
                    lsA[buf] + f * 1024);
        }
        ASYNC16(B + (((size_t)(((n0 >> 4) + w) * kb6 + k6)) << 10) + l * 16,
                lsB[buf] + w * 1024);
    };

    stage(0, 0);
    if (kb6 > 1) {
        stage(1, 1);
        asm volatile("s_waitcnt vmcnt(3)" ::: "memory");
    } else {
        asm volatile("s_waitcnt vmcnt(0)" ::: "memory");
    }
    __builtin_amdgcn_s_barrier();
    for (int t = 0; t < kb6; ++t) {
        if (t + 2 < kb6) stage((t + 2) % 3, t + 2);
        int cur = t % 3;
        v4i af[4], bf[2];
#pragma unroll
        for (int i = 0; i < 4; ++i) af[i] = *(const v4i*)(lsA[cur] + (wr * 4 + i) * 1024 + l * 16);
#pragma unroll
        for (int j = 0; j < 2; ++j) bf[j] = *(const v4i*)(lsB[cur] + (wc * 2 + j) * 1024 + l * 16);
#pragma unroll
        for (int i = 0; i < 4; ++i)
#pragma unroll
            for (int j = 0; j < 2; ++j)
                acc[i][j] = __builtin_amdgcn_mfma_i32_16x16x64_i8(af[i], bf[j], acc[i][j], 0, 0, 0);
        if (t + 2 < kb6) asm volatile("s_waitcnt vmcnt(3)" ::: "memory");
        else             asm volatile("s_waitcnt vmcnt(0)" ::: "memory");
        __builtin_amdgcn_s_barrier();
    }
    int r0 = m0 + wr * 64, c0 = n0 + wc * 32;
    int lg = l >> 4;
    float sbv[2];
#pragma unroll
    for (int j = 0; j < 2; ++j) sbv[j] = sb[c0 + j * 16 + lrow];
#pragma unroll
    for (int i = 0; i < 4; ++i) {
        float4 s4 = *(const float4*)(sa + r0 + i * 16 + lg * 4);
        float sav[4] = {s4.x, s4.y, s4.z, s4.w};
#pragma unroll
        for (int j = 0; j < 2; ++j) {
#pragma unroll
            for (int reg = 0; reg < 4; ++reg) {
                int rr = r0 + i * 16 + lg * 4 + reg;
                C[(size_t)rr * N + c0 + j * 16 + lrow] = (float)acc[i][j][reg] * (sav[reg] * sbv[j]);
            }
        }
    }
}

// ---------------- QKV GEMM with fused rmsnorm+rope+quant / V-transpose epilogue ----------
__global__ __launch_bounds__(256, 2) void gemm_qkv_k(const signed char* __restrict__ A,
        const float* __restrict__ sa, const signed char* __restrict__ B,
        const float* __restrict__ sb,
        const float* __restrict__ qw, const float* __restrict__ kw,
        const float* __restrict__ ct, const float* __restrict__ st,
        signed char* __restrict__ q_i8, float* __restrict__ sq,
        signed char* __restrict__ k_i8, float* __restrict__ sk,
        unsigned short* __restrict__ vtT) {
    __shared__ __align__(16) char smem[68608];
    signed char (*lsA)[8192] = (signed char(*)[8192])smem;
    signed char (*lsB)[8192] = (signed char(*)[8192])(smem + 24576);
    float (*tile)[132] = (float(*)[132])smem;
    float* srow = (float*)(smem + 67584);
    int tid = threadIdx.x;
    int w = tid >> 6, l = tid & 63;
    int wr = w >> 1, wc = w & 1;
    int lrow = l & 15, lg = l >> 4;
    int m0 = blockIdx.y * 128, n0 = blockIdx.x * 128;
    const int kb6 = 32;
    v4i acc[4][4];
#pragma unroll
    for (int i = 0; i < 4; ++i)
#pragma unroll
        for (int j = 0; j < 4; ++j) acc[i][j] = (v4i){0, 0, 0, 0};

    auto stage = [&](int buf, int k6) {
#pragma unroll
        for (int a = 0; a < 2; ++a) {
            int f = a * 4 + w;
            ASYNC16(A + (((size_t)(((m0 >> 4) + f) * kb6 + k6)) << 10) + l * 16,
                    lsA[buf] + f * 1024);
            ASYNC16(B + (((size_t)(((n0 >> 4) + f) * kb6 + k6)) << 10) + l * 16,
                    lsB[buf] + f * 1024);
        }
    };

    stage(0, 0);
    stage(1, 1);
    asm volatile("s_waitcnt vmcnt(4)" ::: "memory");
    __builtin_amdgcn_s_barrier();
    for (int t = 0; t < kb6; ++t) {
        if (t + 2 < kb6) stage((t + 2) % 3, t + 2);
        int cur = t % 3;
        v4i af[4], bf[4];
#pragma unroll
        for (int i = 0; i < 4; ++i) af[i] = *(const v4i*)(lsA[cur] + (wr * 4 + i) * 1024 + l * 16);
#pragma unroll
        for (int j = 0; j < 4; ++j) bf[j] = *(const v4i*)(lsB[cur] + (wc * 4 + j) * 1024 + l * 16);
#pragma unroll
        for (int i = 0; i < 4; ++i)
#pragma unroll
            for (int j = 0; j < 4; ++j)
                acc[i][j] = __builtin_amdgcn_mfma_i32_16x16x64_i8(af[i], bf[j], acc[i][j], 0, 0, 0);
        if (t + 2 < kb6) asm volatile("s_waitcnt vmcnt(4)" ::: "memory");
        else             asm volatile("s_waitcnt vmcnt(0)" ::: "memory");
        __builtin_amdgcn_s_barrier();
    }
    {
        int c0 = n0 + wc * 64;
        float sbv[4];
#pragma unroll
        for (int j = 0; j < 4; ++j) sbv[j] = sb[c0 + j * 16 + lrow];
#pragma unroll
        for (int i = 0; i < 4; ++i) {
            float4 s4 = *(const float4*)(sa + m0 + wr * 64 + i * 16 + lg * 4);
            float sav[4] = {s4.x, s4.y, s4.z, s4.w};
#pragma unroll
            for (int j = 0; j < 4; ++j)
#pragma unroll
                for (int reg = 0; reg < 4; ++reg)
                    tile[wr * 64 + i * 16 + lg * 4 + reg][wc * 64 + j * 16 + lrow] =
                        (float)acc[i][j][reg] * (sav[reg] * sbv[j]);
        }
    }
    __syncthreads();
    int slot = n0 >> 7;
    if (slot < 24) {
        const float* wn = (slot < 16) ? qw : kw;
        signed char* dst8 = (slot < 16) ? q_i8 + (size_t)slot * (SEQ * 128)
                                        : k_i8 + (size_t)(slot - 16) * (SEQ * 128);
        float* sdst = (slot < 16) ? sq + (size_t)slot * SEQ : sk + (size_t)(slot - 16) * SEQ;
        float wn0 = wn[l], wn1 = wn[l + 64];
        for (int it = 0; it < 32; ++it) {
            int tl = it * 4 + w;
            int t = m0 + tl;
            float x0 = tile[tl][l];
            float x1 = tile[tl][l + 64];
            float ss = x0 * x0 + x1 * x1;
#pragma unroll
            for (int m = 1; m <= 32; m <<= 1) ss += __shfl_xor(ss, m);
            float rs = 1.0f / sqrtf(ss / 128.0f + 1e-6f);
            x0 = (x0 * rs) * wn0;
            x1 = (x1 * rs) * wn1;
            float cth = ct[t * 64 + l];
            float sth = st[t * 64 + l];
            float nx0 = x0 * cth - x1 * sth;
            float nx1 = x1 * cth + x0 * sth;
            float amax = fmaxf(fabsf(nx0), fabsf(nx1));
#pragma unroll
            for (int m = 1; m <= 32; m <<= 1) amax = fmaxf(amax, __shfl_xor(amax, m));
            float s = fmaxf(amax / 127.0f, 1e-8f);
            float q0 = fminf(fmaxf(rintf(nx0 / s), -127.f), 127.f);
            float q1 = fminf(fmaxf(rintf(nx1 / s), -127.f), 127.f);
            size_t ta0 = (size_t)(((t >> 4) * 2) << 10)
                       + (size_t)((((l >> 4) & 3) << 8) + ((t & 15) << 4) + (l & 15));
            dst8[ta0] = (signed char)(int)q0;
            dst8[ta0 + 1024] = (signed char)(int)q1;
            if (l == 0) sdst[t] = s;
        }
    } else {
        int kv = slot - 24;
        for (int it = 0; it < 32; ++it) {
            int tl = it * 4 + w;
            float x0 = tile[tl][l];
            float x1 = tile[tl][l + 64];
            float amax = fmaxf(fabsf(x0), fabsf(x1));
#pragma unroll
            for (int m = 1; m <= 32; m <<= 1) amax = fmaxf(amax, __shfl_xor(amax, m));
            if (l == 0) srow[tl] = fmaxf(amax / 127.0f, 1e-8f);
        }
        __syncthreads();
        int d = tid >> 1, th = (tid & 1) * 32;
        size_t base = (size_t)kv * (SEQ * 128);
#pragma unroll
        for (int kbl = 0; kbl < 2; ++kbl) {
            int kb = (m0 >> 6) + kbl;
#pragma unroll
            for (int j = 0; j < 32; j += 2) {
                int t64 = th + j;
                int tg = kbl * 64 + t64;
                float s0 = srow[tg], s1 = srow[tg + 1];
                float a = fminf(fmaxf(rintf(tile[tg][d] / s0), -127.f), 127.f) * s0;
                float b = fminf(fmaxf(rintf(tile[tg + 1][d] / s1), -127.f), 127.f) * s1;
                unsigned int ua = f2h_bits(a), ub = f2h_bits(b);
                int off = kb * 8192 + ((d >> 4) * 2 + ((t64 >> 5) & 1)) * 512
                        + (((d & 15) + (((t64 >> 3) & 3) << 4)) << 3) + (t64 & 7);
                *(unsigned int*)(vtT + base + off) = ua | (ub << 16);
            }
        }
    }
}

// ---------------- attention (single pass): GQA-paired online-softmax flash ----------------
// Online row max; acc/Z rescaled by exp(m_old-m_new). Split-K chunks store (m, Z) raw accs.
__global__ __launch_bounds__(256, 2) void attn_k(const signed char* __restrict__ q_i8,
        const float* __restrict__ sq, const signed char* __restrict__ k_i8,
        const float* __restrict__ sk, const unsigned short* __restrict__ vtT,
        float* __restrict__ attn2, float* __restrict__ pp, float* __restrict__ zb) {
    __shared__ __align__(16) unsigned short vlds[3][8192];  // 48 KB
    __shared__ __align__(16) signed char klds[2][8192];     // 16 KB
    __shared__ __align__(16) unsigned short plds[4096];     // 8 KB wave-private (A then B)
    __shared__ __align__(16) float slds[1024];              // 4 KB chunk K-scales
    int bx = blockIdx.x, hp = blockIdx.y;
    int qb = 31 - (bx >> 1), c = bx & 1;
    int nch2 = (qb >= 16) ? 2 : 1;
    if (c >= nch2) return;
    int q0 = qb * 64;
    int kb0 = c * 16, kb1 = min((c + 1) * 16, qb + 1);
    int tid = threadIdx.x, w = tid >> 6, l = tid & 63;
    int lrow = l & 15, lg = l >> 4;
    int h0 = hp * 2, h1 = h0 + 1;

    const signed char* qtA = q_i8 + (size_t)h0 * (SEQ * 128)
                           + ((size_t)((((q0 >> 4) + w) * 2)) << 10) + l * 16;
    const signed char* qtB = qtA + (size_t)(SEQ * 128);
    v4i qfA0 = *(const v4i*)(qtA), qfA1 = *(const v4i*)(qtA + 1024);
    v4i qfB0 = *(const v4i*)(qtB), qfB1 = *(const v4i*)(qtB + 1024);
    float4 sA = *(const float4*)(sq + (size_t)h0 * SEQ + q0 + w * 16 + lg * 4);
    float4 sB = *(const float4*)(sq + (size_t)h1 * SEQ + q0 + w * 16 + lg * 4);
    float sqrA[4] = {sA.x, sA.y, sA.z, sA.w};
    float sqrB[4] = {sB.x, sB.y, sB.z, sB.w};

    const signed char* kbase = k_i8 + (size_t)hp * (SEQ * 128);
    const float* skb = sk + (size_t)hp * SEQ;
    const unsigned short* vt = vtT + (size_t)hp * (SEQ * 128);

    auto issueV = [&](int kb) {
        unsigned short* vb = &vlds[kb % 3][0];
#pragma unroll
        for (int a = 0; a < 4; ++a) {
            int fv = a * 4 + w;
            ASYNC16(vt + (size_t)kb * 8192 + fv * 512 + l * 8, vb + fv * 512);
        }
    };
    auto issueK = [&](int kb) {
        signed char* kbuf = &klds[kb & 1][0];
#pragma unroll
        for (int a = 0; a < 2; ++a) {
            int f = a * 4 + w;
            ASYNC16(kbase + ((size_t)(kb * 8 + f) << 10) + l * 16, kbuf + f * 1024);
        }
    };

    v4f accA[8], accB[8];
#pragma unroll
    for (int jd = 0; jd < 8; ++jd) {
        accA[jd] = (v4f){0.f, 0.f, 0.f, 0.f};
        accB[jd] = (v4f){0.f, 0.f, 0.f, 0.f};
    }
    float ztA[4] = {0.f, 0.f, 0.f, 0.f};
    float ztB[4] = {0.f, 0.f, 0.f, 0.f};
    float mA[4], mB[4];
#pragma unroll
    for (int r = 0; r < 4; ++r) { mA[r] = -1e30f; mB[r] = -1e30f; }

    ASYNC16(skb + kb0 * 64 + w * 256 + l * 4, (char*)slds + w * 1024);
    issueK(kb0);
    issueV(kb0);
    if (kb0 + 1 < kb1) {
        issueV(kb0 + 1);
        asm volatile("s_waitcnt vmcnt(4)" ::: "memory");
    } else {
        asm volatile("s_waitcnt vmcnt(0)" ::: "memory");
    }
    __builtin_amdgcn_s_barrier();

    for (int kb = kb0; kb < kb1; ++kb) {
        int k0 = kb * 64;
        if (kb + 1 < kb1) issueK(kb + 1);
        if (kb + 2 < kb1) issueV(kb + 2);
        v4i ka[8];
#pragma unroll
        for (int f = 0; f < 8; ++f)
            ka[f] = *(const v4i*)(&klds[kb & 1][0] + f * 1024 + l * 16);
        float skc[4];
#pragma unroll
        for (int j = 0; j < 4; ++j) skc[j] = slds[(kb - kb0) * 64 + j * 16 + lrow];
        v4i sciA[4], sciB[4];
#pragma unroll
        for (int j = 0; j < 4; ++j) {
            v4i z = {0, 0, 0, 0};
            v4i tA = __builtin_amdgcn_mfma_i32_16x16x64_i8(qfA0, ka[j * 2], z, 0, 0, 0);
            sciA[j] = __builtin_amdgcn_mfma_i32_16x16x64_i8(qfA1, ka[j * 2 + 1], tA, 0, 0, 0);
            v4i tB = __builtin_amdgcn_mfma_i32_16x16x64_i8(qfB0, ka[j * 2], z, 0, 0, 0);
            sciB[j] = __builtin_amdgcn_mfma_i32_16x16x64_i8(qfB1, ka[j * 2 + 1], tB, 0, 0, 0);
        }
        // scores (masked) + per-tile row max
        float svA[4][4], svB[4][4];
        float tmA[4], tmB[4];
#pragma unroll
        for (int reg = 0; reg < 4; ++reg) { tmA[reg] = -1e30f; tmB[reg] = -1e30f; }
#pragma unroll
        for (int reg = 0; reg < 4; ++reg) {
            int r = q0 + w * 16 + lg * 4 + reg;
#pragma unroll
            for (int j = 0; j < 4; ++j) {
                int cc = j * 16 + lrow;
                bool ok = (k0 + cc <= r);
                float ss = skc[j] * SM_SCALE;
                svA[reg][j] = ok ? ((float)sciA[j][reg] * sqrA[reg]) * ss : -1e30f;
                svB[reg][j] = ok ? ((float)sciB[j][reg] * sqrB[reg]) * ss : -1e30f;
                tmA[reg] = fmaxf(tmA[reg], svA[reg][j]);
                tmB[reg] = fmaxf(tmB[reg], svB[reg][j]);
            }
        }
#pragma unroll
        for (int reg = 0; reg < 4; ++reg) {
#pragma unroll
            for (int mask = 1; mask <= 8; mask <<= 1) {
                tmA[reg] = fmaxf(tmA[reg], __shfl_xor(tmA[reg], mask));
                tmB[reg] = fmaxf(tmB[reg], __shfl_xor(tmB[reg], mask));
            }
        }
        // online rescale
        float efA[4], efB[4];
#pragma unroll
        for (int reg = 0; reg < 4; ++reg) {
            float mnA = fmaxf(mA[reg], tmA[reg]);
            efA[reg] = __expf(mA[reg] - mnA);       // 0 on first tile
            mA[reg] = mnA;
            ztA[reg] *= efA[reg];
            float mnB = fmaxf(mB[reg], tmB[reg]);
            efB[reg] = __expf(mB[reg] - mnB);
            mB[reg] = mnB;
            ztB[reg] *= efB[reg];
        }
        v4f efvA = {efA[0], efA[1], efA[2], efA[3]};
        v4f efvB = {efB[0], efB[1], efB[2], efB[3]};
#pragma unroll
        for (int jd = 0; jd < 8; ++jd) {
            accA[jd] *= efvA;
            accB[jd] *= efvB;
        }
        // quantize p (head A), PV-stage, then head B in the same wave-private plds
#pragma unroll
        for (int reg = 0; reg < 4; ++reg) {
            int rq = lg * 4 + reg;
#pragma unroll
            for (int j = 0; j < 4; ++j) {
                int cc = j * 16 + lrow;
                float pd = 0.f;
                float sv = svA[reg][j];
                if (sv > -5e29f) {
                    float e = __expf(sv - mA[reg]);
                    ztA[reg] += e;
                    pd = fminf(rintf(127.0f * e), 127.f);
                }
                plds[(w * 2 + (cc >> 5)) * 512 + (rq + 16 * ((cc >> 3) & 3)) * 8 + (cc & 7)] =
                    f2h_bits(pd);
            }
        }
        v8h pfA0 = *(const v8h*)(plds + (w * 2 + 0) * 512 + l * 8);
        v8h pfA1 = *(const v8h*)(plds + (w * 2 + 1) * 512 + l * 8);
#pragma unroll
        for (int reg = 0; reg < 4; ++reg) {
            int rq = lg * 4 + reg;
#pragma unroll
            for (int j = 0; j < 4; ++j) {
                int cc = j * 16 + lrow;
                float pd = 0.f;
                float sv = svB[reg][j];
                if (sv > -5e29f) {
                    float e = __expf(sv - mB[reg]);
                    ztB[reg] += e;
                    pd = fminf(rintf(127.0f * e), 127.f);
                }
                plds[(w * 2 + (cc >> 5)) * 512 + (rq + 16 * ((cc >> 3) & 3)) * 8 + (cc & 7)] =
                    f2h_bits(pd);
            }
        }
        v8h pfB0 = *(const v8h*)(plds + (w * 2 + 0) * 512 + l * 8);
        v8h pfB1 = *(const v8h*)(plds + (w * 2 + 1) * 512 + l * 8);
        const unsigned short* vb = &vlds[kb % 3][0];
#pragma unroll
        for (int jd = 0; jd < 8; ++jd) {
            v8h vh0 = *(const v8h*)(vb + (jd * 2 + 0) * 512 + l * 8);
            v8h vh1 = *(const v8h*)(vb + (jd * 2 + 1) * 512 + l * 8);
            v4f tA = accA[jd];
            tA = __builtin_amdgcn_mfma_f32_16x16x32_f16(pfA0, vh0, tA, 0, 0, 0);
            tA = __builtin_amdgcn_mfma_f32_16x16x32_f16(pfA1, vh1, tA, 0, 0, 0);
            accA[jd] = tA;
            v4f tB = accB[jd];
            tB = __builtin_amdgcn_mfma_f32_16x16x32_f16(pfB0, vh0, tB, 0, 0, 0);
            tB = __builtin_amdgcn_mfma_f32_16x16x32_f16(pfB1, vh1, tB, 0, 0, 0);
            accB[jd] = tB;
        }
        if (kb + 2 < kb1) asm volatile("s_waitcnt vmcnt(4)" ::: "memory");
        else              asm volatile("s_waitcnt vmcnt(0)" ::: "memory");
        __builtin_amdgcn_s_barrier();
    }
    // combine Z across the 16 lanes sharing a row (m already row-uniform)
#pragma unroll
    for (int reg = 0; reg < 4; ++reg) {
#pragma unroll
        for (int mask = 1; mask <= 8; mask <<= 1) {
            ztA[reg] += __shfl_xor(ztA[reg], mask);
            ztB[reg] += __shfl_xor(ztB[reg], mask);
        }
    }
    if (qb < 16) {
        float spA[4], spB[4];
#pragma unroll
        for (int reg = 0; reg < 4; ++reg) {
            spA[reg] = fmaxf((1.0f / ztA[reg]) / 127.0f, 1e-8f);
            spB[reg] = fmaxf((1.0f / ztB[reg]) / 127.0f, 1e-8f);
        }
#pragma unroll
        for (int jd = 0; jd < 8; ++jd)
#pragma unroll
            for (int reg = 0; reg < 4; ++reg) {
                int r = q0 + w * 16 + lg * 4 + reg;
                attn2[(size_t)r * DMODEL + h0 * HDIM + jd * 16 + lrow] = accA[jd][reg] * spA[reg];
                attn2[(size_t)r * DMODEL + h1 * HDIM + jd * 16 + lrow] = accB[jd][reg] * spB[reg];
            }
    } else {
        if (c == 0) {
#pragma unroll
            for (int jd = 0; jd < 8; ++jd)
#pragma unroll
                for (int reg = 0; reg < 4; ++reg) {
                    int r = q0 + w * 16 + lg * 4 + reg;
                    attn2[(size_t)r * DMODEL + h0 * HDIM + jd * 16 + lrow] = accA[jd][reg];
                    attn2[(size_t)r * DMODEL + h1 * HDIM + jd * 16 + lrow] = accB[jd][reg];
                }
        } else {
#pragma unroll
            for (int jd = 0; jd < 8; ++jd)
#pragma unroll
                for (int reg = 0; reg < 4; ++reg) {
                    int rr = w * 16 + lg * 4 + reg;
                    pp[(((size_t)h0 * 16 + (qb - 16)) * 64 + rr) * 128 + jd * 16 + lrow] = accA[jd][reg];
                    pp[(((size_t)h1 * 16 + (qb - 16)) * 64 + rr) * 128 + jd * 16 + lrow] = accB[jd][reg];
                }
        }
        if (lrow == 0) {
            float2* zb2 = (float2*)zb;
            size_t zA = (((size_t)h0 * 16 + (qb - 16)) * 2 + c) * 64;
            size_t zB = (((size_t)h1 * 16 + (qb - 16)) * 2 + c) * 64;
#pragma unroll
            for (int reg = 0; reg < 4; ++reg) {
                zb2[zA + w * 16 + lg * 4 + reg] = make_float2(mA[reg], ztA[reg]);
                zb2[zB + w * 16 + lg * 4 + reg] = make_float2(mB[reg], ztB[reg]);
            }
        }
    }
}

extern "C" void kernel_launch(void* const* d_in, const int* in_sizes, int n_in,
                              void* d_out, int out_size, void* d_ws, size_t ws_size,
                              hipStream_t stream) {
    (void)in_sizes; (void)n_in; (void)out_size; (void)ws_size;
    const float* hidden = (const float*)d_in[0];
    const float* Wq = (const float*)d_in[1];
    const float* Wk = (const float*)d_in[2];
    const float* Wv = (const float*)d_in[3];
    const float* Wo = (const float*)d_in[4];
    const float* qw = (const float*)d_in[5];
    const float* kw = (const float*)d_in[6];
    const int* pos = (const int*)d_in[7];
    float* out = (float*)d_out;
    char* ws = (char*)d_ws;

    const size_t MB = 1024 * 1024;
    signed char* x_i8  = (signed char*)(ws);            // contiguous 16MB tiled i8 block
    signed char* wq_i8 = (signed char*)(ws + 4 * MB);
    signed char* wo_i8 = (signed char*)(ws + 12 * MB);
    signed char* q_i8  = (signed char*)(ws + 16 * MB);  // 4 MB (attn-tiled)
    signed char* k_i8  = (signed char*)(ws + 20 * MB);  // 2 MB (attn-tiled)
    float* sx  = (float*)(ws + 22 * MB);                // contiguous scales
    float* swq = sx + 2048;
    float* swo = sx + 6144;
    float* sq  = sx + 8192;                             // 16*2048
    float* sk  = sq + NH * SEQ;                         // 8*2048
    float* sa  = sk + NKV * SEQ;                        // 2048
    float* ct  = (float*)(ws + 22 * MB + 512 * 1024);   // 512 KB
    float* st  = (float*)(ws + 22 * MB + 1024 * 1024);  // 512 KB
    float* attn2 = (float*)(ws + 32 * MB);              // 16 MB
    float* pp    = (float*)(ws + 48 * MB);              // 8 MB
    unsigned short* vtT = (unsigned short*)(ws + 56 * MB); // 4 MB
    float* zb    = (float*)(ws + 60 * MB);              // 256 KB (float2 m,Z per row/chunk)
    signed char* a_i8 = x_i8;

    quant_rope_k<<<1024, 256, 0, stream>>>(hidden, Wq, Wk, Wv, Wo, pos, x_i8, sx, ct, st);

    gemm_qkv_k<<<dim3(32, 16), 256, 0, stream>>>(x_i8, sx, wq_i8, swq, qw, kw, ct, st,
                                                 q_i8, sq, k_i8, sk, vtT);

    attn_k<<<dim3(64, 8), 256, 0, stream>>>(q_i8, sq, k_i8, sk, vtT, attn2, pp, zb);

    row_quant_red_k<<<128, 256, 0, stream>>>(attn2, pp, zb, a_i8, sa);
    gemm_o_k<<<dim3(32, 16), 256, 0, stream>>>(a_i8, sa, wo_i8, swo, out, 2048, 2048, 2048);
}

// Round 15
// 179.318 us; speedup vs baseline: 1.1844x; 1.0431x over previous
//
#include <hip/hip_runtime.h>
#include <math.h>

#define NH 16
#define NKV 8
#define HDIM 128
#define SEQ 2048
#define DMODEL 2048

typedef int   v4i __attribute__((ext_vector_type(4)));
typedef float v4f __attribute__((ext_vector_type(4)));
typedef _Float16 v8h __attribute__((ext_vector_type(8)));

static constexpr float SM_SCALE = 0.08838834764831843f; // 128**-0.5

#define GLOBP(p) (__attribute__((address_space(1))) void*)(p)
#define LDSP(p)  (__attribute__((address_space(3))) void*)(p)
#define ASYNC16(g, l) __builtin_amdgcn_global_load_lds(GLOBP(g), LDSP(l), 16, 0, 0)

// Fragment-tiled i8 layout for X[R][K] (R%16==0, K%64==0):
// frag (r>>4, k>>6) is 1024B; within: byte = ((k>>4)&3)*256 + (r&15)*16 + (k&15).

__device__ __forceinline__ unsigned short f2h_bits(float x) {
    _Float16 h = (_Float16)x;               // RN, exact for small ints
    return __builtin_bit_cast(unsigned short, h);
}

// ---------------- merged per-row int8 quant (5 inputs) + rope table ----------------
__global__ __launch_bounds__(256) void quant_rope_k(const float* __restrict__ hidden,
        const float* __restrict__ Wq, const float* __restrict__ Wk,
        const float* __restrict__ Wv, const float* __restrict__ Wo,
        const int* __restrict__ pos_ids,
        signed char* __restrict__ out, float* __restrict__ scale,
        float* __restrict__ ct, float* __restrict__ st) {
    int p = blockIdx.x;
    if (p >= 512) {
        int t = (p - 512) * 4 + (threadIdx.x >> 6);
        int fi = threadIdx.x & 63;
        float inv = 1.0f / (float)pow(1.0e6, (double)fi / 64.0);
        float fr = (float)pos_ids[t] * inv;
        float sn, c;
        sincosf(fr, &sn, &c);
        ct[t * 64 + fi] = c;
        st[t * 64 + fi] = sn;
        return;
    }
    int row0g = p * 16;
    const float* in; int lr0;
    if (row0g < 2048)      { in = hidden; lr0 = row0g; }
    else if (row0g < 4096) { in = Wq; lr0 = row0g - 2048; }
    else if (row0g < 5120) { in = Wk; lr0 = row0g - 4096; }
    else if (row0g < 6144) { in = Wv; lr0 = row0g - 5120; }
    else                   { in = Wo; lr0 = row0g - 6144; }
    const int cols = 2048;
    int tid = threadIdx.x;
    __shared__ float srow[16];
    int r = tid >> 4, l16 = tid & 15;
    const float4* x4 = (const float4*)(in + (size_t)(lr0 + r) * cols);
    float amax = 0.f;
    for (int c4 = l16; c4 < (cols >> 2); c4 += 16) {
        float4 v = x4[c4];
        amax = fmaxf(amax, fmaxf(fmaxf(fabsf(v.x), fabsf(v.y)),
                                 fmaxf(fabsf(v.z), fabsf(v.w))));
    }
#pragma unroll
    for (int m = 1; m <= 8; m <<= 1) amax = fmaxf(amax, __shfl_xor(amax, m));
    if (l16 == 0) {
        float s = fmaxf(amax / 127.0f, 1e-8f);
        srow[r] = s;
        scale[row0g + r] = s;
    }
    __syncthreads();
    int total = (cols >> 4) * 16;
    size_t obase = (size_t)p * 32768;
    for (int idx = tid; idx < total; idx += 256) {
        int f = idx >> 6, q = (idx >> 4) & 3, rr = idx & 15;
        const float* src = in + (size_t)(lr0 + rr) * cols + f * 64 + q * 16;
        float s = srow[rr];
        unsigned int wds[4];
#pragma unroll
        for (int g = 0; g < 4; ++g) {
            float4 v = *(const float4*)(src + g * 4);
            int b0 = (int)fminf(fmaxf(rintf(v.x / s), -127.f), 127.f);
            int b1 = (int)fminf(fmaxf(rintf(v.y / s), -127.f), 127.f);
            int b2 = (int)fminf(fmaxf(rintf(v.z / s), -127.f), 127.f);
            int b3 = (int)fminf(fmaxf(rintf(v.w / s), -127.f), 127.f);
            wds[g] = (b0 & 255) | ((b1 & 255) << 8) | ((b2 & 255) << 16) | ((b3 & 255) << 24);
        }
        *(uint4*)(out + obase + (size_t)idx * 16) =
            make_uint4(wds[0], wds[1], wds[2], wds[3]);
    }
}

// ---------------- fused max-aware split-K combine + row quant (attn raw -> a_i8) ----------
// Every row: M=max(m0,m1), w_c=exp(m_c-M), Zt=Z0w0+Z1w1,
// value = (acc0*w0 + acc1*w1) * max((1/Zt)/127, 1e-8).
__global__ __launch_bounds__(256) void row_quant_red_k(const float* __restrict__ attn2,
        const float* __restrict__ pp, const float* __restrict__ zb,
        signed char* __restrict__ out, float* __restrict__ scale) {
    int row0 = blockIdx.x * 16;
    int tid = threadIdx.x;
    __shared__ float srow[16];
    __shared__ float4 spvt[16][17];     // (w0, w1, spv, -)
    {
        int r = tid >> 4, h = tid & 15;
        int row = row0 + r;
        int t32 = row >> 6, rr = row & 63;
        const float2* zb2 = (const float2*)zb;
        float2 a0 = zb2[(((size_t)h * 32 + t32) * 2 + 0) * 64 + rr];
        float2 a1 = zb2[(((size_t)h * 32 + t32) * 2 + 1) * 64 + rr];
        float M = fmaxf(a0.x, a1.x);
        float w0 = __expf(a0.x - M), w1 = __expf(a1.x - M);
        float Zt = a0.y * w0 + a1.y * w1;
        float spv = fmaxf((1.0f / Zt) / 127.0f, 1e-8f);
        spvt[r][h] = make_float4(w0, w1, spv, 0.f);
    }
    __syncthreads();
    int r = tid >> 4, l16 = tid & 15;
    int row = row0 + r;
    const float4* x4 = (const float4*)(attn2 + (size_t)row * 2048);
    size_t ppr = ((size_t)(row >> 6) * 64 + (row & 63)) * 128;
    float amax = 0.f;
    for (int c4 = l16; c4 < 512; c4 += 16) {
        float4 v = x4[c4];
        int h = c4 >> 5;
        int j = (c4 & 31) * 4;
        float4 pv = *(const float4*)&pp[(size_t)h * 32 * 64 * 128 + ppr + j];
        float4 wz = spvt[r][h];
        v.x = (v.x * wz.x + pv.x * wz.y) * wz.z;
        v.y = (v.y * wz.x + pv.y * wz.y) * wz.z;
        v.z = (v.z * wz.x + pv.z * wz.y) * wz.z;
        v.w = (v.w * wz.x + pv.w * wz.y) * wz.z;
        amax = fmaxf(amax, fmaxf(fmaxf(fabsf(v.x), fabsf(v.y)),
                                 fmaxf(fabsf(v.z), fabsf(v.w))));
    }
#pragma unroll
    for (int m = 1; m <= 8; m <<= 1) amax = fmaxf(amax, __shfl_xor(amax, m));
    if (l16 == 0) {
        float s = fmaxf(amax / 127.0f, 1e-8f);
        srow[r] = s;
        scale[row0 + r] = s;
    }
    __syncthreads();
    size_t obase = ((size_t)(row0 >> 4) * 32) << 10;
    for (int idx = tid; idx < 2048; idx += 256) {
        int f = idx >> 6, q = (idx >> 4) & 3, rr16 = idx & 15;
        int rowb = row0 + rr16;
        int colb = f * 64 + q * 16;
        const float* src = attn2 + (size_t)rowb * 2048 + colb;
        float s = srow[rr16];
        int h = f >> 1;
        float4 wz = spvt[rr16][h];
        size_t ppb = (size_t)h * 32 * 64 * 128
                   + ((size_t)(rowb >> 6) * 64 + (rowb & 63)) * 128 + (colb & 127);
        unsigned int wds[4];
#pragma unroll
        for (int g = 0; g < 4; ++g) {
            float4 v = *(const float4*)(src + g * 4);
            float4 pv = *(const float4*)&pp[ppb + g * 4];
            v.x = (v.x * wz.x + pv.x * wz.y) * wz.z;
            v.y = (v.y * wz.x + pv.y * wz.y) * wz.z;
            v.z = (v.z * wz.x + pv.z * wz.y) * wz.z;
            v.w = (v.w * wz.x + pv.w * wz.y) * wz.z;
            int b0 = (int)fminf(fmaxf(rintf(v.x / s), -127.f), 127.f);
            int b1 = (int)fminf(fmaxf(rintf(v.y / s), -127.f), 127.f);
            int b2 = (int)fminf(fmaxf(rintf(v.z / s), -127.f), 127.f);
            int b3 = (int)fminf(fmaxf(rintf(v.w / s), -127.f), 127.f);
            wds[g] = (b0 & 255) | ((b1 & 255) << 8) | ((b2 & 255) << 16) | ((b3 & 255) << 24);
        }
        *(uint4*)(out + obase + (size_t)idx * 16) =
            make_uint4(wds[0], wds[1], wds[2], wds[3]);
    }
}

// ---------------- O-projection GEMM: 128x64 tile -> 512 blocks (2/CU) ----------------
__global__ __launch_bounds__(256, 3) void gemm_o_k(const signed char* __restrict__ A,
        const float* __restrict__ sa, const signed char* __restrict__ B,
        const float* __restrict__ sb, float* __restrict__ C, int M, int N, int K) {
    __shared__ __align__(16) signed char lsA[3][8192];
    __shared__ __align__(16) signed char lsB[3][4096];
    int tid = threadIdx.x;
    int w = tid >> 6, l = tid & 63;
    int wr = w >> 1, wc = w & 1;
    int lrow = l & 15;
    int m0 = blockIdx.y * 128, n0 = blockIdx.x * 64;
    int kb6 = K >> 6;
    v4i acc[4][2];
#pragma unroll
    for (int i = 0; i < 4; ++i)
#pragma unroll
        for (int j = 0; j < 2; ++j) acc[i][j] = (v4i){0, 0, 0, 0};

    auto stage = [&](int buf, int k6) {
#pragma unroll
        for (int a = 0; a < 2; ++a) {
            int f = a * 4 + w;
            ASYNC16(A + (((size_t)(((m0 >> 4) + f) * kb6 + k6)) << 10) + l * 16,
                    lsA[buf] + f * 1024);
        }
        ASYNC16(B + (((size_t)(((n0 >> 4) + w) * kb6 + k6)) << 10) + l * 16,
                lsB[buf] + w * 1024);
    };

    stage(0, 0);
    if (kb6 > 1) {
        stage(1, 1);
        asm volatile("s_waitcnt vmcnt(3)" ::: "memory");
    } else {
        asm volatile("s_waitcnt vmcnt(0)" ::: "memory");
    }
    __builtin_amdgcn_s_barrier();
    for (int t = 0; t < kb6; ++t) {
        if (t + 2 < kb6) stage((t + 2) % 3, t + 2);
        int cur = t % 3;
        v4i af[4], bf[2];
#pragma unroll
        for (int i = 0; i < 4; ++i) af[i] = *(const v4i*)(lsA[cur] + (wr * 4 + i) * 1024 + l * 16);
#pragma unroll
        for (int j = 0; j < 2; ++j) bf[j] = *(const v4i*)(lsB[cur] + (wc * 2 + j) * 1024 + l * 16);
#pragma unroll
        for (int i = 0; i < 4; ++i)
#pragma unroll
            for (int j = 0; j < 2; ++j)
                acc[i][j] = __builtin_amdgcn_mfma_i32_16x16x64_i8(af[i], bf[j], acc[i][j], 0, 0, 0);
        if (t + 2 < kb6) asm volatile("s_waitcnt vmcnt(3)" ::: "memory");
        else             asm volatile("s_waitcnt vmcnt(0)" ::: "memory");
        __builtin_amdgcn_s_barrier();
    }
    int r0 = m0 + wr * 64, c0 = n0 + wc * 32;
    int lg = l >> 4;
    float sbv[2];
#pragma unroll
    for (int j = 0; j < 2; ++j) sbv[j] = sb[c0 + j * 16 + lrow];
#pragma unroll
    for (int i = 0; i < 4; ++i) {
        float4 s4 = *(const float4*)(sa + r0 + i * 16 + lg * 4);
        float sav[4] = {s4.x, s4.y, s4.z, s4.w};
#pragma unroll
        for (int j = 0; j < 2; ++j) {
#pragma unroll
            for (int reg = 0; reg < 4; ++reg) {
                int rr = r0 + i * 16 + lg * 4 + reg;
                C[(size_t)rr * N + c0 + j * 16 + lrow] = (float)acc[i][j][reg] * (sav[reg] * sbv[j]);
            }
        }
    }
}

// ---------------- QKV GEMM with fused rmsnorm+rope+quant / V-transpose epilogue ----------
__global__ __launch_bounds__(256, 2) void gemm_qkv_k(const signed char* __restrict__ A,
        const float* __restrict__ sa, const signed char* __restrict__ B,
        const float* __restrict__ sb,
        const float* __restrict__ qw, const float* __restrict__ kw,
        const float* __restrict__ ct, const float* __restrict__ st,
        signed char* __restrict__ q_i8, float* __restrict__ sq,
        signed char* __restrict__ k_i8, float* __restrict__ sk,
        unsigned short* __restrict__ vtT) {
    __shared__ __align__(16) char smem[68608];
    signed char (*lsA)[8192] = (signed char(*)[8192])smem;
    signed char (*lsB)[8192] = (signed char(*)[8192])(smem + 24576);
    float (*tile)[132] = (float(*)[132])smem;
    float* srow = (float*)(smem + 67584);
    int tid = threadIdx.x;
    int w = tid >> 6, l = tid & 63;
    int wr = w >> 1, wc = w & 1;
    int lrow = l & 15, lg = l >> 4;
    int m0 = blockIdx.y * 128, n0 = blockIdx.x * 128;
    const int kb6 = 32;
    v4i acc[4][4];
#pragma unroll
    for (int i = 0; i < 4; ++i)
#pragma unroll
        for (int j = 0; j < 4; ++j) acc[i][j] = (v4i){0, 0, 0, 0};

    auto stage = [&](int buf, int k6) {
#pragma unroll
        for (int a = 0; a < 2; ++a) {
            int f = a * 4 + w;
            ASYNC16(A + (((size_t)(((m0 >> 4) + f) * kb6 + k6)) << 10) + l * 16,
                    lsA[buf] + f * 1024);
            ASYNC16(B + (((size_t)(((n0 >> 4) + f) * kb6 + k6)) << 10) + l * 16,
                    lsB[buf] + f * 1024);
        }
    };

    stage(0, 0);
    stage(1, 1);
    asm volatile("s_waitcnt vmcnt(4)" ::: "memory");
    __builtin_amdgcn_s_barrier();
    for (int t = 0; t < kb6; ++t) {
        if (t + 2 < kb6) stage((t + 2) % 3, t + 2);
        int cur = t % 3;
        v4i af[4], bf[4];
#pragma unroll
        for (int i = 0; i < 4; ++i) af[i] = *(const v4i*)(lsA[cur] + (wr * 4 + i) * 1024 + l * 16);
#pragma unroll
        for (int j = 0; j < 4; ++j) bf[j] = *(const v4i*)(lsB[cur] + (wc * 4 + j) * 1024 + l * 16);
#pragma unroll
        for (int i = 0; i < 4; ++i)
#pragma unroll
            for (int j = 0; j < 4; ++j)
                acc[i][j] = __builtin_amdgcn_mfma_i32_16x16x64_i8(af[i], bf[j], acc[i][j], 0, 0, 0);
        if (t + 2 < kb6) asm volatile("s_waitcnt vmcnt(4)" ::: "memory");
        else             asm volatile("s_waitcnt vmcnt(0)" ::: "memory");
        __builtin_amdgcn_s_barrier();
    }
    {
        int c0 = n0 + wc * 64;
        float sbv[4];
#pragma unroll
        for (int j = 0; j < 4; ++j) sbv[j] = sb[c0 + j * 16 + lrow];
#pragma unroll
        for (int i = 0; i < 4; ++i) {
            float4 s4 = *(const float4*)(sa + m0 + wr * 64 + i * 16 + lg * 4);
            float sav[4] = {s4.x, s4.y, s4.z, s4.w};
#pragma unroll
            for (int j = 0; j < 4; ++j)
#pragma unroll
                for (int reg = 0; reg < 4; ++reg)
                    tile[wr * 64 + i * 16 + lg * 4 + reg][wc * 64 + j * 16 + lrow] =
                        (float)acc[i][j][reg] * (sav[reg] * sbv[j]);
        }
    }
    __syncthreads();
    int slot = n0 >> 7;
    if (slot < 24) {
        const float* wn = (slot < 16) ? qw : kw;
        signed char* dst8 = (slot < 16) ? q_i8 + (size_t)slot * (SEQ * 128)
                                        : k_i8 + (size_t)(slot - 16) * (SEQ * 128);
        float* sdst = (slot < 16) ? sq + (size_t)slot * SEQ : sk + (size_t)(slot - 16) * SEQ;
        float wn0 = wn[l], wn1 = wn[l + 64];
        for (int it = 0; it < 32; ++it) {
            int tl = it * 4 + w;
            int t = m0 + tl;
            float x0 = tile[tl][l];
            float x1 = tile[tl][l + 64];
            float ss = x0 * x0 + x1 * x1;
#pragma unroll
            for (int m = 1; m <= 32; m <<= 1) ss += __shfl_xor(ss, m);
            float rs = 1.0f / sqrtf(ss / 128.0f + 1e-6f);
            x0 = (x0 * rs) * wn0;
            x1 = (x1 * rs) * wn1;
            float cth = ct[t * 64 + l];
            float sth = st[t * 64 + l];
            float nx0 = x0 * cth - x1 * sth;
            float nx1 = x1 * cth + x0 * sth;
            float amax = fmaxf(fabsf(nx0), fabsf(nx1));
#pragma unroll
            for (int m = 1; m <= 32; m <<= 1) amax = fmaxf(amax, __shfl_xor(amax, m));
            float s = fmaxf(amax / 127.0f, 1e-8f);
            float q0 = fminf(fmaxf(rintf(nx0 / s), -127.f), 127.f);
            float q1 = fminf(fmaxf(rintf(nx1 / s), -127.f), 127.f);
            size_t ta0 = (size_t)(((t >> 4) * 2) << 10)
                       + (size_t)((((l >> 4) & 3) << 8) + ((t & 15) << 4) + (l & 15));
            dst8[ta0] = (signed char)(int)q0;
            dst8[ta0 + 1024] = (signed char)(int)q1;
            if (l == 0) sdst[t] = s;
        }
    } else {
        int kv = slot - 24;
        for (int it = 0; it < 32; ++it) {
            int tl = it * 4 + w;
            float x0 = tile[tl][l];
            float x1 = tile[tl][l + 64];
            float amax = fmaxf(fabsf(x0), fabsf(x1));
#pragma unroll
            for (int m = 1; m <= 32; m <<= 1) amax = fmaxf(amax, __shfl_xor(amax, m));
            if (l == 0) srow[tl] = fmaxf(amax / 127.0f, 1e-8f);
        }
        __syncthreads();
        int d = tid >> 1, th = (tid & 1) * 32;
        size_t base = (size_t)kv * (SEQ * 128);
#pragma unroll
        for (int kbl = 0; kbl < 2; ++kbl) {
            int kb = (m0 >> 6) + kbl;
#pragma unroll
            for (int j = 0; j < 32; j += 2) {
                int t64 = th + j;
                int tg = kbl * 64 + t64;
                float s0 = srow[tg], s1 = srow[tg + 1];
                float a = fminf(fmaxf(rintf(tile[tg][d] / s0), -127.f), 127.f) * s0;
                float b = fminf(fmaxf(rintf(tile[tg + 1][d] / s1), -127.f), 127.f) * s1;
                unsigned int ua = f2h_bits(a), ub = f2h_bits(b);
                int off = kb * 8192 + ((d >> 4) * 2 + ((t64 >> 5) & 1)) * 512
                        + (((d & 15) + (((t64 >> 3) & 3) << 4)) << 3) + (t64 & 7);
                *(unsigned int*)(vtT + base + off) = ua | (ub << 16);
            }
        }
    }
}

// ---------------- attention: GQA-paired online-softmax flash, balanced 2-chunk split ------
// Every tile split at h=(qb+2)>>1 into chunks [0,h) and [h,qb+1) -> only 8/512 blocks idle.
// All chunks write raw accs (c=0 -> attn2, c=1 -> pp) + (m, Z); combine in row_quant_red.
__global__ __launch_bounds__(256, 2) void attn_k(const signed char* __restrict__ q_i8,
        const float* __restrict__ sq, const signed char* __restrict__ k_i8,
        const float* __restrict__ sk, const unsigned short* __restrict__ vtT,
        float* __restrict__ attn2, float* __restrict__ pp, float* __restrict__ zb) {
    __shared__ __align__(16) unsigned short vlds[3][8192];  // 48 KB
    __shared__ __align__(16) signed char klds[2][8192];     // 16 KB
    __shared__ __align__(16) unsigned short plds[4096];     // 8 KB wave-private (A then B)
    __shared__ __align__(16) float slds[1024];              // 4 KB chunk K-scales
    int bx = blockIdx.x, hp = blockIdx.y;
    int qb = 31 - (bx >> 1), c = bx & 1;
    int q0 = qb * 64;
    int hsp = (qb + 2) >> 1;
    int kb0 = c ? hsp : 0;
    int kb1 = c ? (qb + 1) : hsp;
    int tid = threadIdx.x, w = tid >> 6, l = tid & 63;
    int lrow = l & 15, lg = l >> 4;
    int h0 = hp * 2, h1 = h0 + 1;

    if (kb0 >= kb1) {               // only qb==0, c==1: write sentinel (m=-inf, Z=0)
        if (lrow == 0) {
            float2* zb2 = (float2*)zb;
            size_t zA = (((size_t)h0 * 32 + qb) * 2 + c) * 64;
            size_t zB = (((size_t)h1 * 32 + qb) * 2 + c) * 64;
#pragma unroll
            for (int reg = 0; reg < 4; ++reg) {
                zb2[zA + w * 16 + lg * 4 + reg] = make_float2(-1e30f, 0.f);
                zb2[zB + w * 16 + lg * 4 + reg] = make_float2(-1e30f, 0.f);
            }
        }
        return;
    }

    const signed char* qtA = q_i8 + (size_t)h0 * (SEQ * 128)
                           + ((size_t)((((q0 >> 4) + w) * 2)) << 10) + l * 16;
    const signed char* qtB = qtA + (size_t)(SEQ * 128);
    v4i qfA0 = *(const v4i*)(qtA), qfA1 = *(const v4i*)(qtA + 1024);
    v4i qfB0 = *(const v4i*)(qtB), qfB1 = *(const v4i*)(qtB + 1024);
    float4 sA = *(const float4*)(sq + (size_t)h0 * SEQ + q0 + w * 16 + lg * 4);
    float4 sB = *(const float4*)(sq + (size_t)h1 * SEQ + q0 + w * 16 + lg * 4);
    float sqrA[4] = {sA.x, sA.y, sA.z, sA.w};
    float sqrB[4] = {sB.x, sB.y, sB.z, sB.w};

    const signed char* kbase = k_i8 + (size_t)hp * (SEQ * 128);
    const float* skb = sk + (size_t)hp * SEQ;
    const unsigned short* vt = vtT + (size_t)hp * (SEQ * 128);

    auto issueV = [&](int kb) {
        unsigned short* vb = &vlds[kb % 3][0];
#pragma unroll
        for (int a = 0; a < 4; ++a) {
            int fv = a * 4 + w;
            ASYNC16(vt + (size_t)kb * 8192 + fv * 512 + l * 8, vb + fv * 512);
        }
    };
    auto issueK = [&](int kb) {
        signed char* kbuf = &klds[kb & 1][0];
#pragma unroll
        for (int a = 0; a < 2; ++a) {
            int f = a * 4 + w;
            ASYNC16(kbase + ((size_t)(kb * 8 + f) << 10) + l * 16, kbuf + f * 1024);
        }
    };

    v4f accA[8], accB[8];
#pragma unroll
    for (int jd = 0; jd < 8; ++jd) {
        accA[jd] = (v4f){0.f, 0.f, 0.f, 0.f};
        accB[jd] = (v4f){0.f, 0.f, 0.f, 0.f};
    }
    float ztA[4] = {0.f, 0.f, 0.f, 0.f};
    float ztB[4] = {0.f, 0.f, 0.f, 0.f};
    float mA[4], mB[4];
#pragma unroll
    for (int r = 0; r < 4; ++r) { mA[r] = -1e30f; mB[r] = -1e30f; }

    ASYNC16(skb + kb0 * 64 + w * 256 + l * 4, (char*)slds + w * 1024);
    issueK(kb0);
    issueV(kb0);
    if (kb0 + 1 < kb1) {
        issueV(kb0 + 1);
        asm volatile("s_waitcnt vmcnt(4)" ::: "memory");
    } else {
        asm volatile("s_waitcnt vmcnt(0)" ::: "memory");
    }
    __builtin_amdgcn_s_barrier();

    for (int kb = kb0; kb < kb1; ++kb) {
        int k0 = kb * 64;
        if (kb + 1 < kb1) issueK(kb + 1);
        if (kb + 2 < kb1) issueV(kb + 2);
        v4i ka[8];
#pragma unroll
        for (int f = 0; f < 8; ++f)
            ka[f] = *(const v4i*)(&klds[kb & 1][0] + f * 1024 + l * 16);
        float skc[4];
#pragma unroll
        for (int j = 0; j < 4; ++j) skc[j] = slds[(kb - kb0) * 64 + j * 16 + lrow];
        v4i sciA[4], sciB[4];
#pragma unroll
        for (int j = 0; j < 4; ++j) {
            v4i z = {0, 0, 0, 0};
            v4i tA = __builtin_amdgcn_mfma_i32_16x16x64_i8(qfA0, ka[j * 2], z, 0, 0, 0);
            sciA[j] = __builtin_amdgcn_mfma_i32_16x16x64_i8(qfA1, ka[j * 2 + 1], tA, 0, 0, 0);
            v4i tB = __builtin_amdgcn_mfma_i32_16x16x64_i8(qfB0, ka[j * 2], z, 0, 0, 0);
            sciB[j] = __builtin_amdgcn_mfma_i32_16x16x64_i8(qfB1, ka[j * 2 + 1], tB, 0, 0, 0);
        }
        float svA[4][4], svB[4][4];
        float tmA[4], tmB[4];
#pragma unroll
        for (int reg = 0; reg < 4; ++reg) { tmA[reg] = -1e30f; tmB[reg] = -1e30f; }
#pragma unroll
        for (int reg = 0; reg < 4; ++reg) {
            int r = q0 + w * 16 + lg * 4 + reg;
#pragma unroll
            for (int j = 0; j < 4; ++j) {
                int cc = j * 16 + lrow;
                bool ok = (k0 + cc <= r);
                float ss = skc[j] * SM_SCALE;
                svA[reg][j] = ok ? ((float)sciA[j][reg] * sqrA[reg]) * ss : -1e30f;
                svB[reg][j] = ok ? ((float)sciB[j][reg] * sqrB[reg]) * ss : -1e30f;
                tmA[reg] = fmaxf(tmA[reg], svA[reg][j]);
                tmB[reg] = fmaxf(tmB[reg], svB[reg][j]);
            }
        }
#pragma unroll
        for (int reg = 0; reg < 4; ++reg) {
#pragma unroll
            for (int mask = 1; mask <= 8; mask <<= 1) {
                tmA[reg] = fmaxf(tmA[reg], __shfl_xor(tmA[reg], mask));
                tmB[reg] = fmaxf(tmB[reg], __shfl_xor(tmB[reg], mask));
            }
        }
        float efA[4], efB[4];
#pragma unroll
        for (int reg = 0; reg < 4; ++reg) {
            float mnA = fmaxf(mA[reg], tmA[reg]);
            efA[reg] = __expf(mA[reg] - mnA);
            mA[reg] = mnA;
            ztA[reg] *= efA[reg];
            float mnB = fmaxf(mB[reg], tmB[reg]);
            efB[reg] = __expf(mB[reg] - mnB);
            mB[reg] = mnB;
            ztB[reg] *= efB[reg];
        }
        v4f efvA = {efA[0], efA[1], efA[2], efA[3]};
        v4f efvB = {efB[0], efB[1], efB[2], efB[3]};
#pragma unroll
        for (int jd = 0; jd < 8; ++jd) {
            accA[jd] *= efvA;
            accB[jd] *= efvB;
        }
#pragma unroll
        for (int reg = 0; reg < 4; ++reg) {
            int rq = lg * 4 + reg;
#pragma unroll
            for (int j = 0; j < 4; ++j) {
                int cc = j * 16 + lrow;
                float pd = 0.f;
                float sv = svA[reg][j];
                if (sv > -5e29f) {
                    float e = __expf(sv - mA[reg]);
                    ztA[reg] += e;
                    pd = fminf(rintf(127.0f * e), 127.f);
                }
                plds[(w * 2 + (cc >> 5)) * 512 + (rq + 16 * ((cc >> 3) & 3)) * 8 + (cc & 7)] =
                    f2h_bits(pd);
            }
        }
        v8h pfA0 = *(const v8h*)(plds + (w * 2 + 0) * 512 + l * 8);
        v8h pfA1 = *(const v8h*)(plds + (w * 2 + 1) * 512 + l * 8);
#pragma unroll
        for (int reg = 0; reg < 4; ++reg) {
            int rq = lg * 4 + reg;
#pragma unroll
            for (int j = 0; j < 4; ++j) {
                int cc = j * 16 + lrow;
                float pd = 0.f;
                float sv = svB[reg][j];
                if (sv > -5e29f) {
                    float e = __expf(sv - mB[reg]);
                    ztB[reg] += e;
                    pd = fminf(rintf(127.0f * e), 127.f);
                }
                plds[(w * 2 + (cc >> 5)) * 512 + (rq + 16 * ((cc >> 3) & 3)) * 8 + (cc & 7)] =
                    f2h_bits(pd);
            }
        }
        v8h pfB0 = *(const v8h*)(plds + (w * 2 + 0) * 512 + l * 8);
        v8h pfB1 = *(const v8h*)(plds + (w * 2 + 1) * 512 + l * 8);
        const unsigned short* vb = &vlds[kb % 3][0];
#pragma unroll
        for (int jd = 0; jd < 8; ++jd) {
            v8h vh0 = *(const v8h*)(vb + (jd * 2 + 0) * 512 + l * 8);
            v8h vh1 = *(const v8h*)(vb + (jd * 2 + 1) * 512 + l * 8);
            v4f tA = accA[jd];
            tA = __builtin_amdgcn_mfma_f32_16x16x32_f16(pfA0, vh0, tA, 0, 0, 0);
            tA = __builtin_amdgcn_mfma_f32_16x16x32_f16(pfA1, vh1, tA, 0, 0, 0);
            accA[jd] = tA;
            v4f tB = accB[jd];
            tB = __builtin_amdgcn_mfma_f32_16x16x32_f16(pfB0, vh0, tB, 0, 0, 0);
            tB = __builtin_amdgcn_mfma_f32_16x16x32_f16(pfB1, vh1, tB, 0, 0, 0);
            accB[jd] = tB;
        }
        if (kb + 2 < kb1) asm volatile("s_waitcnt vmcnt(4)" ::: "memory");
        else              asm volatile("s_waitcnt vmcnt(0)" ::: "memory");
        __builtin_amdgcn_s_barrier();
    }
#pragma unroll
    for (int reg = 0; reg < 4; ++reg) {
#pragma unroll
        for (int mask = 1; mask <= 8; mask <<= 1) {
            ztA[reg] += __shfl_xor(ztA[reg], mask);
            ztB[reg] += __shfl_xor(ztB[reg], mask);
        }
    }
    // all chunks: write raw accumulators + (m, Z)
    if (c == 0) {
#pragma unroll
        for (int jd = 0; jd < 8; ++jd)
#pragma unroll
            for (int reg = 0; reg < 4; ++reg) {
                int r = q0 + w * 16 + lg * 4 + reg;
                attn2[(size_t)r * DMODEL + h0 * HDIM + jd * 16 + lrow] = accA[jd][reg];
                attn2[(size_t)r * DMODEL + h1 * HDIM + jd * 16 + lrow] = accB[jd][reg];
            }
    } else {
#pragma unroll
        for (int jd = 0; jd < 8; ++jd)
#pragma unroll
            for (int reg = 0; reg < 4; ++reg) {
                int rr = w * 16 + lg * 4 + reg;
                pp[(((size_t)h0 * 32 + qb) * 64 + rr) * 128 + jd * 16 + lrow] = accA[jd][reg];
                pp[(((size_t)h1 * 32 + qb) * 64 + rr) * 128 + jd * 16 + lrow] = accB[jd][reg];
            }
    }
    if (lrow == 0) {
        float2* zb2 = (float2*)zb;
        size_t zA = (((size_t)h0 * 32 + qb) * 2 + c) * 64;
        size_t zB = (((size_t)h1 * 32 + qb) * 2 + c) * 64;
#pragma unroll
        for (int reg = 0; reg < 4; ++reg) {
            zb2[zA + w * 16 + lg * 4 + reg] = make_float2(mA[reg], ztA[reg]);
            zb2[zB + w * 16 + lg * 4 + reg] = make_float2(mB[reg], ztB[reg]);
        }
    }
}

extern "C" void kernel_launch(void* const* d_in, const int* in_sizes, int n_in,
                              void* d_out, int out_size, void* d_ws, size_t ws_size,
                              hipStream_t stream) {
    (void)in_sizes; (void)n_in; (void)out_size; (void)ws_size;
    const float* hidden = (const float*)d_in[0];
    const float* Wq = (const float*)d_in[1];
    const float* Wk = (const float*)d_in[2];
    const float* Wv = (const float*)d_in[3];
    const float* Wo = (const float*)d_in[4];
    const float* qw = (const float*)d_in[5];
    const float* kw = (const float*)d_in[6];
    const int* pos = (const int*)d_in[7];
    float* out = (float*)d_out;
    char* ws = (char*)d_ws;

    const size_t MB = 1024 * 1024;
    signed char* x_i8  = (signed char*)(ws);            // 16 MB tiled i8 block (x,wq,wk,wv,wo)
    signed char* wq_i8 = (signed char*)(ws + 4 * MB);
    signed char* wo_i8 = (signed char*)(ws + 12 * MB);
    signed char* q_i8  = (signed char*)(ws + 16 * MB);  // 4 MB (attn-tiled)
    signed char* k_i8  = (signed char*)(ws + 20 * MB);  // 2 MB (attn-tiled)
    float* sx  = (float*)(ws + 22 * MB);                // scales (~232 KB)
    float* swq = sx + 2048;
    float* swo = sx + 6144;
    float* sq  = sx + 8192;                             // 16*2048
    float* sk  = sq + NH * SEQ;                         // 8*2048
    float* sa  = sk + NKV * SEQ;                        // 2048
    float* ct  = (float*)(ws + 22 * MB + 512 * 1024);   // 512 KB
    float* st  = (float*)(ws + 22 * MB + 1024 * 1024);  // 512 KB  (ends 23.5 MB)
    unsigned short* vtT = (unsigned short*)(ws + 24 * MB); // 4 MB
    float* zb    = (float*)(ws + 28 * MB);              // 512 KB (float2 m,Z per row/chunk)
    float* attn2 = (float*)(ws + 30 * MB);              // 16 MB (chunk-0 raw accs)
    float* pp    = (float*)(ws + 46 * MB);              // 16 MB (chunk-1 raw accs)
    signed char* a_i8 = x_i8;

    quant_rope_k<<<1024, 256, 0, stream>>>(hidden, Wq, Wk, Wv, Wo, pos, x_i8, sx, ct, st);

    gemm_qkv_k<<<dim3(32, 16), 256, 0, stream>>>(x_i8, sx, wq_i8, swq, qw, kw, ct, st,
                                                 q_i8, sq, k_i8, sk, vtT);

    attn_k<<<dim3(64, 8), 256, 0, stream>>>(q_i8, sq, k_i8, sk, vtT, attn2, pp, zb);

    row_quant_red_k<<<128, 256, 0, stream>>>(attn2, pp, zb, a_i8, sa);
    gemm_o_k<<<dim3(32, 16), 256, 0, stream>>>(a_i8, sa, wo_i8, swo, out, 2048, 2048, 2048);
}